// Round 10
// baseline (498.681 us; speedup 1.0000x reference)
//
#include <hip/hip_runtime.h>

typedef unsigned short u16;
typedef __bf16 bf16x8 __attribute__((ext_vector_type(8)));
typedef float f32x4 __attribute__((ext_vector_type(4)));
typedef u16 u16x4 __attribute__((ext_vector_type(4)));

constexpr int SEQ = 2048;
constexpr int NQKV = 6144; // (32 + 2*8) * 128

__device__ __forceinline__ float bf2f(u16 x) {
    unsigned int u = ((unsigned int)x) << 16;
    return __builtin_bit_cast(float, u);
}
__device__ __forceinline__ u16 f2bf(float f) {
    unsigned int u = __builtin_bit_cast(unsigned int, f);
    u += 0x7FFF + ((u >> 16) & 1);
    return (u16)(u >> 16);
}

__device__ __forceinline__ void gload16(const void* g, void* l) {
    void* gg = const_cast<void*>(g);
    __builtin_amdgcn_global_load_lds(
        (__attribute__((address_space(1))) void*)gg,
        (__attribute__((address_space(3))) void*)l, 16, 0, 0);
}

// counted-vmcnt gate + raw barrier (NO vmcnt(0) drain in steady state)
__device__ __forceinline__ void gatebar(int G) {
    if (G == 3) asm volatile("s_waitcnt vmcnt(3)" ::: "memory");
    else if (G == 2) asm volatile("s_waitcnt vmcnt(2)" ::: "memory");
    else asm volatile("s_waitcnt vmcnt(0)" ::: "memory");
    __builtin_amdgcn_sched_barrier(0);
    __builtin_amdgcn_s_barrier();
    __builtin_amdgcn_sched_barrier(0);
}

// ---------------- RoPE table ----------------
__global__ void rope_table_k(float* __restrict__ tab) {
    int idx = blockIdx.x * 256 + threadIdx.x;
    if (idx >= SEQ * 64) return;
    int s = idx >> 6;
    int i = idx & 63;
    float invf = expf(-(float)i * (float)(1.0 / 64.0) * logf(10000.0f));
    float ang = (float)s * invf;
    float sv, cv;
    sincosf(ang, &sv, &cv);
    tab[idx * 2] = cv;
    tab[idx * 2 + 1] = sv;
}

// ---------------- fp32 -> bf16 elementwise cast ----------------
__global__ __launch_bounds__(256) void cast_k(const float* __restrict__ src,
                                              u16* __restrict__ dst, int n4) {
    int i = blockIdx.x * 256 + threadIdx.x;
    if (i >= n4) return;
    f32x4 v = *(const f32x4*)&src[(size_t)i * 4];
    u16x4 o;
#pragma unroll
    for (int j = 0; j < 4; ++j) o[j] = f2bf(v[j]);
    *(u16x4*)&dst[(size_t)i * 4] = o;
}

// ---------------- fp32 transpose+cast (R x C fp32 -> C x R bf16) ----------------
__global__ __launch_bounds__(256) void transpose_cast_k(const float* __restrict__ src,
                                                        u16* __restrict__ dst, int R, int C) {
    __shared__ u16 tile[64][65];
    int t = threadIdx.x;
    int bx = blockIdx.x, by = blockIdx.y;
    int r0 = by * 64, c0 = bx * 64;
#pragma unroll
    for (int it = 0; it < 4; ++it) {
        int row = it * 16 + (t >> 4);
        int col = (t & 15) * 4;
        f32x4 v = *(const f32x4*)&src[(size_t)(r0 + row) * C + c0 + col];
        tile[row][col] = f2bf(v[0]); tile[row][col + 1] = f2bf(v[1]);
        tile[row][col + 2] = f2bf(v[2]); tile[row][col + 3] = f2bf(v[3]);
    }
    __syncthreads();
#pragma unroll
    for (int it = 0; it < 4; ++it) {
        int orow = it * 16 + (t >> 4);
        int ocol = (t & 15) * 4;
        u16x4 v;
        v[0] = tile[ocol][orow]; v[1] = tile[ocol + 1][orow];
        v[2] = tile[ocol + 2][orow]; v[3] = tile[ocol + 3][orow];
        *(u16x4*)&dst[(size_t)(c0 + orow) * R + r0 + ocol] = v;
    }
}

// ---- pipelined GEMM: C[M,N] = A[M,K] * BT[N,K]^T, bf16 in, fp32 acc ----
template <int NF, bool F32OUT>
__global__ __launch_bounds__(512, 4) void gemm_pipe_k(const u16* __restrict__ A,
                                                      const u16* __restrict__ BT,
                                                      void* __restrict__ Cv, int N, int K) {
    constexpr int BN = NF * 64;
    constexpr int SA = 128 * 64;
    constexpr int SB = BN * 64;
    constexpr int SBUF = SA + SB;
    __shared__ alignas(16) char lds[3 * SBUF];

    int t = threadIdx.x;
    int lane = t & 63, w = t >> 6;
    int wr = w >> 2, wc = w & 3;
    int l15 = lane & 15, l4 = lane >> 4;

    int nbn = N / BN;
    int wg = blockIdx.x;
    int cpx = gridDim.x >> 3;
    int swz = (wg & 7) * cpx + (wg >> 3);
    int bm = swz / nbn, bn = swz % nbn;

    const u16* Ab = A + (size_t)bm * 128 * K;
    const u16* Bb = BT + (size_t)bn * BN * K;

    int ar = t >> 2;
    int akc = (t & 3) ^ ((ar >> 1) & 3);
    const u16* ga = Ab + (size_t)ar * K + akc * 8;
    int br0 = t >> 2;
    int bk0 = (t & 3) ^ ((br0 >> 1) & 3);
    const u16* gb0 = Bb + (size_t)br0 * K + bk0 * 8;
    int bc1 = 512 + t;
    int br1 = bc1 >> 2;
    int bk1 = (bc1 & 3) ^ ((br1 >> 1) & 3);
    const u16* gb1 = Bb + (size_t)br1 * K + bk1 * 8;
    bool hasB1 = (NF == 3) && (w < 4);
    int myG = (NF == 3) ? ((w < 4) ? 3 : 2) : 2;

    auto stage = [&](int v) {
        int b = v - (v / 3) * 3;
        char* LA = lds + b * SBUF;
        char* LB = LA + SA;
        int ko = v * 32;
        gload16(ga + ko, LA + t * 16);
        gload16(gb0 + ko, LB + t * 16);
        if (NF == 3) {
            if (hasB1) gload16(gb1 + ko, LB + bc1 * 16);
        }
    };

    f32x4 acc[4][NF];
#pragma unroll
    for (int i = 0; i < 4; ++i)
#pragma unroll
        for (int j = 0; j < NF; ++j) acc[i][j] = f32x4{0.f, 0.f, 0.f, 0.f};

    int arow[4], akk[4];
#pragma unroll
    for (int fm = 0; fm < 4; ++fm) {
        arow[fm] = wr * 64 + fm * 16 + l15;
        akk[fm] = l4 ^ ((arow[fm] >> 1) & 3);
    }
    int brow[NF], bkk[NF];
#pragma unroll
    for (int fn = 0; fn < NF; ++fn) {
        brow[fn] = wc * (NF * 16) + fn * 16 + l15;
        bkk[fn] = l4 ^ ((brow[fn] >> 1) & 3);
    }

    int nk = K >> 5;
    stage(0);
    stage(1);
    gatebar(myG);

    int b = 0;
    for (int v = 0; v < nk; ++v) {
        const u16* LA = (const u16*)(lds + b * SBUF);
        const u16* LB = LA + SA / 2;
        if (v + 2 < nk) stage(v + 2);
        bf16x8 bf[NF];
#pragma unroll
        for (int fn = 0; fn < NF; ++fn)
            bf[fn] = *(const bf16x8*)&LB[brow[fn] * 32 + bkk[fn] * 8];
        __builtin_amdgcn_s_setprio(1);
#pragma unroll
        for (int fm = 0; fm < 4; ++fm) {
            bf16x8 af = *(const bf16x8*)&LA[arow[fm] * 32 + akk[fm] * 8];
#pragma unroll
            for (int fn = 0; fn < NF; ++fn)
                acc[fm][fn] = __builtin_amdgcn_mfma_f32_16x16x32_bf16(af, bf[fn],
                                                                     acc[fm][fn], 0, 0, 0);
        }
        __builtin_amdgcn_s_setprio(0);
        if (v < nk - 1) gatebar((v + 2 < nk) ? myG : 0);
        b = (b == 2) ? 0 : b + 1;
    }

#pragma unroll
    for (int fm = 0; fm < 4; ++fm)
#pragma unroll
        for (int fn = 0; fn < NF; ++fn)
#pragma unroll
            for (int i = 0; i < 4; ++i) {
                int row = bm * 128 + wr * 64 + fm * 16 + l4 * 4 + i;
                int col = bn * BN + wc * (NF * 16) + fn * 16 + l15;
                if constexpr (F32OUT)
                    ((float*)Cv)[(size_t)row * N + col] = acc[fm][fn][i];
                else
                    ((u16*)Cv)[(size_t)row * N + col] = f2bf(acc[fm][fn][i]);
            }
}

// -------- repack + RoPE (vectorized): QKV[s,6144] -> Q[h,s,d], K[hk,s,d], V[hk,s,d] --------
__global__ __launch_bounds__(256) void repack_rope_k(const u16* __restrict__ QKV,
                                                     const float* __restrict__ tab,
                                                     u16* __restrict__ Qo, u16* __restrict__ Ko,
                                                     u16* __restrict__ Vo) {
    int idx = blockIdx.x * 256 + threadIdx.x; // < SEQ*48*16
    int i4 = (idx & 15) * 4;
    int su = idx >> 4;
    int u = su % 48;
    int s = su / 48;
    if (u < 40) {
        const float* tp = tab + (s * 64 + i4) * 2;
        f32x4 t0 = *(const f32x4*)tp;
        f32x4 t1 = *(const f32x4*)(tp + 4);
        float cv[4] = {t0[0], t0[2], t1[0], t1[2]};
        float sv[4] = {t0[1], t0[3], t1[1], t1[3]};
        const u16* base;
        u16* ob;
        if (u < 32) {
            base = QKV + (size_t)s * NQKV + u * 128;
            ob = Qo + ((size_t)u * SEQ + s) * 128;
        } else {
            base = QKV + (size_t)s * NQKV + 4096 + (u - 32) * 128;
            ob = Ko + ((size_t)(u - 32) * SEQ + s) * 128;
        }
        u16x4 x1 = *(const u16x4*)(base + i4);
        u16x4 x2 = *(const u16x4*)(base + 64 + i4);
        u16x4 o1, o2;
#pragma unroll
        for (int j = 0; j < 4; ++j) {
            float a = bf2f(x1[j]), b = bf2f(x2[j]);
            o1[j] = f2bf(a * cv[j] - b * sv[j]);
            o2[j] = f2bf(b * cv[j] + a * sv[j]);
        }
        *(u16x4*)(ob + i4) = o1;
        *(u16x4*)(ob + 64 + i4) = o2;
    } else {
        int hv = u - 40;
        const u16* base = QKV + (size_t)s * NQKV + 5120 + hv * 128;
        u16* ob = Vo + ((size_t)hv * SEQ + s) * 128;
        *(u16x4*)(ob + i4) = *(const u16x4*)(base + i4);
        *(u16x4*)(ob + 64 + i4) = *(const u16x4*)(base + 64 + i4);
    }
}

// ------- causal GQA flash attention: UNPAIRED q-tiles (1024 blocks), KVBLK=64,
// ------- single-buffer K/V (43KB LDS -> 3 blocks/CU), explicit barriers -------
__global__ __launch_bounds__(256) void attn_k(const u16* __restrict__ Qg,
                                              const u16* __restrict__ Kg,
                                              const u16* __restrict__ Vg,
                                              u16* __restrict__ ctx) {
    constexpr float SCL2 = 0.08838834764831845f * 1.44269504088896340736f; // 1/sqrt(128)*log2e
    constexpr float THR = 11.5f;
    __shared__ alignas(16) u16 Klds[64 * 128];   // 16 KB, XOR-swizzled rows
    __shared__ alignas(16) u16 VT[128 * 72];     // 18 KB, V^T stride 72
    __shared__ alignas(16) u16 Plds[4 * 16 * 72]; // 9 KB, per-wave P (stride 72)

    int t = threadIdx.x;
    int lane = t & 63, w = t >> 6;
    int l15 = lane & 15, l4 = lane >> 4;
    int bxx = 31 - blockIdx.x;  // longest q-tiles dispatched FIRST (tail backfill)
    int h = blockIdx.y, hkv = h >> 2;
    const u16* Kh = Kg + (size_t)hkv * SEQ * 128;
    const u16* Vh = Vg + (size_t)hkv * SEQ * 128;
    u16* Pw = &Plds[w * 1152];

    // K staging: linear slots c = t + i*256, row kr, swizzled chunk
    int kr[4], kchs[4];
#pragma unroll
    for (int i2 = 0; i2 < 4; ++i2) {
        int c = t + i2 * 256;
        kr[i2] = c >> 4;
        kchs[i2] = (c & 15) ^ (kr[i2] & 7);
    }
    int vr = lane, vcb = w * 32;

    int q0 = bxx * 64;
    int nt = bxx + 1;

    bf16x8 qf[4], vreg[4];
    f32x4 o[8];
    float m_i[4], l_i[4];

    const u16* Qh = Qg + ((size_t)h * SEQ + q0 + w * 16 + l15) * 128;
#pragma unroll
    for (int ks = 0; ks < 4; ++ks) qf[ks] = *(const bf16x8*)(Qh + ks * 32 + l4 * 8);
#pragma unroll
    for (int nf = 0; nf < 8; ++nf) o[nf] = f32x4{0.f, 0.f, 0.f, 0.f};
#pragma unroll
    for (int i = 0; i < 4; ++i) { m_i[i] = -3.0e38f; l_i[i] = 0.f; }

    for (int tt = 0; tt < nt; ++tt) {
        int kv0 = tt << 6;
        // B1: all waves finished reading K/VT of previous tile
        __builtin_amdgcn_s_barrier();
        __builtin_amdgcn_sched_barrier(0);
        // issue V reg-loads + K gloads for THIS tile
#pragma unroll
        for (int seg = 0; seg < 4; ++seg)
            vreg[seg] = *(const bf16x8*)(Vh + (size_t)(kv0 + vr) * 128 + vcb + seg * 8);
#pragma unroll
        for (int i2 = 0; i2 < 4; ++i2)
            gload16(Kh + (size_t)(kv0 + kr[i2]) * 128 + kchs[i2] * 8,
                    (char*)Klds + (size_t)(t + i2 * 256) * 16);
        asm volatile("s_waitcnt vmcnt(0)" ::: "memory");
        __builtin_amdgcn_sched_barrier(0);
        // scatter V^T (2-lanes/bank = free)
#pragma unroll
        for (int seg = 0; seg < 4; ++seg) {
            int c0 = vcb + seg * 8;
            u16* vv = (u16*)&vreg[seg];
#pragma unroll
            for (int j = 0; j < 8; ++j) VT[(c0 + j) * 72 + vr] = vv[j];
        }
        // B2: everyone's V writes + K gloads visible
        asm volatile("s_waitcnt lgkmcnt(0)" ::: "memory");
        __builtin_amdgcn_sched_barrier(0);
        __builtin_amdgcn_s_barrier();
        __builtin_amdgcn_sched_barrier(0);

        // ---- QK^T ----
        f32x4 sa[4];
#pragma unroll
        for (int cg = 0; cg < 4; ++cg) {
            sa[cg] = f32x4{0.f, 0.f, 0.f, 0.f};
            int row = cg * 16 + l15;
#pragma unroll
            for (int ks = 0; ks < 4; ++ks) {
                int chs = (ks * 4 + l4) ^ (row & 7);
                bf16x8 kf = *(const bf16x8*)&Klds[row * 128 + chs * 8];
                sa[cg] = __builtin_amdgcn_mfma_f32_16x16x32_bf16(qf[ks], kf, sa[cg], 0, 0, 0);
            }
        }
#pragma unroll
        for (int cg = 0; cg < 4; ++cg)
#pragma unroll
            for (int i = 0; i < 4; ++i) sa[cg][i] *= SCL2;
        if (kv0 + 63 > q0 + w * 16) {
#pragma unroll
            for (int cg = 0; cg < 4; ++cg) {
                int col = kv0 + cg * 16 + l15;
#pragma unroll
                for (int i = 0; i < 4; ++i) {
                    int qrow = q0 + w * 16 + l4 * 4 + i;
                    if (col > qrow) sa[cg][i] = -3.0e38f;
                }
            }
        }
        // ---- online softmax (log2 domain, defer-max) ----
        float mx[4];
#pragma unroll
        for (int i = 0; i < 4; ++i) {
            float m0 = fmaxf(fmaxf(sa[0][i], sa[1][i]), fmaxf(sa[2][i], sa[3][i]));
            m0 = fmaxf(m0, __shfl_xor(m0, 1));
            m0 = fmaxf(m0, __shfl_xor(m0, 2));
            m0 = fmaxf(m0, __shfl_xor(m0, 4));
            m0 = fmaxf(m0, __shfl_xor(m0, 8));
            mx[i] = m0;
        }
        bool defer = __all((mx[0] <= m_i[0] + THR) & (mx[1] <= m_i[1] + THR) &
                           (mx[2] <= m_i[2] + THR) & (mx[3] <= m_i[3] + THR));
        float corr[4];
#pragma unroll
        for (int i = 0; i < 4; ++i) {
            float mnew = defer ? m_i[i] : fmaxf(m_i[i], mx[i]);
            corr[i] = __builtin_amdgcn_exp2f(m_i[i] - mnew);
            m_i[i] = mnew;
        }
#pragma unroll
        for (int i = 0; i < 4; ++i) {
            int prow = l4 * 4 + i;
            int sw = (prow >> 1) & 3;
            float rs = 0.f;
#pragma unroll
            for (int cg = 0; cg < 4; ++cg) {
                float p = __builtin_amdgcn_exp2f(sa[cg][i] - m_i[i]);
                rs += p;
                int ch = cg * 2 + (l15 >> 3);
                Pw[prow * 72 + ((ch ^ sw) << 3) + (l15 & 7)] = f2bf(p);
            }
            rs += __shfl_xor(rs, 1);
            rs += __shfl_xor(rs, 2);
            rs += __shfl_xor(rs, 4);
            rs += __shfl_xor(rs, 8);
            l_i[i] = l_i[i] * corr[i] + rs;
        }
        if (!defer) {
#pragma unroll
            for (int nf = 0; nf < 8; ++nf) {
                o[nf][0] *= corr[0]; o[nf][1] *= corr[1];
                o[nf][2] *= corr[2]; o[nf][3] *= corr[3];
            }
        }
        // ---- PV: P + V from LDS (b128 reads) ----
        asm volatile("s_waitcnt lgkmcnt(0)" ::: "memory");
        __builtin_amdgcn_sched_barrier(0);
#pragma unroll
        for (int kst = 0; kst < 2; ++kst) {
            int pchs = (kst * 4 + l4) ^ ((l15 >> 1) & 3);
            bf16x8 pf = *(const bf16x8*)&Pw[l15 * 72 + pchs * 8];
#pragma unroll
            for (int nf = 0; nf < 8; ++nf) {
                bf16x8 vf = *(const bf16x8*)&VT[(nf * 16 + l15) * 72 + kst * 32 + l4 * 8];
                o[nf] = __builtin_amdgcn_mfma_f32_16x16x32_bf16(pf, vf, o[nf], 0, 0, 0);
            }
        }
    }
    float inv[4];
#pragma unroll
    for (int i = 0; i < 4; ++i) inv[i] = 1.0f / l_i[i];
#pragma unroll
    for (int nf = 0; nf < 8; ++nf)
#pragma unroll
        for (int i = 0; i < 4; ++i) {
            int qrow = q0 + w * 16 + l4 * 4 + i;
            ctx[(size_t)qrow * 4096 + h * 128 + nf * 16 + l15] = f2bf(o[nf][i] * inv[i]);
        }
}

extern "C" void kernel_launch(void* const* d_in, const int* in_sizes, int n_in,
                              void* d_out, int out_size, void* d_ws, size_t ws_size,
                              hipStream_t stream) {
    const float* hidden = (const float*)d_in[0];   // fp32 (per reference dtype)
    // d_in[1] = sequence_mask (unused by reference math: all-ones + causal)
    const float* Wqkv = (const float*)d_in[2];     // fp32
    const float* Wo = (const float*)d_in[3];       // fp32
    float* out = (float*)d_out;                    // fp32 output
    char* ws = (char*)d_ws;

    // ws layout (bytes) with verified liveness (no overlapping live intervals):
    u16* WqkvT   = (u16*)(ws + 0);           // transpose1 -> gemm1
    u16* Qb      = (u16*)(ws + 0);           // repack -> attn (WqkvT dead)
    u16* Kb      = (u16*)(ws + 16777216);
    u16* Vb      = (u16*)(ws + 20971520);
    u16* WoT     = (u16*)(ws + 25165824);    // transposeWo -> gemm2
    u16* QKV     = (u16*)(ws + 50331648);    // gemm1 -> repack
    u16* ctx     = (u16*)(ws + 58720256);    // attn -> gemm2
    float* tab   = (float*)(ws + 75497472);  // rope -> repack
    u16* hiddenB = (u16*)(ws + 76546048);    // cast -> gemm1

    rope_table_k<<<512, 256, 0, stream>>>(tab);
    cast_k<<<8192, 256, 0, stream>>>(hidden, hiddenB, 2048 * 4096 / 4);
    transpose_cast_k<<<dim3(96, 64), 256, 0, stream>>>(Wqkv, WqkvT, 4096, 6144);
    gemm_pipe_k<3, false><<<512, 512, 0, stream>>>(hiddenB, WqkvT, QKV, 6144, 4096);
    repack_rope_k<<<6144, 256, 0, stream>>>(QKV, tab, Qb, Kb, Vb);
    transpose_cast_k<<<dim3(64, 64), 256, 0, stream>>>(Wo, WoT, 4096, 4096);
    attn_k<<<dim3(32, 32), 256, 0, stream>>>(Qb, Kb, Vb, ctx);
    gemm_pipe_k<2, true><<<512, 512, 0, stream>>>(ctx, WoT, out, 4096, 4096);
}

// Round 11
// 398.382 us; speedup vs baseline: 1.2518x; 1.2518x over previous
//
#include <hip/hip_runtime.h>

typedef unsigned short u16;
typedef __bf16 bf16x8 __attribute__((ext_vector_type(8)));
typedef float f32x4 __attribute__((ext_vector_type(4)));
typedef u16 u16x4 __attribute__((ext_vector_type(4)));

constexpr int SEQ = 2048;
constexpr int NQKV = 6144; // (32 + 2*8) * 128

__device__ __forceinline__ float bf2f(u16 x) {
    unsigned int u = ((unsigned int)x) << 16;
    return __builtin_bit_cast(float, u);
}
__device__ __forceinline__ u16 f2bf(float f) {
    unsigned int u = __builtin_bit_cast(unsigned int, f);
    u += 0x7FFF + ((u >> 16) & 1);
    return (u16)(u >> 16);
}

__device__ __forceinline__ void gload16(const void* g, void* l) {
    void* gg = const_cast<void*>(g);
    __builtin_amdgcn_global_load_lds(
        (__attribute__((address_space(1))) void*)gg,
        (__attribute__((address_space(3))) void*)l, 16, 0, 0);
}

// counted-vmcnt gate + raw barrier (NO vmcnt(0) drain in steady state)
__device__ __forceinline__ void gatebar(int G) {
    if (G == 4) asm volatile("s_waitcnt vmcnt(4)" ::: "memory");
    else if (G == 3) asm volatile("s_waitcnt vmcnt(3)" ::: "memory");
    else if (G == 2) asm volatile("s_waitcnt vmcnt(2)" ::: "memory");
    else asm volatile("s_waitcnt vmcnt(0)" ::: "memory");
    __builtin_amdgcn_sched_barrier(0);
    __builtin_amdgcn_s_barrier();
    __builtin_amdgcn_sched_barrier(0);
}

// ---------------- RoPE table ----------------
__global__ void rope_table_k(float* __restrict__ tab) {
    int idx = blockIdx.x * 256 + threadIdx.x;
    if (idx >= SEQ * 64) return;
    int s = idx >> 6;
    int i = idx & 63;
    float invf = expf(-(float)i * (float)(1.0 / 64.0) * logf(10000.0f));
    float ang = (float)s * invf;
    float sv, cv;
    sincosf(ang, &sv, &cv);
    tab[idx * 2] = cv;
    tab[idx * 2 + 1] = sv;
}

// ---------------- fp32 -> bf16 elementwise cast ----------------
__global__ __launch_bounds__(256) void cast_k(const float* __restrict__ src,
                                              u16* __restrict__ dst, int n4) {
    int i = blockIdx.x * 256 + threadIdx.x;
    if (i >= n4) return;
    f32x4 v = *(const f32x4*)&src[(size_t)i * 4];
    u16x4 o;
#pragma unroll
    for (int j = 0; j < 4; ++j) o[j] = f2bf(v[j]);
    *(u16x4*)&dst[(size_t)i * 4] = o;
}

// ---------------- fp32 transpose+cast (R x C fp32 -> C x R bf16) ----------------
__global__ __launch_bounds__(256) void transpose_cast_k(const float* __restrict__ src,
                                                        u16* __restrict__ dst, int R, int C) {
    __shared__ u16 tile[64][65];
    int t = threadIdx.x;
    int bx = blockIdx.x, by = blockIdx.y;
    int r0 = by * 64, c0 = bx * 64;
#pragma unroll
    for (int it = 0; it < 4; ++it) {
        int row = it * 16 + (t >> 4);
        int col = (t & 15) * 4;
        f32x4 v = *(const f32x4*)&src[(size_t)(r0 + row) * C + c0 + col];
        tile[row][col] = f2bf(v[0]); tile[row][col + 1] = f2bf(v[1]);
        tile[row][col + 2] = f2bf(v[2]); tile[row][col + 3] = f2bf(v[3]);
    }
    __syncthreads();
#pragma unroll
    for (int it = 0; it < 4; ++it) {
        int orow = it * 16 + (t >> 4);
        int ocol = (t & 15) * 4;
        u16x4 v;
        v[0] = tile[ocol][orow]; v[1] = tile[ocol + 1][orow];
        v[2] = tile[ocol + 2][orow]; v[3] = tile[ocol + 3][orow];
        *(u16x4*)&dst[(size_t)(c0 + orow) * R + r0 + ocol] = v;
    }
}

// ---- pipelined GEMM: C[M,N] = A[M,K] * BT[N,K]^T, bf16 in, fp32 acc ----
template <int NF, bool F32OUT>
__global__ __launch_bounds__(512, 4) void gemm_pipe_k(const u16* __restrict__ A,
                                                      const u16* __restrict__ BT,
                                                      void* __restrict__ Cv, int N, int K) {
    constexpr int BN = NF * 64;
    constexpr int SA = 128 * 64;
    constexpr int SB = BN * 64;
    constexpr int SBUF = SA + SB;
    __shared__ alignas(16) char lds[3 * SBUF];

    int t = threadIdx.x;
    int lane = t & 63, w = t >> 6;
    int wr = w >> 2, wc = w & 3;
    int l15 = lane & 15, l4 = lane >> 4;

    int nbn = N / BN;
    int wg = blockIdx.x;
    int cpx = gridDim.x >> 3;
    int swz = (wg & 7) * cpx + (wg >> 3);
    int bm = swz / nbn, bn = swz % nbn;

    const u16* Ab = A + (size_t)bm * 128 * K;
    const u16* Bb = BT + (size_t)bn * BN * K;

    int ar = t >> 2;
    int akc = (t & 3) ^ ((ar >> 1) & 3);
    const u16* ga = Ab + (size_t)ar * K + akc * 8;
    int br0 = t >> 2;
    int bk0 = (t & 3) ^ ((br0 >> 1) & 3);
    const u16* gb0 = Bb + (size_t)br0 * K + bk0 * 8;
    int bc1 = 512 + t;
    int br1 = bc1 >> 2;
    int bk1 = (bc1 & 3) ^ ((br1 >> 1) & 3);
    const u16* gb1 = Bb + (size_t)br1 * K + bk1 * 8;
    bool hasB1 = (NF == 3) && (w < 4);
    int myG = (NF == 3) ? ((w < 4) ? 3 : 2) : 2;

    auto stage = [&](int v) {
        int b = v - (v / 3) * 3;
        char* LA = lds + b * SBUF;
        char* LB = LA + SA;
        int ko = v * 32;
        gload16(ga + ko, LA + t * 16);
        gload16(gb0 + ko, LB + t * 16);
        if (NF == 3) {
            if (hasB1) gload16(gb1 + ko, LB + bc1 * 16);
        }
    };

    f32x4 acc[4][NF];
#pragma unroll
    for (int i = 0; i < 4; ++i)
#pragma unroll
        for (int j = 0; j < NF; ++j) acc[i][j] = f32x4{0.f, 0.f, 0.f, 0.f};

    int arow[4], akk[4];
#pragma unroll
    for (int fm = 0; fm < 4; ++fm) {
        arow[fm] = wr * 64 + fm * 16 + l15;
        akk[fm] = l4 ^ ((arow[fm] >> 1) & 3);
    }
    int brow[NF], bkk[NF];
#pragma unroll
    for (int fn = 0; fn < NF; ++fn) {
        brow[fn] = wc * (NF * 16) + fn * 16 + l15;
        bkk[fn] = l4 ^ ((brow[fn] >> 1) & 3);
    }

    int nk = K >> 5;
    stage(0);
    stage(1);
    gatebar(myG);

    int b = 0;
    for (int v = 0; v < nk; ++v) {
        const u16* LA = (const u16*)(lds + b * SBUF);
        const u16* LB = LA + SA / 2;
        if (v + 2 < nk) stage(v + 2);
        bf16x8 bf[NF];
#pragma unroll
        for (int fn = 0; fn < NF; ++fn)
            bf[fn] = *(const bf16x8*)&LB[brow[fn] * 32 + bkk[fn] * 8];
        __builtin_amdgcn_s_setprio(1);
#pragma unroll
        for (int fm = 0; fm < 4; ++fm) {
            bf16x8 af = *(const bf16x8*)&LA[arow[fm] * 32 + akk[fm] * 8];
#pragma unroll
            for (int fn = 0; fn < NF; ++fn)
                acc[fm][fn] = __builtin_amdgcn_mfma_f32_16x16x32_bf16(af, bf[fn],
                                                                     acc[fm][fn], 0, 0, 0);
        }
        __builtin_amdgcn_s_setprio(0);
        if (v < nk - 1) gatebar((v + 2 < nk) ? myG : 0);
        b = (b == 2) ? 0 : b + 1;
    }

#pragma unroll
    for (int fm = 0; fm < 4; ++fm)
#pragma unroll
        for (int fn = 0; fn < NF; ++fn)
#pragma unroll
            for (int i = 0; i < 4; ++i) {
                int row = bm * 128 + wr * 64 + fm * 16 + l4 * 4 + i;
                int col = bn * BN + wc * (NF * 16) + fn * 16 + l15;
                if constexpr (F32OUT)
                    ((float*)Cv)[(size_t)row * N + col] = acc[fm][fn][i];
                else
                    ((u16*)Cv)[(size_t)row * N + col] = f2bf(acc[fm][fn][i]);
            }
}

// -------- repack + RoPE (vectorized): QKV[s,6144] -> Q[h,s,d], K[hk,s,d], V[hk,s,d] --------
__global__ __launch_bounds__(256) void repack_rope_k(const u16* __restrict__ QKV,
                                                     const float* __restrict__ tab,
                                                     u16* __restrict__ Qo, u16* __restrict__ Ko,
                                                     u16* __restrict__ Vo) {
    int idx = blockIdx.x * 256 + threadIdx.x; // < SEQ*48*16
    int i4 = (idx & 15) * 4;
    int su = idx >> 4;
    int u = su % 48;
    int s = su / 48;
    if (u < 40) {
        const float* tp = tab + (s * 64 + i4) * 2;
        f32x4 t0 = *(const f32x4*)tp;
        f32x4 t1 = *(const f32x4*)(tp + 4);
        float cv[4] = {t0[0], t0[2], t1[0], t1[2]};
        float sv[4] = {t0[1], t0[3], t1[1], t1[3]};
        const u16* base;
        u16* ob;
        if (u < 32) {
            base = QKV + (size_t)s * NQKV + u * 128;
            ob = Qo + ((size_t)u * SEQ + s) * 128;
        } else {
            base = QKV + (size_t)s * NQKV + 4096 + (u - 32) * 128;
            ob = Ko + ((size_t)(u - 32) * SEQ + s) * 128;
        }
        u16x4 x1 = *(const u16x4*)(base + i4);
        u16x4 x2 = *(const u16x4*)(base + 64 + i4);
        u16x4 o1, o2;
#pragma unroll
        for (int j = 0; j < 4; ++j) {
            float a = bf2f(x1[j]), b = bf2f(x2[j]);
            o1[j] = f2bf(a * cv[j] - b * sv[j]);
            o2[j] = f2bf(b * cv[j] + a * sv[j]);
        }
        *(u16x4*)(ob + i4) = o1;
        *(u16x4*)(ob + 64 + i4) = o2;
    } else {
        int hv = u - 40;
        const u16* base = QKV + (size_t)s * NQKV + 5120 + hv * 128;
        u16* ob = Vo + ((size_t)hv * SEQ + s) * 128;
        *(u16x4*)(ob + i4) = *(const u16x4*)(base + i4);
        *(u16x4*)(ob + 64 + i4) = *(const u16x4*)(base + 64 + i4);
    }
}

// ------- causal GQA flash attention: 512 threads / 8 waves / 128-row q-blocks,
// ------- paired {bx, 15-bx} (34 uniform tiles), double-buffered prefetch (R9 schedule) ----
__global__ __launch_bounds__(512) void attn_k(const u16* __restrict__ Qg,
                                              const u16* __restrict__ Kg,
                                              const u16* __restrict__ Vg,
                                              u16* __restrict__ ctx) {
    constexpr float SCL2 = 0.08838834764831845f * 1.44269504088896340736f; // 1/sqrt(128)*log2e
    constexpr float THR = 11.5f;
    __shared__ alignas(16) u16 Klds[2][64 * 128];   // 2 x 16 KB, XOR-swizzled rows
    __shared__ alignas(16) u16 VT[2][128 * 72];     // 2 x 18 KB, V^T stride 72
    __shared__ alignas(16) u16 Plds[8 * 16 * 72];   // 18 KB, per-wave P (stride 72)

    int t = threadIdx.x;
    int lane = t & 63, w = t >> 6;       // 8 waves
    int l15 = lane & 15, l4 = lane >> 4;
    int bx = blockIdx.x;                 // 0..7
    int h = blockIdx.y, hkv = h >> 2;
    const u16* Kh = Kg + (size_t)hkv * SEQ * 128;
    const u16* Vh = Vg + (size_t)hkv * SEQ * 128;
    u16* Pw = &Plds[w * 1152];

    // K staging: 2 chunks/thread; slots c = t + i*512, row kr, swizzled chunk
    int kr[2], kchs[2];
#pragma unroll
    for (int i2 = 0; i2 < 2; ++i2) {
        int c = t + i2 * 512;
        kr[i2] = c >> 4;
        kchs[i2] = (c & 15) ^ (kr[i2] & 7);
    }
    int vr = lane, vcb = (t >> 6) * 16;  // V: row=lane, 16-col group per wave

    int q0 = bx * 128;        // member A; member B = (15-bx)*128
    int ntA = 2 * bx + 2;     // A tiles; B has 32-2bx; total 34

    bf16x8 qf[4], vreg[2];
    f32x4 o[8];
    float m_i[4], l_i[4];

    auto kvbase = [&](int tt) { return (tt < ntA ? tt : tt - ntA) << 6; };
    auto load_q = [&]() {
        const u16* Qh = Qg + ((size_t)h * SEQ + q0 + w * 16 + l15) * 128;
#pragma unroll
        for (int ks = 0; ks < 4; ++ks) qf[ks] = *(const bf16x8*)(Qh + ks * 32 + l4 * 8);
    };
    auto reset_acc = [&]() {
#pragma unroll
        for (int nf = 0; nf < 8; ++nf) o[nf] = f32x4{0.f, 0.f, 0.f, 0.f};
#pragma unroll
        for (int i = 0; i < 4; ++i) { m_i[i] = -3.0e38f; l_i[i] = 0.f; }
    };
    auto write_ctx = [&]() {
        float inv[4];
#pragma unroll
        for (int i = 0; i < 4; ++i) inv[i] = 1.0f / l_i[i];
#pragma unroll
        for (int nf = 0; nf < 8; ++nf)
#pragma unroll
            for (int i = 0; i < 4; ++i) {
                int qrow = q0 + w * 16 + l4 * 4 + i;
                ctx[(size_t)qrow * 4096 + h * 128 + nf * 16 + l15] = f2bf(o[nf][i] * inv[i]);
            }
    };
    auto loadV = [&](int tt) {  // issue FIRST so K gloads are newest in FIFO
        const u16* Vt = Vh + (size_t)kvbase(tt) * 128;
#pragma unroll
        for (int seg = 0; seg < 2; ++seg)
            vreg[seg] = *(const bf16x8*)(Vt + (size_t)vr * 128 + vcb + seg * 8);
    };
    auto stageK = [&](int tt) {
        const u16* Kt = Kh + (size_t)kvbase(tt) * 128;
        char* kb = (char*)Klds[tt & 1];
#pragma unroll
        for (int i2 = 0; i2 < 2; ++i2)
            gload16(Kt + kr[i2] * 128 + kchs[i2] * 8, kb + (size_t)(t + i2 * 512) * 16);
    };
    auto writeV = [&](int tt) {
        u16* vb = VT[tt & 1];
#pragma unroll
        for (int seg = 0; seg < 2; ++seg) {
            int c0 = vcb + seg * 8;
            u16* vv = (u16*)&vreg[seg];
#pragma unroll
            for (int j = 0; j < 8; ++j) vb[(c0 + j) * 72 + vr] = vv[j];
        }
    };

    load_q();
    reset_acc();
    loadV(0);
    stageK(0);
    asm volatile("s_waitcnt vmcnt(0)" ::: "memory");
    __builtin_amdgcn_sched_barrier(0);
    writeV(0);

    for (int tt = 0; tt < 34; ++tt) {
        // B1: own LDS ops drained + all waves done compute(tt-1); V(tt) writes visible
        asm volatile("s_waitcnt lgkmcnt(0)" ::: "memory");
        __builtin_amdgcn_sched_barrier(0);
        __builtin_amdgcn_s_barrier();
        __builtin_amdgcn_sched_barrier(0);
        bool nxt = (tt + 1 < 34);
        if (nxt) {
            loadV(tt + 1);   // 2 VMEM (reg)
            stageK(tt + 1);  // 2 VMEM (lds), newest
        }
        gatebar(nxt ? 4 : 0); // B2: K(tt) landed for all waves; tt+1 loads in flight
        if (tt == ntA) { // finish member A, switch to member B
            write_ctx();
            q0 = (15 - bx) * 128;
            load_q();
            reset_acc();
        }

        int b = tt & 1;
        int kv0 = kvbase(tt);
        const u16* KL = Klds[b];

        // ---- QK^T ----
        f32x4 sa[4];
#pragma unroll
        for (int cg = 0; cg < 4; ++cg) {
            sa[cg] = f32x4{0.f, 0.f, 0.f, 0.f};
            int row = cg * 16 + l15;
#pragma unroll
            for (int ks = 0; ks < 4; ++ks) {
                int chs = (ks * 4 + l4) ^ (row & 7);
                bf16x8 kf = *(const bf16x8*)&KL[row * 128 + chs * 8];
                sa[cg] = __builtin_amdgcn_mfma_f32_16x16x32_bf16(qf[ks], kf, sa[cg], 0, 0, 0);
            }
        }
#pragma unroll
        for (int cg = 0; cg < 4; ++cg)
#pragma unroll
            for (int i = 0; i < 4; ++i) sa[cg][i] *= SCL2;
        if (kv0 + 63 > q0 + w * 16) {
#pragma unroll
            for (int cg = 0; cg < 4; ++cg) {
                int col = kv0 + cg * 16 + l15;
#pragma unroll
                for (int i = 0; i < 4; ++i) {
                    int qrow = q0 + w * 16 + l4 * 4 + i;
                    if (col > qrow) sa[cg][i] = -3.0e38f;
                }
            }
        }
        // ---- online softmax (log2 domain, defer-max) ----
        float mx[4];
#pragma unroll
        for (int i = 0; i < 4; ++i) {
            float m0 = fmaxf(fmaxf(sa[0][i], sa[1][i]), fmaxf(sa[2][i], sa[3][i]));
            m0 = fmaxf(m0, __shfl_xor(m0, 1));
            m0 = fmaxf(m0, __shfl_xor(m0, 2));
            m0 = fmaxf(m0, __shfl_xor(m0, 4));
            m0 = fmaxf(m0, __shfl_xor(m0, 8));
            mx[i] = m0;
        }
        bool defer = __all((mx[0] <= m_i[0] + THR) & (mx[1] <= m_i[1] + THR) &
                           (mx[2] <= m_i[2] + THR) & (mx[3] <= m_i[3] + THR));
        float corr[4];
#pragma unroll
        for (int i = 0; i < 4; ++i) {
            float mnew = defer ? m_i[i] : fmaxf(m_i[i], mx[i]);
            corr[i] = __builtin_amdgcn_exp2f(m_i[i] - mnew);
            m_i[i] = mnew;
        }
        // write V(tt+1) into the other buffer (V global latency hidden under QK^T)
        if (nxt) writeV(tt + 1);
#pragma unroll
        for (int i = 0; i < 4; ++i) {
            int prow = l4 * 4 + i;
            int sw = (prow >> 1) & 3;
            float rs = 0.f;
#pragma unroll
            for (int cg = 0; cg < 4; ++cg) {
                float p = __builtin_amdgcn_exp2f(sa[cg][i] - m_i[i]);
                rs += p;
                int ch = cg * 2 + (l15 >> 3);
                Pw[prow * 72 + ((ch ^ sw) << 3) + (l15 & 7)] = f2bf(p);
            }
            rs += __shfl_xor(rs, 1);
            rs += __shfl_xor(rs, 2);
            rs += __shfl_xor(rs, 4);
            rs += __shfl_xor(rs, 8);
            l_i[i] = l_i[i] * corr[i] + rs;
        }
        if (!defer) {
#pragma unroll
            for (int nf = 0; nf < 8; ++nf) {
                o[nf][0] *= corr[0]; o[nf][1] *= corr[1];
                o[nf][2] *= corr[2]; o[nf][3] *= corr[3];
            }
        }
        // ---- PV: P + V from LDS (b128 reads, 2-way free conflicts) ----
        asm volatile("s_waitcnt lgkmcnt(0)" ::: "memory");
        __builtin_amdgcn_sched_barrier(0);
#pragma unroll
        for (int kst = 0; kst < 2; ++kst) {
            int pchs = (kst * 4 + l4) ^ ((l15 >> 1) & 3);
            bf16x8 pf = *(const bf16x8*)&Pw[l15 * 72 + pchs * 8];
#pragma unroll
            for (int nf = 0; nf < 8; ++nf) {
                bf16x8 vf = *(const bf16x8*)&VT[b][(nf * 16 + l15) * 72 + kst * 32 + l4 * 8];
                o[nf] = __builtin_amdgcn_mfma_f32_16x16x32_bf16(pf, vf, o[nf], 0, 0, 0);
            }
        }
    }
    write_ctx();
}

extern "C" void kernel_launch(void* const* d_in, const int* in_sizes, int n_in,
                              void* d_out, int out_size, void* d_ws, size_t ws_size,
                              hipStream_t stream) {
    const float* hidden = (const float*)d_in[0];   // fp32 (per reference dtype)
    // d_in[1] = sequence_mask (unused by reference math: all-ones + causal)
    const float* Wqkv = (const float*)d_in[2];     // fp32
    const float* Wo = (const float*)d_in[3];       // fp32
    float* out = (float*)d_out;                    // fp32 output
    char* ws = (char*)d_ws;

    // ws layout (bytes) with verified liveness (no overlapping live intervals):
    u16* WqkvT   = (u16*)(ws + 0);           // transpose1 -> gemm1
    u16* Qb      = (u16*)(ws + 0);           // repack -> attn (WqkvT dead)
    u16* Kb      = (u16*)(ws + 16777216);
    u16* Vb      = (u16*)(ws + 20971520);
    u16* WoT     = (u16*)(ws + 25165824);    // transposeWo -> gemm2
    u16* QKV     = (u16*)(ws + 50331648);    // gemm1 -> repack
    u16* ctx     = (u16*)(ws + 58720256);    // attn -> gemm2
    float* tab   = (float*)(ws + 75497472);  // rope -> repack
    u16* hiddenB = (u16*)(ws + 76546048);    // cast -> gemm1

    rope_table_k<<<512, 256, 0, stream>>>(tab);
    cast_k<<<8192, 256, 0, stream>>>(hidden, hiddenB, 2048 * 4096 / 4);
    transpose_cast_k<<<dim3(96, 64), 256, 0, stream>>>(Wqkv, WqkvT, 4096, 6144);
    gemm_pipe_k<3, false><<<512, 512, 0, stream>>>(hiddenB, WqkvT, QKV, 6144, 4096);
    repack_rope_k<<<6144, 256, 0, stream>>>(QKV, tab, Qb, Kb, Vb);
    transpose_cast_k<<<dim3(64, 64), 256, 0, stream>>>(Wo, WoT, 4096, 4096);
    attn_k<<<dim3(8, 32), 512, 0, stream>>>(Qb, Kb, Vb, ctx);
    gemm_pipe_k<2, true><<<512, 512, 0, stream>>>(ctx, WoT, out, 4096, 4096);
}

// Round 13
// 378.152 us; speedup vs baseline: 1.3187x; 1.0535x over previous
//
#include <hip/hip_runtime.h>

typedef unsigned short u16;
typedef __bf16 bf16x8 __attribute__((ext_vector_type(8)));
typedef float f32x4 __attribute__((ext_vector_type(4)));
typedef u16 u16x4 __attribute__((ext_vector_type(4)));

constexpr int SEQ = 2048;
constexpr int NQKV = 6144; // (32 + 2*8) * 128

__device__ __forceinline__ float bf2f(u16 x) {
    unsigned int u = ((unsigned int)x) << 16;
    return __builtin_bit_cast(float, u);
}
__device__ __forceinline__ u16 f2bf(float f) {
    unsigned int u = __builtin_bit_cast(unsigned int, f);
    u += 0x7FFF + ((u >> 16) & 1);
    return (u16)(u >> 16);
}

__device__ __forceinline__ void gload16(const void* g, void* l) {
    void* gg = const_cast<void*>(g);
    __builtin_amdgcn_global_load_lds(
        (__attribute__((address_space(1))) void*)gg,
        (__attribute__((address_space(3))) void*)l, 16, 0, 0);
}

// counted-vmcnt gate + raw barrier (NO vmcnt(0) drain in steady state)
__device__ __forceinline__ void gatebar(int G) {
    if (G == 4) asm volatile("s_waitcnt vmcnt(4)" ::: "memory");
    else if (G == 3) asm volatile("s_waitcnt vmcnt(3)" ::: "memory");
    else if (G == 2) asm volatile("s_waitcnt vmcnt(2)" ::: "memory");
    else asm volatile("s_waitcnt vmcnt(0)" ::: "memory");
    __builtin_amdgcn_sched_barrier(0);
    __builtin_amdgcn_s_barrier();
    __builtin_amdgcn_sched_barrier(0);
}

// ---------------- RoPE table ----------------
__global__ void rope_table_k(float* __restrict__ tab) {
    int idx = blockIdx.x * 256 + threadIdx.x;
    if (idx >= SEQ * 64) return;
    int s = idx >> 6;
    int i = idx & 63;
    float invf = expf(-(float)i * (float)(1.0 / 64.0) * logf(10000.0f));
    float ang = (float)s * invf;
    float sv, cv;
    sincosf(ang, &sv, &cv);
    tab[idx * 2] = cv;
    tab[idx * 2 + 1] = sv;
}

// ---------------- fp32 -> bf16 elementwise cast ----------------
__global__ __launch_bounds__(256) void cast_k(const float* __restrict__ src,
                                              u16* __restrict__ dst, int n4) {
    int i = blockIdx.x * 256 + threadIdx.x;
    if (i >= n4) return;
    f32x4 v = *(const f32x4*)&src[(size_t)i * 4];
    u16x4 o;
#pragma unroll
    for (int j = 0; j < 4; ++j) o[j] = f2bf(v[j]);
    *(u16x4*)&dst[(size_t)i * 4] = o;
}

// ---------------- fp32 transpose+cast (R x C fp32 -> C x R bf16) ----------------
__global__ __launch_bounds__(256) void transpose_cast_k(const float* __restrict__ src,
                                                        u16* __restrict__ dst, int R, int C) {
    __shared__ u16 tile[64][65];
    int t = threadIdx.x;
    int bx = blockIdx.x, by = blockIdx.y;
    int r0 = by * 64, c0 = bx * 64;
#pragma unroll
    for (int it = 0; it < 4; ++it) {
        int row = it * 16 + (t >> 4);
        int col = (t & 15) * 4;
        f32x4 v = *(const f32x4*)&src[(size_t)(r0 + row) * C + c0 + col];
        tile[row][col] = f2bf(v[0]); tile[row][col + 1] = f2bf(v[1]);
        tile[row][col + 2] = f2bf(v[2]); tile[row][col + 3] = f2bf(v[3]);
    }
    __syncthreads();
#pragma unroll
    for (int it = 0; it < 4; ++it) {
        int orow = it * 16 + (t >> 4);
        int ocol = (t & 15) * 4;
        u16x4 v;
        v[0] = tile[ocol][orow]; v[1] = tile[ocol + 1][orow];
        v[2] = tile[ocol + 2][orow]; v[3] = tile[ocol + 3][orow];
        *(u16x4*)&dst[(size_t)(c0 + orow) * R + r0 + ocol] = v;
    }
}

// ---- pipelined GEMM: C[M,N] = A[M,K] * BT[N,K]^T, bf16 in, fp32 acc ----
template <int NF, bool F32OUT>
__global__ __launch_bounds__(512, 4) void gemm_pipe_k(const u16* __restrict__ A,
                                                      const u16* __restrict__ BT,
                                                      void* __restrict__ Cv, int N, int K) {
    constexpr int BN = NF * 64;
    constexpr int SA = 128 * 64;
    constexpr int SB = BN * 64;
    constexpr int SBUF = SA + SB;
    __shared__ alignas(16) char lds[3 * SBUF];

    int t = threadIdx.x;
    int lane = t & 63, w = t >> 6;
    int wr = w >> 2, wc = w & 3;
    int l15 = lane & 15, l4 = lane >> 4;

    int nbn = N / BN;
    int wg = blockIdx.x;
    int cpx = gridDim.x >> 3;
    int swz = (wg & 7) * cpx + (wg >> 3);
    int bm = swz / nbn, bn = swz % nbn;

    const u16* Ab = A + (size_t)bm * 128 * K;
    const u16* Bb = BT + (size_t)bn * BN * K;

    int ar = t >> 2;
    int akc = (t & 3) ^ ((ar >> 1) & 3);
    const u16* ga = Ab + (size_t)ar * K + akc * 8;
    int br0 = t >> 2;
    int bk0 = (t & 3) ^ ((br0 >> 1) & 3);
    const u16* gb0 = Bb + (size_t)br0 * K + bk0 * 8;
    int bc1 = 512 + t;
    int br1 = bc1 >> 2;
    int bk1 = (bc1 & 3) ^ ((br1 >> 1) & 3);
    const u16* gb1 = Bb + (size_t)br1 * K + bk1 * 8;
    bool hasB1 = (NF == 3) && (w < 4);
    int myG = (NF == 3) ? ((w < 4) ? 3 : 2) : 2;

    auto stage = [&](int v) {
        int b = v - (v / 3) * 3;
        char* LA = lds + b * SBUF;
        char* LB = LA + SA;
        int ko = v * 32;
        gload16(ga + ko, LA + t * 16);
        gload16(gb0 + ko, LB + t * 16);
        if (NF == 3) {
            if (hasB1) gload16(gb1 + ko, LB + bc1 * 16);
        }
    };

    f32x4 acc[4][NF];
#pragma unroll
    for (int i = 0; i < 4; ++i)
#pragma unroll
        for (int j = 0; j < NF; ++j) acc[i][j] = f32x4{0.f, 0.f, 0.f, 0.f};

    int arow[4], akk[4];
#pragma unroll
    for (int fm = 0; fm < 4; ++fm) {
        arow[fm] = wr * 64 + fm * 16 + l15;
        akk[fm] = l4 ^ ((arow[fm] >> 1) & 3);
    }
    int brow[NF], bkk[NF];
#pragma unroll
    for (int fn = 0; fn < NF; ++fn) {
        brow[fn] = wc * (NF * 16) + fn * 16 + l15;
        bkk[fn] = l4 ^ ((brow[fn] >> 1) & 3);
    }

    int nk = K >> 5;
    stage(0);
    stage(1);
    gatebar(myG);

    int b = 0;
    for (int v = 0; v < nk; ++v) {
        const u16* LA = (const u16*)(lds + b * SBUF);
        const u16* LB = LA + SA / 2;
        if (v + 2 < nk) stage(v + 2);
        bf16x8 bf[NF];
#pragma unroll
        for (int fn = 0; fn < NF; ++fn)
            bf[fn] = *(const bf16x8*)&LB[brow[fn] * 32 + bkk[fn] * 8];
        __builtin_amdgcn_s_setprio(1);
#pragma unroll
        for (int fm = 0; fm < 4; ++fm) {
            bf16x8 af = *(const bf16x8*)&LA[arow[fm] * 32 + akk[fm] * 8];
#pragma unroll
            for (int fn = 0; fn < NF; ++fn)
                acc[fm][fn] = __builtin_amdgcn_mfma_f32_16x16x32_bf16(af, bf[fn],
                                                                     acc[fm][fn], 0, 0, 0);
        }
        __builtin_amdgcn_s_setprio(0);
        if (v < nk - 1) gatebar((v + 2 < nk) ? myG : 0);
        b = (b == 2) ? 0 : b + 1;
    }

#pragma unroll
    for (int fm = 0; fm < 4; ++fm)
#pragma unroll
        for (int fn = 0; fn < NF; ++fn)
#pragma unroll
            for (int i = 0; i < 4; ++i) {
                int row = bm * 128 + wr * 64 + fm * 16 + l4 * 4 + i;
                int col = bn * BN + wc * (NF * 16) + fn * 16 + l15;
                if constexpr (F32OUT)
                    ((float*)Cv)[(size_t)row * N + col] = acc[fm][fn][i];
                else
                    ((u16*)Cv)[(size_t)row * N + col] = f2bf(acc[fm][fn][i]);
            }
}

// -------- repack + RoPE (vectorized): QKV[s,6144] -> Q[h,s,d], K[hk,s,d], V[hk,s,d] --------
__global__ __launch_bounds__(256) void repack_rope_k(const u16* __restrict__ QKV,
                                                     const float* __restrict__ tab,
                                                     u16* __restrict__ Qo, u16* __restrict__ Ko,
                                                     u16* __restrict__ Vo) {
    int idx = blockIdx.x * 256 + threadIdx.x; // < SEQ*48*16
    int i4 = (idx & 15) * 4;
    int su = idx >> 4;
    int u = su % 48;
    int s = su / 48;
    if (u < 40) {
        const float* tp = tab + (s * 64 + i4) * 2;
        f32x4 t0 = *(const f32x4*)tp;
        f32x4 t1 = *(const f32x4*)(tp + 4);
        float cv[4] = {t0[0], t0[2], t1[0], t1[2]};
        float sv[4] = {t0[1], t0[3], t1[1], t1[3]};
        const u16* base;
        u16* ob;
        if (u < 32) {
            base = QKV + (size_t)s * NQKV + u * 128;
            ob = Qo + ((size_t)u * SEQ + s) * 128;
        } else {
            base = QKV + (size_t)s * NQKV + 4096 + (u - 32) * 128;
            ob = Ko + ((size_t)(u - 32) * SEQ + s) * 128;
        }
        u16x4 x1 = *(const u16x4*)(base + i4);
        u16x4 x2 = *(const u16x4*)(base + 64 + i4);
        u16x4 o1, o2;
#pragma unroll
        for (int j = 0; j < 4; ++j) {
            float a = bf2f(x1[j]), b = bf2f(x2[j]);
            o1[j] = f2bf(a * cv[j] - b * sv[j]);
            o2[j] = f2bf(b * cv[j] + a * sv[j]);
        }
        *(u16x4*)(ob + i4) = o1;
        *(u16x4*)(ob + 64 + i4) = o2;
    } else {
        int hv = u - 40;
        const u16* base = QKV + (size_t)s * NQKV + 5120 + hv * 128;
        u16* ob = Vo + ((size_t)hv * SEQ + s) * 128;
        *(u16x4*)(ob + i4) = *(const u16x4*)(base + i4);
        *(u16x4*)(ob + 64 + i4) = *(const u16x4*)(base + 64 + i4);
    }
}

// ------- causal GQA flash attention: 512 threads / 8 waves / 128-row q-blocks,
// ------- paired {bx, 15-bx}, dbuf prefetch, SHUFFLE-FREE steady-state softmax -------
__global__ __launch_bounds__(512) void attn_k(const u16* __restrict__ Qg,
                                              const u16* __restrict__ Kg,
                                              const u16* __restrict__ Vg,
                                              u16* __restrict__ ctx) {
    constexpr float SCL2 = 0.08838834764831845f * 1.44269504088896340736f; // 1/sqrt(128)*log2e
    constexpr float THR = 11.5f;
    __shared__ alignas(16) u16 Klds[2][64 * 128];   // 2 x 16 KB, XOR-swizzled rows
    __shared__ alignas(16) u16 VT[2][128 * 72];     // 2 x 18 KB, V^T stride 72
    __shared__ alignas(16) u16 Plds[8 * 16 * 72];   // 18 KB, per-wave P (stride 72)

    int t = threadIdx.x;
    int lane = t & 63, w = t >> 6;       // 8 waves
    int l15 = lane & 15, l4 = lane >> 4;
    int bx = blockIdx.x;                 // 0..7
    int h = blockIdx.y, hkv = h >> 2;
    const u16* Kh = Kg + (size_t)hkv * SEQ * 128;
    const u16* Vh = Vg + (size_t)hkv * SEQ * 128;
    u16* Pw = &Plds[w * 1152];

    // K staging: 2 chunks/thread; slots c = t + i*512, row kr, swizzled chunk
    int kr[2], kchs[2];
#pragma unroll
    for (int i2 = 0; i2 < 2; ++i2) {
        int c = t + i2 * 512;
        kr[i2] = c >> 4;
        kchs[i2] = (c & 15) ^ (kr[i2] & 7);
    }
    int vr = lane, vcb = (t >> 6) * 16;  // V: row=lane, 16-col group per wave

    int q0 = bx * 128;        // member A; member B = (15-bx)*128
    int ntA = 2 * bx + 2;     // A tiles; B has 32-2bx; total 34

    bf16x8 qf[4], vreg[2];
    f32x4 o[8];
    float m_i[4], l_i[4];     // l_i = PER-LANE partial sums (reduced only at write_ctx)

    auto kvbase = [&](int tt) { return (tt < ntA ? tt : tt - ntA) << 6; };
    auto load_q = [&]() {
        const u16* Qh = Qg + ((size_t)h * SEQ + q0 + w * 16 + l15) * 128;
#pragma unroll
        for (int ks = 0; ks < 4; ++ks) qf[ks] = *(const bf16x8*)(Qh + ks * 32 + l4 * 8);
    };
    auto reset_acc = [&]() {
#pragma unroll
        for (int nf = 0; nf < 8; ++nf) o[nf] = f32x4{0.f, 0.f, 0.f, 0.f};
#pragma unroll
        for (int i = 0; i < 4; ++i) { m_i[i] = -3.0e38f; l_i[i] = 0.f; }
    };
    auto write_ctx = [&]() {
        float inv[4];
#pragma unroll
        for (int i = 0; i < 4; ++i) {
            float rs = l_i[i];          // reduce per-lane partials across l15 (once per q-tile)
            rs += __shfl_xor(rs, 1);
            rs += __shfl_xor(rs, 2);
            rs += __shfl_xor(rs, 4);
            rs += __shfl_xor(rs, 8);
            inv[i] = 1.0f / rs;
        }
#pragma unroll
        for (int nf = 0; nf < 8; ++nf)
#pragma unroll
            for (int i = 0; i < 4; ++i) {
                int qrow = q0 + w * 16 + l4 * 4 + i;
                ctx[(size_t)qrow * 4096 + h * 128 + nf * 16 + l15] = f2bf(o[nf][i] * inv[i]);
            }
    };
    auto loadV = [&](int tt) {  // issue FIRST so K gloads are newest in FIFO
        const u16* Vt = Vh + (size_t)kvbase(tt) * 128;
#pragma unroll
        for (int seg = 0; seg < 2; ++seg)
            vreg[seg] = *(const bf16x8*)(Vt + (size_t)vr * 128 + vcb + seg * 8);
    };
    auto stageK = [&](int tt) {
        const u16* Kt = Kh + (size_t)kvbase(tt) * 128;
        char* kb = (char*)Klds[tt & 1];
#pragma unroll
        for (int i2 = 0; i2 < 2; ++i2)
            gload16(Kt + kr[i2] * 128 + kchs[i2] * 8, kb + (size_t)(t + i2 * 512) * 16);
    };
    auto writeV = [&](int tt) {
        u16* vb = VT[tt & 1];
#pragma unroll
        for (int seg = 0; seg < 2; ++seg) {
            int c0 = vcb + seg * 8;
            u16* vv = (u16*)&vreg[seg];
#pragma unroll
            for (int j = 0; j < 8; ++j) vb[(c0 + j) * 72 + vr] = vv[j];
        }
    };

    load_q();
    reset_acc();
    loadV(0);
    stageK(0);
    asm volatile("s_waitcnt vmcnt(0)" ::: "memory");
    __builtin_amdgcn_sched_barrier(0);
    writeV(0);

    for (int tt = 0; tt < 34; ++tt) {
        // B1: own LDS ops drained + all waves done compute(tt-1); V(tt) writes visible
        asm volatile("s_waitcnt lgkmcnt(0)" ::: "memory");
        __builtin_amdgcn_sched_barrier(0);
        __builtin_amdgcn_s_barrier();
        __builtin_amdgcn_sched_barrier(0);
        bool nxt = (tt + 1 < 34);
        if (nxt) {
            loadV(tt + 1);   // 2 VMEM (reg)
            stageK(tt + 1);  // 2 VMEM (lds), newest
        }
        gatebar(nxt ? 4 : 0); // B2: K(tt) landed for all waves; tt+1 loads in flight
        if (tt == ntA) { // finish member A, switch to member B
            write_ctx();
            q0 = (15 - bx) * 128;
            load_q();
            reset_acc();
        }

        int b = tt & 1;
        int kv0 = kvbase(tt);
        const u16* KL = Klds[b];

        // ---- QK^T ----
        f32x4 sa[4];
#pragma unroll
        for (int cg = 0; cg < 4; ++cg) {
            sa[cg] = f32x4{0.f, 0.f, 0.f, 0.f};
            int row = cg * 16 + l15;
#pragma unroll
            for (int ks = 0; ks < 4; ++ks) {
                int chs = (ks * 4 + l4) ^ (row & 7);
                bf16x8 kf = *(const bf16x8*)&KL[row * 128 + chs * 8];
                sa[cg] = __builtin_amdgcn_mfma_f32_16x16x32_bf16(qf[ks], kf, sa[cg], 0, 0, 0);
            }
        }
#pragma unroll
        for (int cg = 0; cg < 4; ++cg)
#pragma unroll
            for (int i = 0; i < 4; ++i) sa[cg][i] *= SCL2;
        if (kv0 + 63 > q0 + w * 16) {
#pragma unroll
            for (int cg = 0; cg < 4; ++cg) {
                int col = kv0 + cg * 16 + l15;
#pragma unroll
                for (int i = 0; i < 4; ++i) {
                    int qrow = q0 + w * 16 + l4 * 4 + i;
                    if (col > qrow) sa[cg][i] = -3.0e38f;
                }
            }
        }
        // ---- online softmax: per-lane defer test, NO shuffles in steady state ----
        float lmx[4];
#pragma unroll
        for (int i = 0; i < 4; ++i)
            lmx[i] = fmaxf(fmaxf(sa[0][i], sa[1][i]), fmaxf(sa[2][i], sa[3][i]));
        bool defer = __all((lmx[0] <= m_i[0] + THR) & (lmx[1] <= m_i[1] + THR) &
                           (lmx[2] <= m_i[2] + THR) & (lmx[3] <= m_i[3] + THR));
        if (!defer) {
            float corr[4];
#pragma unroll
            for (int i = 0; i < 4; ++i) {
                float m0 = lmx[i];   // full row-max tree (rare path)
                m0 = fmaxf(m0, __shfl_xor(m0, 1));
                m0 = fmaxf(m0, __shfl_xor(m0, 2));
                m0 = fmaxf(m0, __shfl_xor(m0, 4));
                m0 = fmaxf(m0, __shfl_xor(m0, 8));
                float mnew = fmaxf(m_i[i], m0);
                corr[i] = __builtin_amdgcn_exp2f(m_i[i] - mnew);
                m_i[i] = mnew;
                l_i[i] *= corr[i];
            }
#pragma unroll
            for (int nf = 0; nf < 8; ++nf) {
                o[nf][0] *= corr[0]; o[nf][1] *= corr[1];
                o[nf][2] *= corr[2]; o[nf][3] *= corr[3];
            }
        }
        // write V(tt+1) into the other buffer (V global latency hidden under QK^T)
        if (nxt) writeV(tt + 1);
#pragma unroll
        for (int i = 0; i < 4; ++i) {
            int prow = l4 * 4 + i;
            int sw = (prow >> 1) & 3;
            float rs = 0.f;
#pragma unroll
            for (int cg = 0; cg < 4; ++cg) {
                float p = __builtin_amdgcn_exp2f(sa[cg][i] - m_i[i]);
                rs += p;
                int ch = cg * 2 + (l15 >> 3);
                Pw[prow * 72 + ((ch ^ sw) << 3) + (l15 & 7)] = f2bf(p);
            }
            l_i[i] += rs;   // per-lane partial; reduced once in write_ctx
        }
        // ---- PV: P + V from LDS (b128 reads, 2-way free conflicts) ----
        asm volatile("s_waitcnt lgkmcnt(0)" ::: "memory");
        __builtin_amdgcn_sched_barrier(0);
#pragma unroll
        for (int kst = 0; kst < 2; ++kst) {
            int pchs = (kst * 4 + l4) ^ ((l15 >> 1) & 3);
            bf16x8 pf = *(const bf16x8*)&Pw[l15 * 72 + pchs * 8];
#pragma unroll
            for (int nf = 0; nf < 8; ++nf) {
                bf16x8 vf = *(const bf16x8*)&VT[b][(nf * 16 + l15) * 72 + kst * 32 + l4 * 8];
                o[nf] = __builtin_amdgcn_mfma_f32_16x16x32_bf16(pf, vf, o[nf], 0, 0, 0);
            }
        }
    }
    write_ctx();
}

extern "C" void kernel_launch(void* const* d_in, const int* in_sizes, int n_in,
                              void* d_out, int out_size, void* d_ws, size_t ws_size,
                              hipStream_t stream) {
    const float* hidden = (const float*)d_in[0];   // fp32 (per reference dtype)
    // d_in[1] = sequence_mask (unused by reference math: all-ones + causal)
    const float* Wqkv = (const float*)d_in[2];     // fp32
    const float* Wo = (const float*)d_in[3];       // fp32
    float* out = (float*)d_out;                    // fp32 output
    char* ws = (char*)d_ws;

    // ws layout (bytes) with verified liveness (no overlapping live intervals):
    u16* WqkvT   = (u16*)(ws + 0);           // transpose1 -> gemm1
    u16* Qb      = (u16*)(ws + 0);           // repack -> attn (WqkvT dead)
    u16* Kb      = (u16*)(ws + 16777216);
    u16* Vb      = (u16*)(ws + 20971520);
    u16* WoT     = (u16*)(ws + 25165824);    // transposeWo -> gemm2
    u16* QKV     = (u16*)(ws + 50331648);    // gemm1 -> repack
    u16* ctx     = (u16*)(ws + 58720256);    // attn -> gemm2
    float* tab   = (float*)(ws + 75497472);  // rope -> repack
    u16* hiddenB = (u16*)(ws + 76546048);    // cast -> gemm1

    rope_table_k<<<512, 256, 0, stream>>>(tab);
    cast_k<<<8192, 256, 0, stream>>>(hidden, hiddenB, 2048 * 4096 / 4);
    transpose_cast_k<<<dim3(96, 64), 256, 0, stream>>>(Wqkv, WqkvT, 4096, 6144);
    gemm_pipe_k<3, false><<<512, 512, 0, stream>>>(hiddenB, WqkvT, QKV, 6144, 4096);
    repack_rope_k<<<6144, 256, 0, stream>>>(QKV, tab, Qb, Kb, Vb);
    transpose_cast_k<<<dim3(64, 64), 256, 0, stream>>>(Wo, WoT, 4096, 4096);
    attn_k<<<dim3(8, 32), 512, 0, stream>>>(Qb, Kb, Vb, ctx);
    gemm_pipe_k<2, true><<<512, 512, 0, stream>>>(ctx, WoT, out, 4096, 4096);
}

// Round 14
// 360.383 us; speedup vs baseline: 1.3838x; 1.0493x over previous
//
#include <hip/hip_runtime.h>

typedef unsigned short u16;
typedef __bf16 bf16x8 __attribute__((ext_vector_type(8)));
typedef float f32x4 __attribute__((ext_vector_type(4)));
typedef u16 u16x4 __attribute__((ext_vector_type(4)));

constexpr int SEQ = 2048;
constexpr int NQKV = 6144; // (32 + 2*8) * 128

__device__ __forceinline__ float bf2f(u16 x) {
    unsigned int u = ((unsigned int)x) << 16;
    return __builtin_bit_cast(float, u);
}
__device__ __forceinline__ u16 f2bf(float f) {
    unsigned int u = __builtin_bit_cast(unsigned int, f);
    u += 0x7FFF + ((u >> 16) & 1);
    return (u16)(u >> 16);
}

__device__ __forceinline__ void gload16(const void* g, void* l) {
    void* gg = const_cast<void*>(g);
    __builtin_amdgcn_global_load_lds(
        (__attribute__((address_space(1))) void*)gg,
        (__attribute__((address_space(3))) void*)l, 16, 0, 0);
}

// counted-vmcnt gate + raw barrier (NO vmcnt(0) drain in steady state)
__device__ __forceinline__ void gatebar(int G) {
    if (G == 4) asm volatile("s_waitcnt vmcnt(4)" ::: "memory");
    else if (G == 3) asm volatile("s_waitcnt vmcnt(3)" ::: "memory");
    else if (G == 2) asm volatile("s_waitcnt vmcnt(2)" ::: "memory");
    else asm volatile("s_waitcnt vmcnt(0)" ::: "memory");
    __builtin_amdgcn_sched_barrier(0);
    __builtin_amdgcn_s_barrier();
    __builtin_amdgcn_sched_barrier(0);
}

// ---------------- RoPE table ----------------
__global__ void rope_table_k(float* __restrict__ tab) {
    int idx = blockIdx.x * 256 + threadIdx.x;
    if (idx >= SEQ * 64) return;
    int s = idx >> 6;
    int i = idx & 63;
    float invf = expf(-(float)i * (float)(1.0 / 64.0) * logf(10000.0f));
    float ang = (float)s * invf;
    float sv, cv;
    sincosf(ang, &sv, &cv);
    tab[idx * 2] = cv;
    tab[idx * 2 + 1] = sv;
}

// ---------------- fp32 -> bf16 elementwise cast ----------------
__global__ __launch_bounds__(256) void cast_k(const float* __restrict__ src,
                                              u16* __restrict__ dst, int n4) {
    int i = blockIdx.x * 256 + threadIdx.x;
    if (i >= n4) return;
    f32x4 v = *(const f32x4*)&src[(size_t)i * 4];
    u16x4 o;
#pragma unroll
    for (int j = 0; j < 4; ++j) o[j] = f2bf(v[j]);
    *(u16x4*)&dst[(size_t)i * 4] = o;
}

// ---------------- fp32 transpose+cast (R x C fp32 -> C x R bf16) ----------------
__global__ __launch_bounds__(256) void transpose_cast_k(const float* __restrict__ src,
                                                        u16* __restrict__ dst, int R, int C) {
    __shared__ u16 tile[64][65];
    int t = threadIdx.x;
    int bx = blockIdx.x, by = blockIdx.y;
    int r0 = by * 64, c0 = bx * 64;
#pragma unroll
    for (int it = 0; it < 4; ++it) {
        int row = it * 16 + (t >> 4);
        int col = (t & 15) * 4;
        f32x4 v = *(const f32x4*)&src[(size_t)(r0 + row) * C + c0 + col];
        tile[row][col] = f2bf(v[0]); tile[row][col + 1] = f2bf(v[1]);
        tile[row][col + 2] = f2bf(v[2]); tile[row][col + 3] = f2bf(v[3]);
    }
    __syncthreads();
#pragma unroll
    for (int it = 0; it < 4; ++it) {
        int orow = it * 16 + (t >> 4);
        int ocol = (t & 15) * 4;
        u16x4 v;
        v[0] = tile[ocol][orow]; v[1] = tile[ocol + 1][orow];
        v[2] = tile[ocol + 2][orow]; v[3] = tile[ocol + 3][orow];
        *(u16x4*)&dst[(size_t)(c0 + orow) * R + r0 + ocol] = v;
    }
}

// ---- pipelined GEMM: C[M,N] = A[M,K] * BT[N,K]^T, bf16 in, fp32 acc ----
// XCD rectangle swizzle: each XCD owns an 8x8 block rectangle (bm x bn) so its
// private L2 sees 8 A-rows + 8 B-cols (20MB) instead of 2 rows + ALL cols (50MB).
template <int NF, bool F32OUT>
__global__ __launch_bounds__(512, 4) void gemm_pipe_k(const u16* __restrict__ A,
                                                      const u16* __restrict__ BT,
                                                      void* __restrict__ Cv, int N, int K) {
    constexpr int BN = NF * 64;
    constexpr int SA = 128 * 64;
    constexpr int SB = BN * 64;
    constexpr int SBUF = SA + SB;
    __shared__ alignas(16) char lds[3 * SBUF];

    int t = threadIdx.x;
    int lane = t & 63, w = t >> 6;
    int wr = w >> 2, wc = w & 3;
    int l15 = lane & 15, l4 = lane >> 4;

    // rectangle XCD swizzle (nbm=16, nbn=32, 512 blocks for both GEMMs)
    int wg = blockIdx.x;
    int xcd = wg & 7, j = wg >> 3;            // j in 0..63
    int bm = ((xcd >> 2) << 3) + (j >> 3);    // 2 row-groups of 8
    int bn = ((xcd & 3) << 3) + (j & 7);      // 4 col-groups of 8

    const u16* Ab = A + (size_t)bm * 128 * K;
    const u16* Bb = BT + (size_t)bn * BN * K;

    int ar = t >> 2;
    int akc = (t & 3) ^ ((ar >> 1) & 3);
    const u16* ga = Ab + (size_t)ar * K + akc * 8;
    int br0 = t >> 2;
    int bk0 = (t & 3) ^ ((br0 >> 1) & 3);
    const u16* gb0 = Bb + (size_t)br0 * K + bk0 * 8;
    int bc1 = 512 + t;
    int br1 = bc1 >> 2;
    int bk1 = (bc1 & 3) ^ ((br1 >> 1) & 3);
    const u16* gb1 = Bb + (size_t)br1 * K + bk1 * 8;
    bool hasB1 = (NF == 3) && (w < 4);
    int myG = (NF == 3) ? ((w < 4) ? 3 : 2) : 2;

    auto stage = [&](int v) {
        int b = v - (v / 3) * 3;
        char* LA = lds + b * SBUF;
        char* LB = LA + SA;
        int ko = v * 32;
        gload16(ga + ko, LA + t * 16);
        gload16(gb0 + ko, LB + t * 16);
        if (NF == 3) {
            if (hasB1) gload16(gb1 + ko, LB + bc1 * 16);
        }
    };

    f32x4 acc[4][NF];
#pragma unroll
    for (int i = 0; i < 4; ++i)
#pragma unroll
        for (int j2 = 0; j2 < NF; ++j2) acc[i][j2] = f32x4{0.f, 0.f, 0.f, 0.f};

    int arow[4], akk[4];
#pragma unroll
    for (int fm = 0; fm < 4; ++fm) {
        arow[fm] = wr * 64 + fm * 16 + l15;
        akk[fm] = l4 ^ ((arow[fm] >> 1) & 3);
    }
    int brow[NF], bkk[NF];
#pragma unroll
    for (int fn = 0; fn < NF; ++fn) {
        brow[fn] = wc * (NF * 16) + fn * 16 + l15;
        bkk[fn] = l4 ^ ((brow[fn] >> 1) & 3);
    }

    int nk = K >> 5;
    stage(0);
    stage(1);
    gatebar(myG);

    int b = 0;
    for (int v = 0; v < nk; ++v) {
        const u16* LA = (const u16*)(lds + b * SBUF);
        const u16* LB = LA + SA / 2;
        if (v + 2 < nk) stage(v + 2);
        bf16x8 bf[NF];
#pragma unroll
        for (int fn = 0; fn < NF; ++fn)
            bf[fn] = *(const bf16x8*)&LB[brow[fn] * 32 + bkk[fn] * 8];
        __builtin_amdgcn_s_setprio(1);
#pragma unroll
        for (int fm = 0; fm < 4; ++fm) {
            bf16x8 af = *(const bf16x8*)&LA[arow[fm] * 32 + akk[fm] * 8];
#pragma unroll
            for (int fn = 0; fn < NF; ++fn)
                acc[fm][fn] = __builtin_amdgcn_mfma_f32_16x16x32_bf16(af, bf[fn],
                                                                     acc[fm][fn], 0, 0, 0);
        }
        __builtin_amdgcn_s_setprio(0);
        if (v < nk - 1) gatebar((v + 2 < nk) ? myG : 0);
        b = (b == 2) ? 0 : b + 1;
    }

#pragma unroll
    for (int fm = 0; fm < 4; ++fm)
#pragma unroll
        for (int fn = 0; fn < NF; ++fn)
#pragma unroll
            for (int i = 0; i < 4; ++i) {
                int row = bm * 128 + wr * 64 + fm * 16 + l4 * 4 + i;
                int col = bn * BN + wc * (NF * 16) + fn * 16 + l15;
                if constexpr (F32OUT)
                    ((float*)Cv)[(size_t)row * N + col] = acc[fm][fn][i];
                else
                    ((u16*)Cv)[(size_t)row * N + col] = f2bf(acc[fm][fn][i]);
            }
}

// -------- repack + RoPE (vectorized): QKV[s,6144] -> Q[h,s,d], K[hk,s,d], V[hk,s,d] --------
__global__ __launch_bounds__(256) void repack_rope_k(const u16* __restrict__ QKV,
                                                     const float* __restrict__ tab,
                                                     u16* __restrict__ Qo, u16* __restrict__ Ko,
                                                     u16* __restrict__ Vo) {
    int idx = blockIdx.x * 256 + threadIdx.x; // < SEQ*48*16
    int i4 = (idx & 15) * 4;
    int su = idx >> 4;
    int u = su % 48;
    int s = su / 48;
    if (u < 40) {
        const float* tp = tab + (s * 64 + i4) * 2;
        f32x4 t0 = *(const f32x4*)tp;
        f32x4 t1 = *(const f32x4*)(tp + 4);
        float cv[4] = {t0[0], t0[2], t1[0], t1[2]};
        float sv[4] = {t0[1], t0[3], t1[1], t1[3]};
        const u16* base;
        u16* ob;
        if (u < 32) {
            base = QKV + (size_t)s * NQKV + u * 128;
            ob = Qo + ((size_t)u * SEQ + s) * 128;
        } else {
            base = QKV + (size_t)s * NQKV + 4096 + (u - 32) * 128;
            ob = Ko + ((size_t)(u - 32) * SEQ + s) * 128;
        }
        u16x4 x1 = *(const u16x4*)(base + i4);
        u16x4 x2 = *(const u16x4*)(base + 64 + i4);
        u16x4 o1, o2;
#pragma unroll
        for (int j = 0; j < 4; ++j) {
            float a = bf2f(x1[j]), b = bf2f(x2[j]);
            o1[j] = f2bf(a * cv[j] - b * sv[j]);
            o2[j] = f2bf(b * cv[j] + a * sv[j]);
        }
        *(u16x4*)(ob + i4) = o1;
        *(u16x4*)(ob + 64 + i4) = o2;
    } else {
        int hv = u - 40;
        const u16* base = QKV + (size_t)s * NQKV + 5120 + hv * 128;
        u16* ob = Vo + ((size_t)hv * SEQ + s) * 128;
        *(u16x4*)(ob + i4) = *(const u16x4*)(base + i4);
        *(u16x4*)(ob + 64 + i4) = *(const u16x4*)(base + 64 + i4);
    }
}

// ------- causal GQA flash attention: 512 threads / 8 waves / 128-row q-blocks,
// ------- paired {bx, 15-bx}, dbuf prefetch, SHUFFLE-FREE steady-state softmax -------
__global__ __launch_bounds__(512) void attn_k(const u16* __restrict__ Qg,
                                              const u16* __restrict__ Kg,
                                              const u16* __restrict__ Vg,
                                              u16* __restrict__ ctx) {
    constexpr float SCL2 = 0.08838834764831845f * 1.44269504088896340736f; // 1/sqrt(128)*log2e
    constexpr float THR = 11.5f;
    __shared__ alignas(16) u16 Klds[2][64 * 128];   // 2 x 16 KB, XOR-swizzled rows
    __shared__ alignas(16) u16 VT[2][128 * 72];     // 2 x 18 KB, V^T stride 72
    __shared__ alignas(16) u16 Plds[8 * 16 * 72];   // 18 KB, per-wave P (stride 72)

    int t = threadIdx.x;
    int lane = t & 63, w = t >> 6;       // 8 waves
    int l15 = lane & 15, l4 = lane >> 4;
    int bx = blockIdx.x;                 // 0..7
    int h = blockIdx.y, hkv = h >> 2;
    const u16* Kh = Kg + (size_t)hkv * SEQ * 128;
    const u16* Vh = Vg + (size_t)hkv * SEQ * 128;
    u16* Pw = &Plds[w * 1152];

    // K staging: 2 chunks/thread; slots c = t + i*512, row kr, swizzled chunk
    int kr[2], kchs[2];
#pragma unroll
    for (int i2 = 0; i2 < 2; ++i2) {
        int c = t + i2 * 512;
        kr[i2] = c >> 4;
        kchs[i2] = (c & 15) ^ (kr[i2] & 7);
    }
    int vr = lane, vcb = (t >> 6) * 16;  // V: row=lane, 16-col group per wave

    int q0 = bx * 128;        // member A; member B = (15-bx)*128
    int ntA = 2 * bx + 2;     // A tiles; B has 32-2bx; total 34

    bf16x8 qf[4], vreg[2];
    f32x4 o[8];
    float m_i[4], l_i[4];     // l_i = PER-LANE partial sums (reduced only at write_ctx)

    auto kvbase = [&](int tt) { return (tt < ntA ? tt : tt - ntA) << 6; };
    auto load_q = [&]() {
        const u16* Qh = Qg + ((size_t)h * SEQ + q0 + w * 16 + l15) * 128;
#pragma unroll
        for (int ks = 0; ks < 4; ++ks) qf[ks] = *(const bf16x8*)(Qh + ks * 32 + l4 * 8);
    };
    auto reset_acc = [&]() {
#pragma unroll
        for (int nf = 0; nf < 8; ++nf) o[nf] = f32x4{0.f, 0.f, 0.f, 0.f};
#pragma unroll
        for (int i = 0; i < 4; ++i) { m_i[i] = -3.0e38f; l_i[i] = 0.f; }
    };
    auto write_ctx = [&]() {
        float inv[4];
#pragma unroll
        for (int i = 0; i < 4; ++i) {
            float rs = l_i[i];          // reduce per-lane partials across l15 (once per q-tile)
            rs += __shfl_xor(rs, 1);
            rs += __shfl_xor(rs, 2);
            rs += __shfl_xor(rs, 4);
            rs += __shfl_xor(rs, 8);
            inv[i] = 1.0f / rs;
        }
#pragma unroll
        for (int nf = 0; nf < 8; ++nf)
#pragma unroll
            for (int i = 0; i < 4; ++i) {
                int qrow = q0 + w * 16 + l4 * 4 + i;
                ctx[(size_t)qrow * 4096 + h * 128 + nf * 16 + l15] = f2bf(o[nf][i] * inv[i]);
            }
    };
    auto loadV = [&](int tt) {  // issue FIRST so K gloads are newest in FIFO
        const u16* Vt = Vh + (size_t)kvbase(tt) * 128;
#pragma unroll
        for (int seg = 0; seg < 2; ++seg)
            vreg[seg] = *(const bf16x8*)(Vt + (size_t)vr * 128 + vcb + seg * 8);
    };
    auto stageK = [&](int tt) {
        const u16* Kt = Kh + (size_t)kvbase(tt) * 128;
        char* kb = (char*)Klds[tt & 1];
#pragma unroll
        for (int i2 = 0; i2 < 2; ++i2)
            gload16(Kt + kr[i2] * 128 + kchs[i2] * 8, kb + (size_t)(t + i2 * 512) * 16);
    };
    auto writeV = [&](int tt) {
        u16* vb = VT[tt & 1];
#pragma unroll
        for (int seg = 0; seg < 2; ++seg) {
            int c0 = vcb + seg * 8;
            u16* vv = (u16*)&vreg[seg];
#pragma unroll
            for (int j = 0; j < 8; ++j) vb[(c0 + j) * 72 + vr] = vv[j];
        }
    };

    load_q();
    reset_acc();
    loadV(0);
    stageK(0);
    asm volatile("s_waitcnt vmcnt(0)" ::: "memory");
    __builtin_amdgcn_sched_barrier(0);
    writeV(0);

    for (int tt = 0; tt < 34; ++tt) {
        // B1: own LDS ops drained + all waves done compute(tt-1); V(tt) writes visible
        asm volatile("s_waitcnt lgkmcnt(0)" ::: "memory");
        __builtin_amdgcn_sched_barrier(0);
        __builtin_amdgcn_s_barrier();
        __builtin_amdgcn_sched_barrier(0);
        bool nxt = (tt + 1 < 34);
        if (nxt) {
            loadV(tt + 1);   // 2 VMEM (reg)
            stageK(tt + 1);  // 2 VMEM (lds), newest
        }
        gatebar(nxt ? 4 : 0); // B2: K(tt) landed for all waves; tt+1 loads in flight
        if (tt == ntA) { // finish member A, switch to member B
            write_ctx();
            q0 = (15 - bx) * 128;
            load_q();
            reset_acc();
        }

        int b = tt & 1;
        int kv0 = kvbase(tt);
        const u16* KL = Klds[b];

        // ---- QK^T ----
        f32x4 sa[4];
#pragma unroll
        for (int cg = 0; cg < 4; ++cg) {
            sa[cg] = f32x4{0.f, 0.f, 0.f, 0.f};
            int row = cg * 16 + l15;
#pragma unroll
            for (int ks = 0; ks < 4; ++ks) {
                int chs = (ks * 4 + l4) ^ (row & 7);
                bf16x8 kf = *(const bf16x8*)&KL[row * 128 + chs * 8];
                sa[cg] = __builtin_amdgcn_mfma_f32_16x16x32_bf16(qf[ks], kf, sa[cg], 0, 0, 0);
            }
        }
#pragma unroll
        for (int cg = 0; cg < 4; ++cg)
#pragma unroll
            for (int i = 0; i < 4; ++i) sa[cg][i] *= SCL2;
        if (kv0 + 63 > q0 + w * 16) {
#pragma unroll
            for (int cg = 0; cg < 4; ++cg) {
                int col = kv0 + cg * 16 + l15;
#pragma unroll
                for (int i = 0; i < 4; ++i) {
                    int qrow = q0 + w * 16 + l4 * 4 + i;
                    if (col > qrow) sa[cg][i] = -3.0e38f;
                }
            }
        }
        // ---- online softmax: per-lane defer test, NO shuffles in steady state ----
        float lmx[4];
#pragma unroll
        for (int i = 0; i < 4; ++i)
            lmx[i] = fmaxf(fmaxf(sa[0][i], sa[1][i]), fmaxf(sa[2][i], sa[3][i]));
        bool defer = __all((lmx[0] <= m_i[0] + THR) & (lmx[1] <= m_i[1] + THR) &
                           (lmx[2] <= m_i[2] + THR) & (lmx[3] <= m_i[3] + THR));
        if (!defer) {
            float corr[4];
#pragma unroll
            for (int i = 0; i < 4; ++i) {
                float m0 = lmx[i];   // full row-max tree (rare path)
                m0 = fmaxf(m0, __shfl_xor(m0, 1));
                m0 = fmaxf(m0, __shfl_xor(m0, 2));
                m0 = fmaxf(m0, __shfl_xor(m0, 4));
                m0 = fmaxf(m0, __shfl_xor(m0, 8));
                float mnew = fmaxf(m_i[i], m0);
                corr[i] = __builtin_amdgcn_exp2f(m_i[i] - mnew);
                m_i[i] = mnew;
                l_i[i] *= corr[i];
            }
#pragma unroll
            for (int nf = 0; nf < 8; ++nf) {
                o[nf][0] *= corr[0]; o[nf][1] *= corr[1];
                o[nf][2] *= corr[2]; o[nf][3] *= corr[3];
            }
        }
        // write V(tt+1) into the other buffer (V global latency hidden under QK^T)
        if (nxt) writeV(tt + 1);
#pragma unroll
        for (int i = 0; i < 4; ++i) {
            int prow = l4 * 4 + i;
            int sw = (prow >> 1) & 3;
            float rs = 0.f;
#pragma unroll
            for (int cg = 0; cg < 4; ++cg) {
                float p = __builtin_amdgcn_exp2f(sa[cg][i] - m_i[i]);
                rs += p;
                int ch = cg * 2 + (l15 >> 3);
                Pw[prow * 72 + ((ch ^ sw) << 3) + (l15 & 7)] = f2bf(p);
            }
            l_i[i] += rs;   // per-lane partial; reduced once in write_ctx
        }
        // ---- PV: P + V from LDS (b128 reads, 2-way free conflicts) ----
        asm volatile("s_waitcnt lgkmcnt(0)" ::: "memory");
        __builtin_amdgcn_sched_barrier(0);
#pragma unroll
        for (int kst = 0; kst < 2; ++kst) {
            int pchs = (kst * 4 + l4) ^ ((l15 >> 1) & 3);
            bf16x8 pf = *(const bf16x8*)&Pw[l15 * 72 + pchs * 8];
#pragma unroll
            for (int nf = 0; nf < 8; ++nf) {
                bf16x8 vf = *(const bf16x8*)&VT[b][(nf * 16 + l15) * 72 + kst * 32 + l4 * 8];
                o[nf] = __builtin_amdgcn_mfma_f32_16x16x32_bf16(pf, vf, o[nf], 0, 0, 0);
            }
        }
    }
    write_ctx();
}

extern "C" void kernel_launch(void* const* d_in, const int* in_sizes, int n_in,
                              void* d_out, int out_size, void* d_ws, size_t ws_size,
                              hipStream_t stream) {
    const float* hidden = (const float*)d_in[0];   // fp32 (per reference dtype)
    // d_in[1] = sequence_mask (unused by reference math: all-ones + causal)
    const float* Wqkv = (const float*)d_in[2];     // fp32
    const float* Wo = (const float*)d_in[3];       // fp32
    float* out = (float*)d_out;                    // fp32 output
    char* ws = (char*)d_ws;

    // ws layout (bytes) with verified liveness (no overlapping live intervals):
    u16* WqkvT   = (u16*)(ws + 0);           // transpose1 -> gemm1
    u16* Qb      = (u16*)(ws + 0);           // repack -> attn (WqkvT dead)
    u16* Kb      = (u16*)(ws + 16777216);
    u16* Vb      = (u16*)(ws + 20971520);
    u16* WoT     = (u16*)(ws + 25165824);    // transposeWo -> gemm2
    u16* QKV     = (u16*)(ws + 50331648);    // gemm1 -> repack
    u16* ctx     = (u16*)(ws + 58720256);    // attn -> gemm2
    float* tab   = (float*)(ws + 75497472);  // rope -> repack
    u16* hiddenB = (u16*)(ws + 76546048);    // cast -> gemm1

    rope_table_k<<<512, 256, 0, stream>>>(tab);
    cast_k<<<8192, 256, 0, stream>>>(hidden, hiddenB, 2048 * 4096 / 4);
    transpose_cast_k<<<dim3(96, 64), 256, 0, stream>>>(Wqkv, WqkvT, 4096, 6144);
    gemm_pipe_k<3, false><<<512, 512, 0, stream>>>(hiddenB, WqkvT, QKV, 6144, 4096);
    repack_rope_k<<<6144, 256, 0, stream>>>(QKV, tab, Qb, Kb, Vb);
    transpose_cast_k<<<dim3(64, 64), 256, 0, stream>>>(Wo, WoT, 4096, 4096);
    attn_k<<<dim3(8, 32), 512, 0, stream>>>(Qb, Kb, Vb, ctx);
    gemm_pipe_k<2, true><<<512, 512, 0, stream>>>(ctx, WoT, out, 4096, 4096);
}

// Round 15
// 334.321 us; speedup vs baseline: 1.4916x; 1.0780x over previous
//
#include <hip/hip_runtime.h>

typedef unsigned short u16;
typedef __bf16 bf16x8 __attribute__((ext_vector_type(8)));
typedef float f32x4 __attribute__((ext_vector_type(4)));
typedef u16 u16x4 __attribute__((ext_vector_type(4)));

constexpr int SEQ = 2048;
constexpr int NQKV = 6144; // (32 + 2*8) * 128

__device__ __forceinline__ float bf2f(u16 x) {
    unsigned int u = ((unsigned int)x) << 16;
    return __builtin_bit_cast(float, u);
}
__device__ __forceinline__ u16 f2bf(float f) {
    unsigned int u = __builtin_bit_cast(unsigned int, f);
    u += 0x7FFF + ((u >> 16) & 1);
    return (u16)(u >> 16);
}

__device__ __forceinline__ void gload16(const void* g, void* l) {
    void* gg = const_cast<void*>(g);
    __builtin_amdgcn_global_load_lds(
        (__attribute__((address_space(1))) void*)gg,
        (__attribute__((address_space(3))) void*)l, 16, 0, 0);
}

// counted-vmcnt gate + raw barrier
__device__ __forceinline__ void gatebar(int G) {
    if (G == 4) asm volatile("s_waitcnt vmcnt(4)" ::: "memory");
    else if (G == 3) asm volatile("s_waitcnt vmcnt(3)" ::: "memory");
    else if (G == 2) asm volatile("s_waitcnt vmcnt(2)" ::: "memory");
    else asm volatile("s_waitcnt vmcnt(0)" ::: "memory");
    __builtin_amdgcn_sched_barrier(0);
    __builtin_amdgcn_s_barrier();
    __builtin_amdgcn_sched_barrier(0);
}

// ---------------- RoPE table ----------------
__global__ void rope_table_k(float* __restrict__ tab) {
    int idx = blockIdx.x * 256 + threadIdx.x;
    if (idx >= SEQ * 64) return;
    int s = idx >> 6;
    int i = idx & 63;
    float invf = expf(-(float)i * (float)(1.0 / 64.0) * logf(10000.0f));
    float ang = (float)s * invf;
    float sv, cv;
    sincosf(ang, &sv, &cv);
    tab[idx * 2] = cv;
    tab[idx * 2 + 1] = sv;
}

// ---------------- fp32 -> bf16 elementwise cast ----------------
__global__ __launch_bounds__(256) void cast_k(const float* __restrict__ src,
                                              u16* __restrict__ dst, int n4) {
    int i = blockIdx.x * 256 + threadIdx.x;
    if (i >= n4) return;
    f32x4 v = *(const f32x4*)&src[(size_t)i * 4];
    u16x4 o;
#pragma unroll
    for (int j = 0; j < 4; ++j) o[j] = f2bf(v[j]);
    *(u16x4*)&dst[(size_t)i * 4] = o;
}

// ---------------- fp32 transpose+cast (R x C fp32 -> C x R bf16) ----------------
__global__ __launch_bounds__(256) void transpose_cast_k(const float* __restrict__ src,
                                                        u16* __restrict__ dst, int R, int C) {
    __shared__ u16 tile[64][65];
    int t = threadIdx.x;
    int bx = blockIdx.x, by = blockIdx.y;
    int r0 = by * 64, c0 = bx * 64;
#pragma unroll
    for (int it = 0; it < 4; ++it) {
        int row = it * 16 + (t >> 4);
        int col = (t & 15) * 4;
        f32x4 v = *(const f32x4*)&src[(size_t)(r0 + row) * C + c0 + col];
        tile[row][col] = f2bf(v[0]); tile[row][col + 1] = f2bf(v[1]);
        tile[row][col + 2] = f2bf(v[2]); tile[row][col + 3] = f2bf(v[3]);
    }
    __syncthreads();
#pragma unroll
    for (int it = 0; it < 4; ++it) {
        int orow = it * 16 + (t >> 4);
        int ocol = (t & 15) * 4;
        u16x4 v;
        v[0] = tile[ocol][orow]; v[1] = tile[ocol + 1][orow];
        v[2] = tile[ocol + 2][orow]; v[3] = tile[ocol + 3][orow];
        *(u16x4*)&dst[(size_t)(c0 + orow) * R + r0 + ocol] = v;
    }
}

// ---- GEMM1 big-tile: C[2048,6144] = A[2048,4096] * BT[6144,4096]^T ----
// BM=256, BN=192, BK=64; 256 blocks = 1/CU; 8 waves (2Mx4N); 2 LDS buffers;
// one vmcnt(0)+barrier per 64-K tile (48 MFMA/wave between syncs).
__global__ __launch_bounds__(512, 2) void gemm1_big_k(const u16* __restrict__ A,
                                                      const u16* __restrict__ BT,
                                                      u16* __restrict__ C) {
    constexpr int K = 4096, N = 6144;
    constexpr int SBUF = 57344; // 256*128 + 192*128 bytes
    __shared__ alignas(16) char lds[2 * SBUF];

    int t = threadIdx.x;
    int lane = t & 63, w = t >> 6;
    int wr = w >> 2, wc = w & 3;
    int l15 = lane & 15, l4 = lane >> 4;

    // XCD rectangle: 8 bm x 32 bn; xcd grid 2x4 -> each XCD 4bm x 8bn
    int wg = blockIdx.x;
    int xcd = wg & 7, j = wg >> 3; // j in 0..31
    int bm = ((xcd >> 2) << 2) + (j >> 3); // 0..7
    int bn = ((xcd & 3) << 3) + (j & 7);   // 0..31

    const u16* Ab = A + (size_t)bm * 256 * K;
    const u16* Bb = BT + (size_t)bn * 192 * K;

    // staging: A 4 chunks/thread (2048 chunks), B 3 chunks/thread (1536 chunks)
    const u16* ga[4]; int da[4];
#pragma unroll
    for (int i = 0; i < 4; ++i) {
        int c = t + i * 512;
        int row = c >> 3;
        int ch = (c & 7) ^ (row & 7);
        ga[i] = Ab + (size_t)row * K + ch * 8;
        da[i] = c * 16;
    }
    const u16* gb[3]; int db[3];
#pragma unroll
    for (int i = 0; i < 3; ++i) {
        int c = t + i * 512;
        int row = c >> 3;
        int ch = (c & 7) ^ (row & 7);
        gb[i] = Bb + (size_t)row * K + ch * 8;
        db[i] = 32768 + c * 16;
    }

    auto stage = [&](int kt) {
        char* L = lds + (kt & 1) * SBUF;
        int ko = kt * 64;
#pragma unroll
        for (int i = 0; i < 4; ++i) gload16(ga[i] + ko, L + da[i]);
#pragma unroll
        for (int i = 0; i < 3; ++i) gload16(gb[i] + ko, L + db[i]);
    };

    f32x4 acc[8][3];
#pragma unroll
    for (int i = 0; i < 8; ++i)
#pragma unroll
        for (int j2 = 0; j2 < 3; ++j2) acc[i][j2] = f32x4{0.f, 0.f, 0.f, 0.f};

    int arow[8];
#pragma unroll
    for (int fm = 0; fm < 8; ++fm) arow[fm] = wr * 128 + fm * 16 + l15;
    int brow[3];
#pragma unroll
    for (int fn = 0; fn < 3; ++fn) brow[fn] = wc * 48 + fn * 16 + l15;

    stage(0);
    gatebar(0);

    for (int kt = 0; kt < 64; ++kt) {
        const u16* L = (const u16*)(lds + (kt & 1) * SBUF);
        if (kt + 1 < 64) stage(kt + 1);
        // B-fragments for the whole tile (register-resident)
        bf16x8 bf[3][2];
#pragma unroll
        for (int fn = 0; fn < 3; ++fn)
#pragma unroll
            for (int kk = 0; kk < 2; ++kk) {
                int ch = (kk * 4 + l4) ^ (brow[fn] & 7);
                bf[fn][kk] = *(const bf16x8*)&L[16384 + brow[fn] * 64 + ch * 8];
            }
        // 4 phases x (2 m-frags x 3 n x 2 kk = 12 MFMA)
#pragma unroll
        for (int p = 0; p < 4; ++p) {
            bf16x8 af[2][2];
#pragma unroll
            for (int f2 = 0; f2 < 2; ++f2)
#pragma unroll
                for (int kk = 0; kk < 2; ++kk) {
                    int r = arow[p * 2 + f2];
                    int ch = (kk * 4 + l4) ^ (r & 7);
                    af[f2][kk] = *(const bf16x8*)&L[r * 64 + ch * 8];
                }
            __builtin_amdgcn_s_setprio(1);
#pragma unroll
            for (int f2 = 0; f2 < 2; ++f2)
#pragma unroll
                for (int kk = 0; kk < 2; ++kk)
#pragma unroll
                    for (int fn = 0; fn < 3; ++fn)
                        acc[p * 2 + f2][fn] = __builtin_amdgcn_mfma_f32_16x16x32_bf16(
                            af[f2][kk], bf[fn][kk], acc[p * 2 + f2][fn], 0, 0, 0);
            __builtin_amdgcn_s_setprio(0);
        }
        gatebar(0); // own stage(kt+1) drained (covered by ~48 MFMA) + all waves synced
    }

#pragma unroll
    for (int fm = 0; fm < 8; ++fm)
#pragma unroll
        for (int fn = 0; fn < 3; ++fn)
#pragma unroll
            for (int i = 0; i < 4; ++i) {
                int row = bm * 256 + wr * 128 + fm * 16 + l4 * 4 + i;
                int col = bn * 192 + wc * 48 + fn * 16 + l15;
                C[(size_t)row * N + col] = f2bf(acc[fm][fn][i]);
            }
}

// ---- pipelined GEMM (GEMM2): C[M,N] = A[M,K] * BT[N,K]^T, bf16 in, fp32 acc ----
template <int NF, bool F32OUT>
__global__ __launch_bounds__(512, 4) void gemm_pipe_k(const u16* __restrict__ A,
                                                      const u16* __restrict__ BT,
                                                      void* __restrict__ Cv, int N, int K) {
    constexpr int BN = NF * 64;
    constexpr int SA = 128 * 64;
    constexpr int SB = BN * 64;
    constexpr int SBUF = SA + SB;
    __shared__ alignas(16) char lds[3 * SBUF];

    int t = threadIdx.x;
    int lane = t & 63, w = t >> 6;
    int wr = w >> 2, wc = w & 3;
    int l15 = lane & 15, l4 = lane >> 4;

    // rectangle XCD swizzle (nbm=16, nbn=32, 512 blocks)
    int wg = blockIdx.x;
    int xcd = wg & 7, j = wg >> 3;
    int bm = ((xcd >> 2) << 3) + (j >> 3);
    int bn = ((xcd & 3) << 3) + (j & 7);

    const u16* Ab = A + (size_t)bm * 128 * K;
    const u16* Bb = BT + (size_t)bn * BN * K;

    int ar = t >> 2;
    int akc = (t & 3) ^ ((ar >> 1) & 3);
    const u16* ga = Ab + (size_t)ar * K + akc * 8;
    int br0 = t >> 2;
    int bk0 = (t & 3) ^ ((br0 >> 1) & 3);
    const u16* gb0 = Bb + (size_t)br0 * K + bk0 * 8;
    int bc1 = 512 + t;
    int br1 = bc1 >> 2;
    int bk1 = (bc1 & 3) ^ ((br1 >> 1) & 3);
    const u16* gb1 = Bb + (size_t)br1 * K + bk1 * 8;
    bool hasB1 = (NF == 3) && (w < 4);
    int myG = (NF == 3) ? ((w < 4) ? 3 : 2) : 2;

    auto stage = [&](int v) {
        int b = v - (v / 3) * 3;
        char* LA = lds + b * SBUF;
        char* LB = LA + SA;
        int ko = v * 32;
        gload16(ga + ko, LA + t * 16);
        gload16(gb0 + ko, LB + t * 16);
        if (NF == 3) {
            if (hasB1) gload16(gb1 + ko, LB + bc1 * 16);
        }
    };

    f32x4 acc[4][NF];
#pragma unroll
    for (int i = 0; i < 4; ++i)
#pragma unroll
        for (int j2 = 0; j2 < NF; ++j2) acc[i][j2] = f32x4{0.f, 0.f, 0.f, 0.f};

    int arow[4], akk[4];
#pragma unroll
    for (int fm = 0; fm < 4; ++fm) {
        arow[fm] = wr * 64 + fm * 16 + l15;
        akk[fm] = l4 ^ ((arow[fm] >> 1) & 3);
    }
    int brow[NF], bkk[NF];
#pragma unroll
    for (int fn = 0; fn < NF; ++fn) {
        brow[fn] = wc * (NF * 16) + fn * 16 + l15;
        bkk[fn] = l4 ^ ((brow[fn] >> 1) & 3);
    }

    int nk = K >> 5;
    stage(0);
    stage(1);
    gatebar(myG);

    int b = 0;
    for (int v = 0; v < nk; ++v) {
        const u16* LA = (const u16*)(lds + b * SBUF);
        const u16* LB = LA + SA / 2;
        if (v + 2 < nk) stage(v + 2);
        bf16x8 bf[NF];
#pragma unroll
        for (int fn = 0; fn < NF; ++fn)
            bf[fn] = *(const bf16x8*)&LB[brow[fn] * 32 + bkk[fn] * 8];
        __builtin_amdgcn_s_setprio(1);
#pragma unroll
        for (int fm = 0; fm < 4; ++fm) {
            bf16x8 af = *(const bf16x8*)&LA[arow[fm] * 32 + akk[fm] * 8];
#pragma unroll
            for (int fn = 0; fn < NF; ++fn)
                acc[fm][fn] = __builtin_amdgcn_mfma_f32_16x16x32_bf16(af, bf[fn],
                                                                     acc[fm][fn], 0, 0, 0);
        }
        __builtin_amdgcn_s_setprio(0);
        if (v < nk - 1) gatebar((v + 2 < nk) ? myG : 0);
        b = (b == 2) ? 0 : b + 1;
    }

#pragma unroll
    for (int fm = 0; fm < 4; ++fm)
#pragma unroll
        for (int fn = 0; fn < NF; ++fn)
#pragma unroll
            for (int i = 0; i < 4; ++i) {
                int row = bm * 128 + wr * 64 + fm * 16 + l4 * 4 + i;
                int col = bn * BN + wc * (NF * 16) + fn * 16 + l15;
                if constexpr (F32OUT)
                    ((float*)Cv)[(size_t)row * N + col] = acc[fm][fn][i];
                else
                    ((u16*)Cv)[(size_t)row * N + col] = f2bf(acc[fm][fn][i]);
            }
}

// -------- repack + RoPE (vectorized): QKV[s,6144] -> Q[h,s,d], K[hk,s,d], V[hk,s,d] --------
__global__ __launch_bounds__(256) void repack_rope_k(const u16* __restrict__ QKV,
                                                     const float* __restrict__ tab,
                                                     u16* __restrict__ Qo, u16* __restrict__ Ko,
                                                     u16* __restrict__ Vo) {
    int idx = blockIdx.x * 256 + threadIdx.x; // < SEQ*48*16
    int i4 = (idx & 15) * 4;
    int su = idx >> 4;
    int u = su % 48;
    int s = su / 48;
    if (u < 40) {
        const float* tp = tab + (s * 64 + i4) * 2;
        f32x4 t0 = *(const f32x4*)tp;
        f32x4 t1 = *(const f32x4*)(tp + 4);
        float cv[4] = {t0[0], t0[2], t1[0], t1[2]};
        float sv[4] = {t0[1], t0[3], t1[1], t1[3]};
        const u16* base;
        u16* ob;
        if (u < 32) {
            base = QKV + (size_t)s * NQKV + u * 128;
            ob = Qo + ((size_t)u * SEQ + s) * 128;
        } else {
            base = QKV + (size_t)s * NQKV + 4096 + (u - 32) * 128;
            ob = Ko + ((size_t)(u - 32) * SEQ + s) * 128;
        }
        u16x4 x1 = *(const u16x4*)(base + i4);
        u16x4 x2 = *(const u16x4*)(base + 64 + i4);
        u16x4 o1, o2;
#pragma unroll
        for (int j = 0; j < 4; ++j) {
            float a = bf2f(x1[j]), b = bf2f(x2[j]);
            o1[j] = f2bf(a * cv[j] - b * sv[j]);
            o2[j] = f2bf(b * cv[j] + a * sv[j]);
        }
        *(u16x4*)(ob + i4) = o1;
        *(u16x4*)(ob + 64 + i4) = o2;
    } else {
        int hv = u - 40;
        const u16* base = QKV + (size_t)s * NQKV + 5120 + hv * 128;
        u16* ob = Vo + ((size_t)hv * SEQ + s) * 128;
        *(u16x4*)(ob + i4) = *(const u16x4*)(base + i4);
        *(u16x4*)(ob + 64 + i4) = *(const u16x4*)(base + 64 + i4);
    }
}

// ------- causal GQA flash attention: 512 threads / 8 waves / 128-row q-blocks,
// ------- paired {bx, 15-bx}, dbuf prefetch, SHUFFLE-FREE steady-state softmax -------
__global__ __launch_bounds__(512) void attn_k(const u16* __restrict__ Qg,
                                              const u16* __restrict__ Kg,
                                              const u16* __restrict__ Vg,
                                              u16* __restrict__ ctx) {
    constexpr float SCL2 = 0.08838834764831845f * 1.44269504088896340736f; // 1/sqrt(128)*log2e
    constexpr float THR = 11.5f;
    __shared__ alignas(16) u16 Klds[2][64 * 128];   // 2 x 16 KB, XOR-swizzled rows
    __shared__ alignas(16) u16 VT[2][128 * 72];     // 2 x 18 KB, V^T stride 72
    __shared__ alignas(16) u16 Plds[8 * 16 * 72];   // 18 KB, per-wave P (stride 72)

    int t = threadIdx.x;
    int lane = t & 63, w = t >> 6;       // 8 waves
    int l15 = lane & 15, l4 = lane >> 4;
    int bx = blockIdx.x;                 // 0..7
    int h = blockIdx.y, hkv = h >> 2;
    const u16* Kh = Kg + (size_t)hkv * SEQ * 128;
    const u16* Vh = Vg + (size_t)hkv * SEQ * 128;
    u16* Pw = &Plds[w * 1152];

    int kr[2], kchs[2];
#pragma unroll
    for (int i2 = 0; i2 < 2; ++i2) {
        int c = t + i2 * 512;
        kr[i2] = c >> 4;
        kchs[i2] = (c & 15) ^ (kr[i2] & 7);
    }
    int vr = lane, vcb = (t >> 6) * 16;

    int q0 = bx * 128;
    int ntA = 2 * bx + 2;

    bf16x8 qf[4], vreg[2];
    f32x4 o[8];
    float m_i[4], l_i[4];

    auto kvbase = [&](int tt) { return (tt < ntA ? tt : tt - ntA) << 6; };
    auto load_q = [&]() {
        const u16* Qh = Qg + ((size_t)h * SEQ + q0 + w * 16 + l15) * 128;
#pragma unroll
        for (int ks = 0; ks < 4; ++ks) qf[ks] = *(const bf16x8*)(Qh + ks * 32 + l4 * 8);
    };
    auto reset_acc = [&]() {
#pragma unroll
        for (int nf = 0; nf < 8; ++nf) o[nf] = f32x4{0.f, 0.f, 0.f, 0.f};
#pragma unroll
        for (int i = 0; i < 4; ++i) { m_i[i] = -3.0e38f; l_i[i] = 0.f; }
    };
    auto write_ctx = [&]() {
        float inv[4];
#pragma unroll
        for (int i = 0; i < 4; ++i) {
            float rs = l_i[i];
            rs += __shfl_xor(rs, 1);
            rs += __shfl_xor(rs, 2);
            rs += __shfl_xor(rs, 4);
            rs += __shfl_xor(rs, 8);
            inv[i] = 1.0f / rs;
        }
#pragma unroll
        for (int nf = 0; nf < 8; ++nf)
#pragma unroll
            for (int i = 0; i < 4; ++i) {
                int qrow = q0 + w * 16 + l4 * 4 + i;
                ctx[(size_t)qrow * 4096 + h * 128 + nf * 16 + l15] = f2bf(o[nf][i] * inv[i]);
            }
    };
    auto loadV = [&](int tt) {
        const u16* Vt = Vh + (size_t)kvbase(tt) * 128;
#pragma unroll
        for (int seg = 0; seg < 2; ++seg)
            vreg[seg] = *(const bf16x8*)(Vt + (size_t)vr * 128 + vcb + seg * 8);
    };
    auto stageK = [&](int tt) {
        const u16* Kt = Kh + (size_t)kvbase(tt) * 128;
        char* kb = (char*)Klds[tt & 1];
#pragma unroll
        for (int i2 = 0; i2 < 2; ++i2)
            gload16(Kt + kr[i2] * 128 + kchs[i2] * 8, kb + (size_t)(t + i2 * 512) * 16);
    };
    auto writeV = [&](int tt) {
        u16* vb = VT[tt & 1];
#pragma unroll
        for (int seg = 0; seg < 2; ++seg) {
            int c0 = vcb + seg * 8;
            u16* vv = (u16*)&vreg[seg];
#pragma unroll
            for (int j = 0; j < 8; ++j) vb[(c0 + j) * 72 + vr] = vv[j];
        }
    };

    load_q();
    reset_acc();
    loadV(0);
    stageK(0);
    asm volatile("s_waitcnt vmcnt(0)" ::: "memory");
    __builtin_amdgcn_sched_barrier(0);
    writeV(0);

    for (int tt = 0; tt < 34; ++tt) {
        asm volatile("s_waitcnt lgkmcnt(0)" ::: "memory");
        __builtin_amdgcn_sched_barrier(0);
        __builtin_amdgcn_s_barrier();
        __builtin_amdgcn_sched_barrier(0);
        bool nxt = (tt + 1 < 34);
        if (nxt) {
            loadV(tt + 1);
            stageK(tt + 1);
        }
        gatebar(nxt ? 4 : 0);
        if (tt == ntA) {
            write_ctx();
            q0 = (15 - bx) * 128;
            load_q();
            reset_acc();
        }

        int b = tt & 1;
        int kv0 = kvbase(tt);
        const u16* KL = Klds[b];

        f32x4 sa[4];
#pragma unroll
        for (int cg = 0; cg < 4; ++cg) {
            sa[cg] = f32x4{0.f, 0.f, 0.f, 0.f};
            int row = cg * 16 + l15;
#pragma unroll
            for (int ks = 0; ks < 4; ++ks) {
                int chs = (ks * 4 + l4) ^ (row & 7);
                bf16x8 kf = *(const bf16x8*)&KL[row * 128 + chs * 8];
                sa[cg] = __builtin_amdgcn_mfma_f32_16x16x32_bf16(qf[ks], kf, sa[cg], 0, 0, 0);
            }
        }
#pragma unroll
        for (int cg = 0; cg < 4; ++cg)
#pragma unroll
            for (int i = 0; i < 4; ++i) sa[cg][i] *= SCL2;
        if (kv0 + 63 > q0 + w * 16) {
#pragma unroll
            for (int cg = 0; cg < 4; ++cg) {
                int col = kv0 + cg * 16 + l15;
#pragma unroll
                for (int i = 0; i < 4; ++i) {
                    int qrow = q0 + w * 16 + l4 * 4 + i;
                    if (col > qrow) sa[cg][i] = -3.0e38f;
                }
            }
        }
        float lmx[4];
#pragma unroll
        for (int i = 0; i < 4; ++i)
            lmx[i] = fmaxf(fmaxf(sa[0][i], sa[1][i]), fmaxf(sa[2][i], sa[3][i]));
        bool defer = __all((lmx[0] <= m_i[0] + THR) & (lmx[1] <= m_i[1] + THR) &
                           (lmx[2] <= m_i[2] + THR) & (lmx[3] <= m_i[3] + THR));
        if (!defer) {
            float corr[4];
#pragma unroll
            for (int i = 0; i < 4; ++i) {
                float m0 = lmx[i];
                m0 = fmaxf(m0, __shfl_xor(m0, 1));
                m0 = fmaxf(m0, __shfl_xor(m0, 2));
                m0 = fmaxf(m0, __shfl_xor(m0, 4));
                m0 = fmaxf(m0, __shfl_xor(m0, 8));
                float mnew = fmaxf(m_i[i], m0);
                corr[i] = __builtin_amdgcn_exp2f(m_i[i] - mnew);
                m_i[i] = mnew;
                l_i[i] *= corr[i];
            }
#pragma unroll
            for (int nf = 0; nf < 8; ++nf) {
                o[nf][0] *= corr[0]; o[nf][1] *= corr[1];
                o[nf][2] *= corr[2]; o[nf][3] *= corr[3];
            }
        }
        if (nxt) writeV(tt + 1);
#pragma unroll
        for (int i = 0; i < 4; ++i) {
            int prow = l4 * 4 + i;
            int sw = (prow >> 1) & 3;
            float rs = 0.f;
#pragma unroll
            for (int cg = 0; cg < 4; ++cg) {
                float p = __builtin_amdgcn_exp2f(sa[cg][i] - m_i[i]);
                rs += p;
                int ch = cg * 2 + (l15 >> 3);
                Pw[prow * 72 + ((ch ^ sw) << 3) + (l15 & 7)] = f2bf(p);
            }
            l_i[i] += rs;
        }
        asm volatile("s_waitcnt lgkmcnt(0)" ::: "memory");
        __builtin_amdgcn_sched_barrier(0);
#pragma unroll
        for (int kst = 0; kst < 2; ++kst) {
            int pchs = (kst * 4 + l4) ^ ((l15 >> 1) & 3);
            bf16x8 pf = *(const bf16x8*)&Pw[l15 * 72 + pchs * 8];
#pragma unroll
            for (int nf = 0; nf < 8; ++nf) {
                bf16x8 vf = *(const bf16x8*)&VT[b][(nf * 16 + l15) * 72 + kst * 32 + l4 * 8];
                o[nf] = __builtin_amdgcn_mfma_f32_16x16x32_bf16(pf, vf, o[nf], 0, 0, 0);
            }
        }
    }
    write_ctx();
}

extern "C" void kernel_launch(void* const* d_in, const int* in_sizes, int n_in,
                              void* d_out, int out_size, void* d_ws, size_t ws_size,
                              hipStream_t stream) {
    const float* hidden = (const float*)d_in[0];   // fp32 (per reference dtype)
    // d_in[1] = sequence_mask (unused by reference math: all-ones + causal)
    const float* Wqkv = (const float*)d_in[2];     // fp32
    const float* Wo = (const float*)d_in[3];       // fp32
    float* out = (float*)d_out;                    // fp32 output
    char* ws = (char*)d_ws;

    u16* WqkvT   = (u16*)(ws + 0);           // transpose1 -> gemm1
    u16* Qb      = (u16*)(ws + 0);           // repack -> attn (WqkvT dead)
    u16* Kb      = (u16*)(ws + 16777216);
    u16* Vb      = (u16*)(ws + 20971520);
    u16* WoT     = (u16*)(ws + 25165824);    // transposeWo -> gemm2
    u16* QKV     = (u16*)(ws + 50331648);    // gemm1 -> repack
    u16* ctx     = (u16*)(ws + 58720256);    // attn -> gemm2
    float* tab   = (float*)(ws + 75497472);  // rope -> repack
    u16* hiddenB = (u16*)(ws + 76546048);    // cast -> gemm1

    rope_table_k<<<512, 256, 0, stream>>>(tab);
    cast_k<<<8192, 256, 0, stream>>>(hidden, hiddenB, 2048 * 4096 / 4);
    transpose_cast_k<<<dim3(96, 64), 256, 0, stream>>>(Wqkv, WqkvT, 4096, 6144);
    gemm1_big_k<<<256, 512, 0, stream>>>(hiddenB, WqkvT, QKV);
    repack_rope_k<<<6144, 256, 0, stream>>>(QKV, tab, Qb, Kb, Vb);
    transpose_cast_k<<<dim3(64, 64), 256, 0, stream>>>(Wo, WoT, 4096, 4096);
    attn_k<<<dim3(8, 32), 512, 0, stream>>>(Qb, Kb, Vb, ctx);
    gemm_pipe_k<2, true><<<512, 512, 0, stream>>>(ctx, WoT, out, 4096, 4096);
}

// Round 16
// 325.741 us; speedup vs baseline: 1.5309x; 1.0263x over previous
//
#include <hip/hip_runtime.h>

typedef unsigned short u16;
typedef __bf16 bf16x8 __attribute__((ext_vector_type(8)));
typedef float f32x4 __attribute__((ext_vector_type(4)));
typedef u16 u16x4 __attribute__((ext_vector_type(4)));

constexpr int SEQ = 2048;
constexpr int NQKV = 6144; // (32 + 2*8) * 128

__device__ __forceinline__ float bf2f(u16 x) {
    unsigned int u = ((unsigned int)x) << 16;
    return __builtin_bit_cast(float, u);
}
__device__ __forceinline__ u16 f2bf(float f) {
    unsigned int u = __builtin_bit_cast(unsigned int, f);
    u += 0x7FFF + ((u >> 16) & 1);
    return (u16)(u >> 16);
}

__device__ __forceinline__ void gload16(const void* g, void* l) {
    void* gg = const_cast<void*>(g);
    __builtin_amdgcn_global_load_lds(
        (__attribute__((address_space(1))) void*)gg,
        (__attribute__((address_space(3))) void*)l, 16, 0, 0);
}

// counted-vmcnt gate + raw barrier
__device__ __forceinline__ void gatebar(int G) {
    if (G == 4) asm volatile("s_waitcnt vmcnt(4)" ::: "memory");
    else if (G == 3) asm volatile("s_waitcnt vmcnt(3)" ::: "memory");
    else if (G == 2) asm volatile("s_waitcnt vmcnt(2)" ::: "memory");
    else asm volatile("s_waitcnt vmcnt(0)" ::: "memory");
    __builtin_amdgcn_sched_barrier(0);
    __builtin_amdgcn_s_barrier();
    __builtin_amdgcn_sched_barrier(0);
}

// ---------------- RoPE table ----------------
__global__ void rope_table_k(float* __restrict__ tab) {
    int idx = blockIdx.x * 256 + threadIdx.x;
    if (idx >= SEQ * 64) return;
    int s = idx >> 6;
    int i = idx & 63;
    float invf = expf(-(float)i * (float)(1.0 / 64.0) * logf(10000.0f));
    float ang = (float)s * invf;
    float sv, cv;
    sincosf(ang, &sv, &cv);
    tab[idx * 2] = cv;
    tab[idx * 2 + 1] = sv;
}

// ---------------- fp32 -> bf16 elementwise cast ----------------
__global__ __launch_bounds__(256) void cast_k(const float* __restrict__ src,
                                              u16* __restrict__ dst, int n4) {
    int i = blockIdx.x * 256 + threadIdx.x;
    if (i >= n4) return;
    f32x4 v = *(const f32x4*)&src[(size_t)i * 4];
    u16x4 o;
#pragma unroll
    for (int j = 0; j < 4; ++j) o[j] = f2bf(v[j]);
    *(u16x4*)&dst[(size_t)i * 4] = o;
}

// ---------------- fp32 transpose+cast (R x C fp32 -> C x R bf16) ----------------
__global__ __launch_bounds__(256) void transpose_cast_k(const float* __restrict__ src,
                                                        u16* __restrict__ dst, int R, int C) {
    __shared__ u16 tile[64][65];
    int t = threadIdx.x;
    int bx = blockIdx.x, by = blockIdx.y;
    int r0 = by * 64, c0 = bx * 64;
#pragma unroll
    for (int it = 0; it < 4; ++it) {
        int row = it * 16 + (t >> 4);
        int col = (t & 15) * 4;
        f32x4 v = *(const f32x4*)&src[(size_t)(r0 + row) * C + c0 + col];
        tile[row][col] = f2bf(v[0]); tile[row][col + 1] = f2bf(v[1]);
        tile[row][col + 2] = f2bf(v[2]); tile[row][col + 3] = f2bf(v[3]);
    }
    __syncthreads();
#pragma unroll
    for (int it = 0; it < 4; ++it) {
        int orow = it * 16 + (t >> 4);
        int ocol = (t & 15) * 4;
        u16x4 v;
        v[0] = tile[ocol][orow]; v[1] = tile[ocol + 1][orow];
        v[2] = tile[ocol + 2][orow]; v[3] = tile[ocol + 3][orow];
        *(u16x4*)&dst[(size_t)(c0 + orow) * R + r0 + ocol] = v;
    }
}

// ---- GEMM1 big-tile: C[2048,6144] = A[2048,4096] * BT[6144,4096]^T ----
__global__ __launch_bounds__(512, 2) void gemm1_big_k(const u16* __restrict__ A,
                                                      const u16* __restrict__ BT,
                                                      u16* __restrict__ C) {
    constexpr int K = 4096, N = 6144;
    constexpr int SBUF = 57344; // 256*128 + 192*128 bytes
    __shared__ alignas(16) char lds[2 * SBUF];

    int t = threadIdx.x;
    int lane = t & 63, w = t >> 6;
    int wr = w >> 2, wc = w & 3;
    int l15 = lane & 15, l4 = lane >> 4;

    int wg = blockIdx.x;
    int xcd = wg & 7, j = wg >> 3;
    int bm = ((xcd >> 2) << 2) + (j >> 3);
    int bn = ((xcd & 3) << 3) + (j & 7);

    const u16* Ab = A + (size_t)bm * 256 * K;
    const u16* Bb = BT + (size_t)bn * 192 * K;

    const u16* ga[4]; int da[4];
#pragma unroll
    for (int i = 0; i < 4; ++i) {
        int c = t + i * 512;
        int row = c >> 3;
        int ch = (c & 7) ^ (row & 7);
        ga[i] = Ab + (size_t)row * K + ch * 8;
        da[i] = c * 16;
    }
    const u16* gb[3]; int db[3];
#pragma unroll
    for (int i = 0; i < 3; ++i) {
        int c = t + i * 512;
        int row = c >> 3;
        int ch = (c & 7) ^ (row & 7);
        gb[i] = Bb + (size_t)row * K + ch * 8;
        db[i] = 32768 + c * 16;
    }

    auto stage = [&](int kt) {
        char* L = lds + (kt & 1) * SBUF;
        int ko = kt * 64;
#pragma unroll
        for (int i = 0; i < 4; ++i) gload16(ga[i] + ko, L + da[i]);
#pragma unroll
        for (int i = 0; i < 3; ++i) gload16(gb[i] + ko, L + db[i]);
    };

    f32x4 acc[8][3];
#pragma unroll
    for (int i = 0; i < 8; ++i)
#pragma unroll
        for (int j2 = 0; j2 < 3; ++j2) acc[i][j2] = f32x4{0.f, 0.f, 0.f, 0.f};

    int arow[8];
#pragma unroll
    for (int fm = 0; fm < 8; ++fm) arow[fm] = wr * 128 + fm * 16 + l15;
    int brow[3];
#pragma unroll
    for (int fn = 0; fn < 3; ++fn) brow[fn] = wc * 48 + fn * 16 + l15;

    stage(0);
    gatebar(0);

    for (int kt = 0; kt < 64; ++kt) {
        const u16* L = (const u16*)(lds + (kt & 1) * SBUF);
        if (kt + 1 < 64) stage(kt + 1);
        bf16x8 bf[3][2];
#pragma unroll
        for (int fn = 0; fn < 3; ++fn)
#pragma unroll
            for (int kk = 0; kk < 2; ++kk) {
                int ch = (kk * 4 + l4) ^ (brow[fn] & 7);
                bf[fn][kk] = *(const bf16x8*)&L[16384 + brow[fn] * 64 + ch * 8];
            }
#pragma unroll
        for (int p = 0; p < 4; ++p) {
            bf16x8 af[2][2];
#pragma unroll
            for (int f2 = 0; f2 < 2; ++f2)
#pragma unroll
                for (int kk = 0; kk < 2; ++kk) {
                    int r = arow[p * 2 + f2];
                    int ch = (kk * 4 + l4) ^ (r & 7);
                    af[f2][kk] = *(const bf16x8*)&L[r * 64 + ch * 8];
                }
            __builtin_amdgcn_s_setprio(1);
#pragma unroll
            for (int f2 = 0; f2 < 2; ++f2)
#pragma unroll
                for (int kk = 0; kk < 2; ++kk)
#pragma unroll
                    for (int fn = 0; fn < 3; ++fn)
                        acc[p * 2 + f2][fn] = __builtin_amdgcn_mfma_f32_16x16x32_bf16(
                            af[f2][kk], bf[fn][kk], acc[p * 2 + f2][fn], 0, 0, 0);
            __builtin_amdgcn_s_setprio(0);
        }
        gatebar(0);
    }

#pragma unroll
    for (int fm = 0; fm < 8; ++fm)
#pragma unroll
        for (int fn = 0; fn < 3; ++fn)
#pragma unroll
            for (int i = 0; i < 4; ++i) {
                int row = bm * 256 + wr * 128 + fm * 16 + l4 * 4 + i;
                int col = bn * 192 + wc * 48 + fn * 16 + l15;
                C[(size_t)row * N + col] = f2bf(acc[fm][fn][i]);
            }
}

// ---- GEMM2 big-tile: out[2048,4096] = ctx[2048,4096] * WoT[4096,4096]^T (fp32 out) ----
// BM=256, BN=128, BK=64; 256 blocks = 1/CU; 8 waves (2Mx4N); 2 LDS buffers (96KB).
__global__ __launch_bounds__(512, 2) void gemm2_big_k(const u16* __restrict__ A,
                                                      const u16* __restrict__ BT,
                                                      float* __restrict__ C) {
    constexpr int K = 4096, N = 4096;
    constexpr int SBUF = 49152; // 256*128 + 128*128 bytes
    __shared__ alignas(16) char lds[2 * SBUF];

    int t = threadIdx.x;
    int lane = t & 63, w = t >> 6;
    int wr = w >> 2, wc = w & 3;
    int l15 = lane & 15, l4 = lane >> 4;

    // XCD rectangle: 8 bm x 32 bn; each XCD 4bm x 8bn
    int wg = blockIdx.x;
    int xcd = wg & 7, j = wg >> 3;
    int bm = ((xcd >> 2) << 2) + (j >> 3);
    int bn = ((xcd & 3) << 3) + (j & 7);

    const u16* Ab = A + (size_t)bm * 256 * K;
    const u16* Bb = BT + (size_t)bn * 128 * K;

    const u16* ga[4]; int da[4];
#pragma unroll
    for (int i = 0; i < 4; ++i) {
        int c = t + i * 512;
        int row = c >> 3;
        int ch = (c & 7) ^ (row & 7);
        ga[i] = Ab + (size_t)row * K + ch * 8;
        da[i] = c * 16;
    }
    const u16* gb[2]; int db[2];
#pragma unroll
    for (int i = 0; i < 2; ++i) {
        int c = t + i * 512;
        int row = c >> 3;
        int ch = (c & 7) ^ (row & 7);
        gb[i] = Bb + (size_t)row * K + ch * 8;
        db[i] = 32768 + c * 16;
    }

    auto stage = [&](int kt) {
        char* L = lds + (kt & 1) * SBUF;
        int ko = kt * 64;
#pragma unroll
        for (int i = 0; i < 4; ++i) gload16(ga[i] + ko, L + da[i]);
#pragma unroll
        for (int i = 0; i < 2; ++i) gload16(gb[i] + ko, L + db[i]);
    };

    f32x4 acc[8][2];
#pragma unroll
    for (int i = 0; i < 8; ++i)
#pragma unroll
        for (int j2 = 0; j2 < 2; ++j2) acc[i][j2] = f32x4{0.f, 0.f, 0.f, 0.f};

    int arow[8];
#pragma unroll
    for (int fm = 0; fm < 8; ++fm) arow[fm] = wr * 128 + fm * 16 + l15;
    int brow[2];
#pragma unroll
    for (int fn = 0; fn < 2; ++fn) brow[fn] = wc * 32 + fn * 16 + l15;

    stage(0);
    gatebar(0);

    for (int kt = 0; kt < 64; ++kt) {
        const u16* L = (const u16*)(lds + (kt & 1) * SBUF);
        if (kt + 1 < 64) stage(kt + 1);
        bf16x8 bf[2][2];
#pragma unroll
        for (int fn = 0; fn < 2; ++fn)
#pragma unroll
            for (int kk = 0; kk < 2; ++kk) {
                int ch = (kk * 4 + l4) ^ (brow[fn] & 7);
                bf[fn][kk] = *(const bf16x8*)&L[16384 + brow[fn] * 64 + ch * 8];
            }
#pragma unroll
        for (int p = 0; p < 4; ++p) {
            bf16x8 af[2][2];
#pragma unroll
            for (int f2 = 0; f2 < 2; ++f2)
#pragma unroll
                for (int kk = 0; kk < 2; ++kk) {
                    int r = arow[p * 2 + f2];
                    int ch = (kk * 4 + l4) ^ (r & 7);
                    af[f2][kk] = *(const bf16x8*)&L[r * 64 + ch * 8];
                }
            __builtin_amdgcn_s_setprio(1);
#pragma unroll
            for (int f2 = 0; f2 < 2; ++f2)
#pragma unroll
                for (int kk = 0; kk < 2; ++kk)
#pragma unroll
                    for (int fn = 0; fn < 2; ++fn)
                        acc[p * 2 + f2][fn] = __builtin_amdgcn_mfma_f32_16x16x32_bf16(
                            af[f2][kk], bf[fn][kk], acc[p * 2 + f2][fn], 0, 0, 0);
            __builtin_amdgcn_s_setprio(0);
        }
        gatebar(0);
    }

#pragma unroll
    for (int fm = 0; fm < 8; ++fm)
#pragma unroll
        for (int fn = 0; fn < 2; ++fn)
#pragma unroll
            for (int i = 0; i < 4; ++i) {
                int row = bm * 256 + wr * 128 + fm * 16 + l4 * 4 + i;
                int col = bn * 128 + wc * 32 + fn * 16 + l15;
                C[(size_t)row * N + col] = acc[fm][fn][i];
            }
}

// -------- repack + RoPE (vectorized): QKV[s,6144] -> Q[h,s,d], K[hk,s,d], V[hk,s,d] --------
__global__ __launch_bounds__(256) void repack_rope_k(const u16* __restrict__ QKV,
                                                     const float* __restrict__ tab,
                                                     u16* __restrict__ Qo, u16* __restrict__ Ko,
                                                     u16* __restrict__ Vo) {
    int idx = blockIdx.x * 256 + threadIdx.x; // < SEQ*48*16
    int i4 = (idx & 15) * 4;
    int su = idx >> 4;
    int u = su % 48;
    int s = su / 48;
    if (u < 40) {
        const float* tp = tab + (s * 64 + i4) * 2;
        f32x4 t0 = *(const f32x4*)tp;
        f32x4 t1 = *(const f32x4*)(tp + 4);
        float cv[4] = {t0[0], t0[2], t1[0], t1[2]};
        float sv[4] = {t0[1], t0[3], t1[1], t1[3]};
        const u16* base;
        u16* ob;
        if (u < 32) {
            base = QKV + (size_t)s * NQKV + u * 128;
            ob = Qo + ((size_t)u * SEQ + s) * 128;
        } else {
            base = QKV + (size_t)s * NQKV + 4096 + (u - 32) * 128;
            ob = Ko + ((size_t)(u - 32) * SEQ + s) * 128;
        }
        u16x4 x1 = *(const u16x4*)(base + i4);
        u16x4 x2 = *(const u16x4*)(base + 64 + i4);
        u16x4 o1, o2;
#pragma unroll
        for (int j = 0; j < 4; ++j) {
            float a = bf2f(x1[j]), b = bf2f(x2[j]);
            o1[j] = f2bf(a * cv[j] - b * sv[j]);
            o2[j] = f2bf(b * cv[j] + a * sv[j]);
        }
        *(u16x4*)(ob + i4) = o1;
        *(u16x4*)(ob + 64 + i4) = o2;
    } else {
        int hv = u - 40;
        const u16* base = QKV + (size_t)s * NQKV + 5120 + hv * 128;
        u16* ob = Vo + ((size_t)hv * SEQ + s) * 128;
        *(u16x4*)(ob + i4) = *(const u16x4*)(base + i4);
        *(u16x4*)(ob + 64 + i4) = *(const u16x4*)(base + 64 + i4);
    }
}

// ------- causal GQA flash attention: 512 threads / 8 waves / 128-row q-blocks,
// ------- paired {bx, 15-bx}, dbuf prefetch, SHUFFLE-FREE steady-state softmax -------
__global__ __launch_bounds__(512) void attn_k(const u16* __restrict__ Qg,
                                              const u16* __restrict__ Kg,
                                              const u16* __restrict__ Vg,
                                              u16* __restrict__ ctx) {
    constexpr float SCL2 = 0.08838834764831845f * 1.44269504088896340736f; // 1/sqrt(128)*log2e
    constexpr float THR = 11.5f;
    __shared__ alignas(16) u16 Klds[2][64 * 128];   // 2 x 16 KB, XOR-swizzled rows
    __shared__ alignas(16) u16 VT[2][128 * 72];     // 2 x 18 KB, V^T stride 72
    __shared__ alignas(16) u16 Plds[8 * 16 * 72];   // 18 KB, per-wave P (stride 72)

    int t = threadIdx.x;
    int lane = t & 63, w = t >> 6;       // 8 waves
    int l15 = lane & 15, l4 = lane >> 4;
    int bx = blockIdx.x;                 // 0..7
    int h = blockIdx.y, hkv = h >> 2;
    const u16* Kh = Kg + (size_t)hkv * SEQ * 128;
    const u16* Vh = Vg + (size_t)hkv * SEQ * 128;
    u16* Pw = &Plds[w * 1152];

    int kr[2], kchs[2];
#pragma unroll
    for (int i2 = 0; i2 < 2; ++i2) {
        int c = t + i2 * 512;
        kr[i2] = c >> 4;
        kchs[i2] = (c & 15) ^ (kr[i2] & 7);
    }
    int vr = lane, vcb = (t >> 6) * 16;

    int q0 = bx * 128;
    int ntA = 2 * bx + 2;

    bf16x8 qf[4], vreg[2];
    f32x4 o[8];
    float m_i[4], l_i[4];

    auto kvbase = [&](int tt) { return (tt < ntA ? tt : tt - ntA) << 6; };
    auto load_q = [&]() {
        const u16* Qh = Qg + ((size_t)h * SEQ + q0 + w * 16 + l15) * 128;
#pragma unroll
        for (int ks = 0; ks < 4; ++ks) qf[ks] = *(const bf16x8*)(Qh + ks * 32 + l4 * 8);
    };
    auto reset_acc = [&]() {
#pragma unroll
        for (int nf = 0; nf < 8; ++nf) o[nf] = f32x4{0.f, 0.f, 0.f, 0.f};
#pragma unroll
        for (int i = 0; i < 4; ++i) { m_i[i] = -3.0e38f; l_i[i] = 0.f; }
    };
    auto write_ctx = [&]() {
        float inv[4];
#pragma unroll
        for (int i = 0; i < 4; ++i) {
            float rs = l_i[i];
            rs += __shfl_xor(rs, 1);
            rs += __shfl_xor(rs, 2);
            rs += __shfl_xor(rs, 4);
            rs += __shfl_xor(rs, 8);
            inv[i] = 1.0f / rs;
        }
#pragma unroll
        for (int nf = 0; nf < 8; ++nf)
#pragma unroll
            for (int i = 0; i < 4; ++i) {
                int qrow = q0 + w * 16 + l4 * 4 + i;
                ctx[(size_t)qrow * 4096 + h * 128 + nf * 16 + l15] = f2bf(o[nf][i] * inv[i]);
            }
    };
    auto loadV = [&](int tt) {
        const u16* Vt = Vh + (size_t)kvbase(tt) * 128;
#pragma unroll
        for (int seg = 0; seg < 2; ++seg)
            vreg[seg] = *(const bf16x8*)(Vt + (size_t)vr * 128 + vcb + seg * 8);
    };
    auto stageK = [&](int tt) {
        const u16* Kt = Kh + (size_t)kvbase(tt) * 128;
        char* kb = (char*)Klds[tt & 1];
#pragma unroll
        for (int i2 = 0; i2 < 2; ++i2)
            gload16(Kt + kr[i2] * 128 + kchs[i2] * 8, kb + (size_t)(t + i2 * 512) * 16);
    };
    auto writeV = [&](int tt) {
        u16* vb = VT[tt & 1];
#pragma unroll
        for (int seg = 0; seg < 2; ++seg) {
            int c0 = vcb + seg * 8;
            u16* vv = (u16*)&vreg[seg];
#pragma unroll
            for (int j = 0; j < 8; ++j) vb[(c0 + j) * 72 + vr] = vv[j];
        }
    };

    load_q();
    reset_acc();
    loadV(0);
    stageK(0);
    asm volatile("s_waitcnt vmcnt(0)" ::: "memory");
    __builtin_amdgcn_sched_barrier(0);
    writeV(0);

    for (int tt = 0; tt < 34; ++tt) {
        asm volatile("s_waitcnt lgkmcnt(0)" ::: "memory");
        __builtin_amdgcn_sched_barrier(0);
        __builtin_amdgcn_s_barrier();
        __builtin_amdgcn_sched_barrier(0);
        bool nxt = (tt + 1 < 34);
        if (nxt) {
            loadV(tt + 1);
            stageK(tt + 1);
        }
        gatebar(nxt ? 4 : 0);
        if (tt == ntA) {
            write_ctx();
            q0 = (15 - bx) * 128;
            load_q();
            reset_acc();
        }

        int b = tt & 1;
        int kv0 = kvbase(tt);
        const u16* KL = Klds[b];

        f32x4 sa[4];
#pragma unroll
        for (int cg = 0; cg < 4; ++cg) {
            sa[cg] = f32x4{0.f, 0.f, 0.f, 0.f};
            int row = cg * 16 + l15;
#pragma unroll
            for (int ks = 0; ks < 4; ++ks) {
                int chs = (ks * 4 + l4) ^ (row & 7);
                bf16x8 kf = *(const bf16x8*)&KL[row * 128 + chs * 8];
                sa[cg] = __builtin_amdgcn_mfma_f32_16x16x32_bf16(qf[ks], kf, sa[cg], 0, 0, 0);
            }
        }
#pragma unroll
        for (int cg = 0; cg < 4; ++cg)
#pragma unroll
            for (int i = 0; i < 4; ++i) sa[cg][i] *= SCL2;
        if (kv0 + 63 > q0 + w * 16) {
#pragma unroll
            for (int cg = 0; cg < 4; ++cg) {
                int col = kv0 + cg * 16 + l15;
#pragma unroll
                for (int i = 0; i < 4; ++i) {
                    int qrow = q0 + w * 16 + l4 * 4 + i;
                    if (col > qrow) sa[cg][i] = -3.0e38f;
                }
            }
        }
        float lmx[4];
#pragma unroll
        for (int i = 0; i < 4; ++i)
            lmx[i] = fmaxf(fmaxf(sa[0][i], sa[1][i]), fmaxf(sa[2][i], sa[3][i]));
        bool defer = __all((lmx[0] <= m_i[0] + THR) & (lmx[1] <= m_i[1] + THR) &
                           (lmx[2] <= m_i[2] + THR) & (lmx[3] <= m_i[3] + THR));
        if (!defer) {
            float corr[4];
#pragma unroll
            for (int i = 0; i < 4; ++i) {
                float m0 = lmx[i];
                m0 = fmaxf(m0, __shfl_xor(m0, 1));
                m0 = fmaxf(m0, __shfl_xor(m0, 2));
                m0 = fmaxf(m0, __shfl_xor(m0, 4));
                m0 = fmaxf(m0, __shfl_xor(m0, 8));
                float mnew = fmaxf(m_i[i], m0);
                corr[i] = __builtin_amdgcn_exp2f(m_i[i] - mnew);
                m_i[i] = mnew;
                l_i[i] *= corr[i];
            }
#pragma unroll
            for (int nf = 0; nf < 8; ++nf) {
                o[nf][0] *= corr[0]; o[nf][1] *= corr[1];
                o[nf][2] *= corr[2]; o[nf][3] *= corr[3];
            }
        }
        if (nxt) writeV(tt + 1);
#pragma unroll
        for (int i = 0; i < 4; ++i) {
            int prow = l4 * 4 + i;
            int sw = (prow >> 1) & 3;
            float rs = 0.f;
#pragma unroll
            for (int cg = 0; cg < 4; ++cg) {
                float p = __builtin_amdgcn_exp2f(sa[cg][i] - m_i[i]);
                rs += p;
                int ch = cg * 2 + (l15 >> 3);
                Pw[prow * 72 + ((ch ^ sw) << 3) + (l15 & 7)] = f2bf(p);
            }
            l_i[i] += rs;
        }
        asm volatile("s_waitcnt lgkmcnt(0)" ::: "memory");
        __builtin_amdgcn_sched_barrier(0);
#pragma unroll
        for (int kst = 0; kst < 2; ++kst) {
            int pchs = (kst * 4 + l4) ^ ((l15 >> 1) & 3);
            bf16x8 pf = *(const bf16x8*)&Pw[l15 * 72 + pchs * 8];
#pragma unroll
            for (int nf = 0; nf < 8; ++nf) {
                bf16x8 vf = *(const bf16x8*)&VT[b][(nf * 16 + l15) * 72 + kst * 32 + l4 * 8];
                o[nf] = __builtin_amdgcn_mfma_f32_16x16x32_bf16(pf, vf, o[nf], 0, 0, 0);
            }
        }
    }
    write_ctx();
}

extern "C" void kernel_launch(void* const* d_in, const int* in_sizes, int n_in,
                              void* d_out, int out_size, void* d_ws, size_t ws_size,
                              hipStream_t stream) {
    const float* hidden = (const float*)d_in[0];   // fp32 (per reference dtype)
    // d_in[1] = sequence_mask (unused by reference math: all-ones + causal)
    const float* Wqkv = (const float*)d_in[2];     // fp32
    const float* Wo = (const float*)d_in[3];       // fp32
    float* out = (float*)d_out;                    // fp32 output
    char* ws = (char*)d_ws;

    u16* WqkvT   = (u16*)(ws + 0);           // transpose1 -> gemm1
    u16* Qb      = (u16*)(ws + 0);           // repack -> attn (WqkvT dead)
    u16* Kb      = (u16*)(ws + 16777216);
    u16* Vb      = (u16*)(ws + 20971520);
    u16* WoT     = (u16*)(ws + 25165824);    // transposeWo -> gemm2
    u16* QKV     = (u16*)(ws + 50331648);    // gemm1 -> repack
    u16* ctx     = (u16*)(ws + 58720256);    // attn -> gemm2
    float* tab   = (float*)(ws + 75497472);  // rope -> repack
    u16* hiddenB = (u16*)(ws + 76546048);    // cast -> gemm1

    rope_table_k<<<512, 256, 0, stream>>>(tab);
    cast_k<<<8192, 256, 0, stream>>>(hidden, hiddenB, 2048 * 4096 / 4);
    transpose_cast_k<<<dim3(96, 64), 256, 0, stream>>>(Wqkv, WqkvT, 4096, 6144);
    gemm1_big_k<<<256, 512, 0, stream>>>(hiddenB, WqkvT, QKV);
    repack_rope_k<<<6144, 256, 0, stream>>>(QKV, tab, Qb, Kb, Vb);
    transpose_cast_k<<<dim3(64, 64), 256, 0, stream>>>(Wo, WoT, 4096, 4096);
    attn_k<<<dim3(8, 32), 512, 0, stream>>>(Qb, Kb, Vb, ctx);
    gemm2_big_k<<<256, 512, 0, stream>>>(ctx, WoT, out);
}

// Round 17
// 311.411 us; speedup vs baseline: 1.6014x; 1.0460x over previous
//
#include <hip/hip_runtime.h>

typedef unsigned short u16;
typedef __bf16 bf16x8 __attribute__((ext_vector_type(8)));
typedef float f32x4 __attribute__((ext_vector_type(4)));
typedef u16 u16x4 __attribute__((ext_vector_type(4)));

constexpr int SEQ = 2048;
constexpr int NQKV = 6144; // (32 + 2*8) * 128

__device__ __forceinline__ float bf2f(u16 x) {
    unsigned int u = ((unsigned int)x) << 16;
    return __builtin_bit_cast(float, u);
}
__device__ __forceinline__ u16 f2bf(float f) {
    unsigned int u = __builtin_bit_cast(unsigned int, f);
    u += 0x7FFF + ((u >> 16) & 1);
    return (u16)(u >> 16);
}

__device__ __forceinline__ void gload16(const void* g, void* l) {
    void* gg = const_cast<void*>(g);
    __builtin_amdgcn_global_load_lds(
        (__attribute__((address_space(1))) void*)gg,
        (__attribute__((address_space(3))) void*)l, 16, 0, 0);
}

// counted-vmcnt gate + raw barrier
__device__ __forceinline__ void gatebar(int G) {
    if (G == 4) asm volatile("s_waitcnt vmcnt(4)" ::: "memory");
    else if (G == 3) asm volatile("s_waitcnt vmcnt(3)" ::: "memory");
    else if (G == 2) asm volatile("s_waitcnt vmcnt(2)" ::: "memory");
    else asm volatile("s_waitcnt vmcnt(0)" ::: "memory");
    __builtin_amdgcn_sched_barrier(0);
    __builtin_amdgcn_s_barrier();
    __builtin_amdgcn_sched_barrier(0);
}

// ---------------- RoPE table ----------------
__global__ void rope_table_k(float* __restrict__ tab) {
    int idx = blockIdx.x * 256 + threadIdx.x;
    if (idx >= SEQ * 64) return;
    int s = idx >> 6;
    int i = idx & 63;
    float invf = expf(-(float)i * (float)(1.0 / 64.0) * logf(10000.0f));
    float ang = (float)s * invf;
    float sv, cv;
    sincosf(ang, &sv, &cv);
    tab[idx * 2] = cv;
    tab[idx * 2 + 1] = sv;
}

// ---------------- fp32 -> bf16 elementwise cast ----------------
__global__ __launch_bounds__(256) void cast_k(const float* __restrict__ src,
                                              u16* __restrict__ dst, int n4) {
    int i = blockIdx.x * 256 + threadIdx.x;
    if (i >= n4) return;
    f32x4 v = *(const f32x4*)&src[(size_t)i * 4];
    u16x4 o;
#pragma unroll
    for (int j = 0; j < 4; ++j) o[j] = f2bf(v[j]);
    *(u16x4*)&dst[(size_t)i * 4] = o;
}

// ---------------- fp32 transpose+cast (R x C fp32 -> C x R bf16) ----------------
__global__ __launch_bounds__(256) void transpose_cast_k(const float* __restrict__ src,
                                                        u16* __restrict__ dst, int R, int C) {
    __shared__ u16 tile[64][65];
    int t = threadIdx.x;
    int bx = blockIdx.x, by = blockIdx.y;
    int r0 = by * 64, c0 = bx * 64;
#pragma unroll
    for (int it = 0; it < 4; ++it) {
        int row = it * 16 + (t >> 4);
        int col = (t & 15) * 4;
        f32x4 v = *(const f32x4*)&src[(size_t)(r0 + row) * C + c0 + col];
        tile[row][col] = f2bf(v[0]); tile[row][col + 1] = f2bf(v[1]);
        tile[row][col + 2] = f2bf(v[2]); tile[row][col + 3] = f2bf(v[3]);
    }
    __syncthreads();
#pragma unroll
    for (int it = 0; it < 4; ++it) {
        int orow = it * 16 + (t >> 4);
        int ocol = (t & 15) * 4;
        u16x4 v;
        v[0] = tile[ocol][orow]; v[1] = tile[ocol + 1][orow];
        v[2] = tile[ocol + 2][orow]; v[3] = tile[ocol + 3][orow];
        *(u16x4*)&dst[(size_t)(c0 + orow) * R + r0 + ocol] = v;
    }
}

// ---- V transpose: VT_g[hv][d][s] <- QKV[s][5120 + hv*128 + d] (bf16) ----
__global__ __launch_bounds__(256) void transpose_vt_k(const u16* __restrict__ QKV,
                                                      u16* __restrict__ VTg) {
    __shared__ u16 tile[64][65];
    int t = threadIdx.x;
    int s0 = blockIdx.x * 64;
    int hv = blockIdx.y >> 1;
    int d0 = (blockIdx.y & 1) * 64;
    const u16* src = QKV + (size_t)s0 * NQKV + 5120 + hv * 128 + d0;
#pragma unroll
    for (int it = 0; it < 4; ++it) {
        int row = it * 16 + (t >> 4);
        int col = (t & 15) * 4;
        u16x4 v = *(const u16x4*)&src[(size_t)row * NQKV + col];
        tile[row][col] = v[0]; tile[row][col + 1] = v[1];
        tile[row][col + 2] = v[2]; tile[row][col + 3] = v[3];
    }
    __syncthreads();
    u16* dst = VTg + (size_t)hv * 128 * SEQ + (size_t)d0 * SEQ + s0;
#pragma unroll
    for (int it = 0; it < 4; ++it) {
        int orow = it * 16 + (t >> 4);
        int ocol = (t & 15) * 4;
        u16x4 v;
        v[0] = tile[ocol][orow]; v[1] = tile[ocol + 1][orow];
        v[2] = tile[ocol + 2][orow]; v[3] = tile[ocol + 3][orow];
        *(u16x4*)&dst[(size_t)orow * SEQ + ocol] = v;
    }
}

// ---- GEMM1 big-tile: C[2048,6144] = A[2048,4096] * BT[6144,4096]^T ----
__global__ __launch_bounds__(512, 2) void gemm1_big_k(const u16* __restrict__ A,
                                                      const u16* __restrict__ BT,
                                                      u16* __restrict__ C) {
    constexpr int K = 4096, N = 6144;
    constexpr int SBUF = 57344;
    __shared__ alignas(16) char lds[2 * SBUF];

    int t = threadIdx.x;
    int lane = t & 63, w = t >> 6;
    int wr = w >> 2, wc = w & 3;
    int l15 = lane & 15, l4 = lane >> 4;

    int wg = blockIdx.x;
    int xcd = wg & 7, j = wg >> 3;
    int bm = ((xcd >> 2) << 2) + (j >> 3);
    int bn = ((xcd & 3) << 3) + (j & 7);

    const u16* Ab = A + (size_t)bm * 256 * K;
    const u16* Bb = BT + (size_t)bn * 192 * K;

    const u16* ga[4]; int da[4];
#pragma unroll
    for (int i = 0; i < 4; ++i) {
        int c = t + i * 512;
        int row = c >> 3;
        int ch = (c & 7) ^ (row & 7);
        ga[i] = Ab + (size_t)row * K + ch * 8;
        da[i] = c * 16;
    }
    const u16* gb[3]; int db[3];
#pragma unroll
    for (int i = 0; i < 3; ++i) {
        int c = t + i * 512;
        int row = c >> 3;
        int ch = (c & 7) ^ (row & 7);
        gb[i] = Bb + (size_t)row * K + ch * 8;
        db[i] = 32768 + c * 16;
    }

    auto stage = [&](int kt) {
        char* L = lds + (kt & 1) * SBUF;
        int ko = kt * 64;
#pragma unroll
        for (int i = 0; i < 4; ++i) gload16(ga[i] + ko, L + da[i]);
#pragma unroll
        for (int i = 0; i < 3; ++i) gload16(gb[i] + ko, L + db[i]);
    };

    f32x4 acc[8][3];
#pragma unroll
    for (int i = 0; i < 8; ++i)
#pragma unroll
        for (int j2 = 0; j2 < 3; ++j2) acc[i][j2] = f32x4{0.f, 0.f, 0.f, 0.f};

    int arow[8];
#pragma unroll
    for (int fm = 0; fm < 8; ++fm) arow[fm] = wr * 128 + fm * 16 + l15;
    int brow[3];
#pragma unroll
    for (int fn = 0; fn < 3; ++fn) brow[fn] = wc * 48 + fn * 16 + l15;

    stage(0);
    gatebar(0);

    for (int kt = 0; kt < 64; ++kt) {
        const u16* L = (const u16*)(lds + (kt & 1) * SBUF);
        if (kt + 1 < 64) stage(kt + 1);
        bf16x8 bf[3][2];
#pragma unroll
        for (int fn = 0; fn < 3; ++fn)
#pragma unroll
            for (int kk = 0; kk < 2; ++kk) {
                int ch = (kk * 4 + l4) ^ (brow[fn] & 7);
                bf[fn][kk] = *(const bf16x8*)&L[16384 + brow[fn] * 64 + ch * 8];
            }
#pragma unroll
        for (int p = 0; p < 4; ++p) {
            bf16x8 af[2][2];
#pragma unroll
            for (int f2 = 0; f2 < 2; ++f2)
#pragma unroll
                for (int kk = 0; kk < 2; ++kk) {
                    int r = arow[p * 2 + f2];
                    int ch = (kk * 4 + l4) ^ (r & 7);
                    af[f2][kk] = *(const bf16x8*)&L[r * 64 + ch * 8];
                }
            __builtin_amdgcn_s_setprio(1);
#pragma unroll
            for (int f2 = 0; f2 < 2; ++f2)
#pragma unroll
                for (int kk = 0; kk < 2; ++kk)
#pragma unroll
                    for (int fn = 0; fn < 3; ++fn)
                        acc[p * 2 + f2][fn] = __builtin_amdgcn_mfma_f32_16x16x32_bf16(
                            af[f2][kk], bf[fn][kk], acc[p * 2 + f2][fn], 0, 0, 0);
            __builtin_amdgcn_s_setprio(0);
        }
        gatebar(0);
    }

#pragma unroll
    for (int fm = 0; fm < 8; ++fm)
#pragma unroll
        for (int fn = 0; fn < 3; ++fn)
#pragma unroll
            for (int i = 0; i < 4; ++i) {
                int row = bm * 256 + wr * 128 + fm * 16 + l4 * 4 + i;
                int col = bn * 192 + wc * 48 + fn * 16 + l15;
                C[(size_t)row * N + col] = f2bf(acc[fm][fn][i]);
            }
}

// ---- GEMM2 big-tile: out[2048,4096] = ctx[2048,4096] * WoT[4096,4096]^T (fp32 out) ----
__global__ __launch_bounds__(512, 2) void gemm2_big_k(const u16* __restrict__ A,
                                                      const u16* __restrict__ BT,
                                                      float* __restrict__ C) {
    constexpr int K = 4096, N = 4096;
    constexpr int SBUF = 49152;
    __shared__ alignas(16) char lds[2 * SBUF];

    int t = threadIdx.x;
    int lane = t & 63, w = t >> 6;
    int wr = w >> 2, wc = w & 3;
    int l15 = lane & 15, l4 = lane >> 4;

    int wg = blockIdx.x;
    int xcd = wg & 7, j = wg >> 3;
    int bm = ((xcd >> 2) << 2) + (j >> 3);
    int bn = ((xcd & 3) << 3) + (j & 7);

    const u16* Ab = A + (size_t)bm * 256 * K;
    const u16* Bb = BT + (size_t)bn * 128 * K;

    const u16* ga[4]; int da[4];
#pragma unroll
    for (int i = 0; i < 4; ++i) {
        int c = t + i * 512;
        int row = c >> 3;
        int ch = (c & 7) ^ (row & 7);
        ga[i] = Ab + (size_t)row * K + ch * 8;
        da[i] = c * 16;
    }
    const u16* gb[2]; int db[2];
#pragma unroll
    for (int i = 0; i < 2; ++i) {
        int c = t + i * 512;
        int row = c >> 3;
        int ch = (c & 7) ^ (row & 7);
        gb[i] = Bb + (size_t)row * K + ch * 8;
        db[i] = 32768 + c * 16;
    }

    auto stage = [&](int kt) {
        char* L = lds + (kt & 1) * SBUF;
        int ko = kt * 64;
#pragma unroll
        for (int i = 0; i < 4; ++i) gload16(ga[i] + ko, L + da[i]);
#pragma unroll
        for (int i = 0; i < 2; ++i) gload16(gb[i] + ko, L + db[i]);
    };

    f32x4 acc[8][2];
#pragma unroll
    for (int i = 0; i < 8; ++i)
#pragma unroll
        for (int j2 = 0; j2 < 2; ++j2) acc[i][j2] = f32x4{0.f, 0.f, 0.f, 0.f};

    int arow[8];
#pragma unroll
    for (int fm = 0; fm < 8; ++fm) arow[fm] = wr * 128 + fm * 16 + l15;
    int brow[2];
#pragma unroll
    for (int fn = 0; fn < 2; ++fn) brow[fn] = wc * 32 + fn * 16 + l15;

    stage(0);
    gatebar(0);

    for (int kt = 0; kt < 64; ++kt) {
        const u16* L = (const u16*)(lds + (kt & 1) * SBUF);
        if (kt + 1 < 64) stage(kt + 1);
        bf16x8 bf[2][2];
#pragma unroll
        for (int fn = 0; fn < 2; ++fn)
#pragma unroll
            for (int kk = 0; kk < 2; ++kk) {
                int ch = (kk * 4 + l4) ^ (brow[fn] & 7);
                bf[fn][kk] = *(const bf16x8*)&L[16384 + brow[fn] * 64 + ch * 8];
            }
#pragma unroll
        for (int p = 0; p < 4; ++p) {
            bf16x8 af[2][2];
#pragma unroll
            for (int f2 = 0; f2 < 2; ++f2)
#pragma unroll
                for (int kk = 0; kk < 2; ++kk) {
                    int r = arow[p * 2 + f2];
                    int ch = (kk * 4 + l4) ^ (r & 7);
                    af[f2][kk] = *(const bf16x8*)&L[r * 64 + ch * 8];
                }
            __builtin_amdgcn_s_setprio(1);
#pragma unroll
            for (int f2 = 0; f2 < 2; ++f2)
#pragma unroll
                for (int kk = 0; kk < 2; ++kk)
#pragma unroll
                    for (int fn = 0; fn < 2; ++fn)
                        acc[p * 2 + f2][fn] = __builtin_amdgcn_mfma_f32_16x16x32_bf16(
                            af[f2][kk], bf[fn][kk], acc[p * 2 + f2][fn], 0, 0, 0);
            __builtin_amdgcn_s_setprio(0);
        }
        gatebar(0);
    }

#pragma unroll
    for (int fm = 0; fm < 8; ++fm)
#pragma unroll
        for (int fn = 0; fn < 2; ++fn)
#pragma unroll
            for (int i = 0; i < 4; ++i) {
                int row = bm * 256 + wr * 128 + fm * 16 + l4 * 4 + i;
                int col = bn * 128 + wc * 32 + fn * 16 + l15;
                C[(size_t)row * N + col] = acc[fm][fn][i];
            }
}

// -------- repack + RoPE (Q,K only): QKV[s,6144] -> Q[h,s,d], K[hk,s,d] --------
__global__ __launch_bounds__(256) void repack_rope_k(const u16* __restrict__ QKV,
                                                     const float* __restrict__ tab,
                                                     u16* __restrict__ Qo, u16* __restrict__ Ko) {
    int idx = blockIdx.x * 256 + threadIdx.x; // < SEQ*40*16
    int i4 = (idx & 15) * 4;
    int su = idx >> 4;
    int u = su % 40;
    int s = su / 40;
    const float* tp = tab + (s * 64 + i4) * 2;
    f32x4 t0 = *(const f32x4*)tp;
    f32x4 t1 = *(const f32x4*)(tp + 4);
    float cv[4] = {t0[0], t0[2], t1[0], t1[2]};
    float sv[4] = {t0[1], t0[3], t1[1], t1[3]};
    const u16* base;
    u16* ob;
    if (u < 32) {
        base = QKV + (size_t)s * NQKV + u * 128;
        ob = Qo + ((size_t)u * SEQ + s) * 128;
    } else {
        base = QKV + (size_t)s * NQKV + 4096 + (u - 32) * 128;
        ob = Ko + ((size_t)(u - 32) * SEQ + s) * 128;
    }
    u16x4 x1 = *(const u16x4*)(base + i4);
    u16x4 x2 = *(const u16x4*)(base + 64 + i4);
    u16x4 o1, o2;
#pragma unroll
    for (int j = 0; j < 4; ++j) {
        float a = bf2f(x1[j]), b = bf2f(x2[j]);
        o1[j] = f2bf(a * cv[j] - b * sv[j]);
        o2[j] = f2bf(b * cv[j] + a * sv[j]);
    }
    *(u16x4*)(ob + i4) = o1;
    *(u16x4*)(ob + 64 + i4) = o2;
}

// ------- causal GQA flash attention: 512 threads / 8 waves / 128-row q-blocks,
// ------- paired {bx, 15-bx}, K AND V^T both via gload_lds double-buffer -------
__global__ __launch_bounds__(512) void attn_k(const u16* __restrict__ Qg,
                                              const u16* __restrict__ Kg,
                                              const u16* __restrict__ VTg,
                                              u16* __restrict__ ctx) {
    constexpr float SCL2 = 0.08838834764831845f * 1.44269504088896340736f; // 1/sqrt(128)*log2e
    constexpr float THR = 11.5f;
    __shared__ alignas(16) u16 Klds[2][64 * 128];   // 2 x 16 KB, XOR-swizzled rows
    __shared__ alignas(16) u16 VTl[2][128 * 64];    // 2 x 16 KB, V^T [d][kv], XOR-swizzled
    __shared__ alignas(16) u16 Plds[8 * 16 * 72];   // 18 KB, per-wave P (stride 72)

    int t = threadIdx.x;
    int lane = t & 63, w = t >> 6;       // 8 waves
    int l15 = lane & 15, l4 = lane >> 4;
    int bx = blockIdx.x;                 // 0..7
    int h = blockIdx.y, hkv = h >> 2;
    const u16* Kh = Kg + (size_t)hkv * SEQ * 128;
    const u16* Vh = VTg + (size_t)hkv * 128 * SEQ;  // V^T: [128][SEQ]
    u16* Pw = &Plds[w * 1152];

    // K staging: slot c = t + i*512; row = c>>4 (128B rows), chunk swz
    int kr[2], kchs[2];
#pragma unroll
    for (int i2 = 0; i2 < 2; ++i2) {
        int c = t + i2 * 512;
        kr[i2] = c >> 4;
        kchs[i2] = (c & 15) ^ (kr[i2] & 7);
    }
    // V^T staging: slot c = t + i*512; d = c>>3 (64kv=128B rows, 8 chunks), chunk swz
    int vd[2], vchs[2];
#pragma unroll
    for (int i2 = 0; i2 < 2; ++i2) {
        int c = t + i2 * 512;
        vd[i2] = c >> 3;
        vchs[i2] = (c & 7) ^ (vd[i2] & 7);
    }

    int q0 = bx * 128;        // member A; member B = (15-bx)*128
    int ntA = 2 * bx + 2;     // A tiles; B has 32-2bx; total 34

    bf16x8 qf[4];
    f32x4 o[8];
    float m_i[4], l_i[4];     // l_i = per-lane partials (reduced at write_ctx)

    auto kvbase = [&](int tt) { return (tt < ntA ? tt : tt - ntA) << 6; };
    auto load_q = [&]() {
        const u16* Qh = Qg + ((size_t)h * SEQ + q0 + w * 16 + l15) * 128;
#pragma unroll
        for (int ks = 0; ks < 4; ++ks) qf[ks] = *(const bf16x8*)(Qh + ks * 32 + l4 * 8);
    };
    auto reset_acc = [&]() {
#pragma unroll
        for (int nf = 0; nf < 8; ++nf) o[nf] = f32x4{0.f, 0.f, 0.f, 0.f};
#pragma unroll
        for (int i = 0; i < 4; ++i) { m_i[i] = -3.0e38f; l_i[i] = 0.f; }
    };
    auto write_ctx = [&]() {
        float inv[4];
#pragma unroll
        for (int i = 0; i < 4; ++i) {
            float rs = l_i[i];
            rs += __shfl_xor(rs, 1);
            rs += __shfl_xor(rs, 2);
            rs += __shfl_xor(rs, 4);
            rs += __shfl_xor(rs, 8);
            inv[i] = 1.0f / rs;
        }
#pragma unroll
        for (int nf = 0; nf < 8; ++nf)
#pragma unroll
            for (int i = 0; i < 4; ++i) {
                int qrow = q0 + w * 16 + l4 * 4 + i;
                ctx[(size_t)qrow * 4096 + h * 128 + nf * 16 + l15] = f2bf(o[nf][i] * inv[i]);
            }
    };
    auto stage = [&](int tt) {
        int kv0 = kvbase(tt);
        const u16* Kt = Kh + (size_t)kv0 * 128;
        char* kb = (char*)Klds[tt & 1];
        char* vb = (char*)VTl[tt & 1];
#pragma unroll
        for (int i2 = 0; i2 < 2; ++i2)
            gload16(Kt + kr[i2] * 128 + kchs[i2] * 8, kb + (size_t)(t + i2 * 512) * 16);
#pragma unroll
        for (int i2 = 0; i2 < 2; ++i2)
            gload16(Vh + (size_t)vd[i2] * SEQ + kv0 + vchs[i2] * 8,
                    vb + (size_t)(t + i2 * 512) * 16);
    };

    load_q();
    reset_acc();
    stage(0);

    for (int tt = 0; tt < 34; ++tt) {
        // B1: all waves done compute(tt-1) -> safe to overwrite buf (tt+1)&1
        __builtin_amdgcn_s_barrier();
        __builtin_amdgcn_sched_barrier(0);
        bool nxt = (tt + 1 < 34);
        if (nxt) stage(tt + 1); // 4 VMEM
        gatebar(nxt ? 4 : 0);   // K(tt),VT(tt) landed for all waves; tt+1 in flight
        if (tt == ntA) {
            write_ctx();
            q0 = (15 - bx) * 128;
            load_q();
            reset_acc();
        }

        int b = tt & 1;
        int kv0 = kvbase(tt);
        const u16* KL = Klds[b];
        const u16* VL = VTl[b];

        // ---- QK^T ----
        f32x4 sa[4];
#pragma unroll
        for (int cg = 0; cg < 4; ++cg) {
            sa[cg] = f32x4{0.f, 0.f, 0.f, 0.f};
            int row = cg * 16 + l15;
#pragma unroll
            for (int ks = 0; ks < 4; ++ks) {
                int chs = (ks * 4 + l4) ^ (row & 7);
                bf16x8 kf = *(const bf16x8*)&KL[row * 128 + chs * 8];
                sa[cg] = __builtin_amdgcn_mfma_f32_16x16x32_bf16(qf[ks], kf, sa[cg], 0, 0, 0);
            }
        }
#pragma unroll
        for (int cg = 0; cg < 4; ++cg)
#pragma unroll
            for (int i = 0; i < 4; ++i) sa[cg][i] *= SCL2;
        if (kv0 + 63 > q0 + w * 16) {
#pragma unroll
            for (int cg = 0; cg < 4; ++cg) {
                int col = kv0 + cg * 16 + l15;
#pragma unroll
                for (int i = 0; i < 4; ++i) {
                    int qrow = q0 + w * 16 + l4 * 4 + i;
                    if (col > qrow) sa[cg][i] = -3.0e38f;
                }
            }
        }
        // ---- online softmax: per-lane defer test, no shuffles in steady state ----
        float lmx[4];
#pragma unroll
        for (int i = 0; i < 4; ++i)
            lmx[i] = fmaxf(fmaxf(sa[0][i], sa[1][i]), fmaxf(sa[2][i], sa[3][i]));
        bool defer = __all((lmx[0] <= m_i[0] + THR) & (lmx[1] <= m_i[1] + THR) &
                           (lmx[2] <= m_i[2] + THR) & (lmx[3] <= m_i[3] + THR));
        if (!defer) {
            float corr[4];
#pragma unroll
            for (int i = 0; i < 4; ++i) {
                float m0 = lmx[i];
                m0 = fmaxf(m0, __shfl_xor(m0, 1));
                m0 = fmaxf(m0, __shfl_xor(m0, 2));
                m0 = fmaxf(m0, __shfl_xor(m0, 4));
                m0 = fmaxf(m0, __shfl_xor(m0, 8));
                float mnew = fmaxf(m_i[i], m0);
                corr[i] = __builtin_amdgcn_exp2f(m_i[i] - mnew);
                m_i[i] = mnew;
                l_i[i] *= corr[i];
            }
#pragma unroll
            for (int nf = 0; nf < 8; ++nf) {
                o[nf][0] *= corr[0]; o[nf][1] *= corr[1];
                o[nf][2] *= corr[2]; o[nf][3] *= corr[3];
            }
        }
#pragma unroll
        for (int i = 0; i < 4; ++i) {
            int prow = l4 * 4 + i;
            int sw = (prow >> 1) & 3;
            float rs = 0.f;
#pragma unroll
            for (int cg = 0; cg < 4; ++cg) {
                float p = __builtin_amdgcn_exp2f(sa[cg][i] - m_i[i]);
                rs += p;
                int ch = cg * 2 + (l15 >> 3);
                Pw[prow * 72 + ((ch ^ sw) << 3) + (l15 & 7)] = f2bf(p);
            }
            l_i[i] += rs;
        }
        // ---- PV: P (per-wave LDS) x V^T (swizzled LDS, b128 reads) ----
        asm volatile("s_waitcnt lgkmcnt(0)" ::: "memory");
        __builtin_amdgcn_sched_barrier(0);
#pragma unroll
        for (int kst = 0; kst < 2; ++kst) {
            int pchs = (kst * 4 + l4) ^ ((l15 >> 1) & 3);
            bf16x8 pf = *(const bf16x8*)&Pw[l15 * 72 + pchs * 8];
#pragma unroll
            for (int nf = 0; nf < 8; ++nf) {
                int d = nf * 16 + l15;
                int vch = (kst * 4 + l4) ^ (d & 7);
                bf16x8 vf = *(const bf16x8*)&VL[d * 64 + vch * 8];
                o[nf] = __builtin_amdgcn_mfma_f32_16x16x32_bf16(pf, vf, o[nf], 0, 0, 0);
            }
        }
    }
    write_ctx();
}

extern "C" void kernel_launch(void* const* d_in, const int* in_sizes, int n_in,
                              void* d_out, int out_size, void* d_ws, size_t ws_size,
                              hipStream_t stream) {
    const float* hidden = (const float*)d_in[0];   // fp32 (per reference dtype)
    // d_in[1] = sequence_mask (unused by reference math: all-ones + causal)
    const float* Wqkv = (const float*)d_in[2];     // fp32
    const float* Wo = (const float*)d_in[3];       // fp32
    float* out = (float*)d_out;                    // fp32 output
    char* ws = (char*)d_ws;

    u16* WqkvT   = (u16*)(ws + 0);           // transpose1 -> gemm1
    u16* Qb      = (u16*)(ws + 0);           // repack -> attn (WqkvT dead)
    u16* Kb      = (u16*)(ws + 16777216);
    u16* VTg     = (u16*)(ws + 20971520);    // transpose_vt -> attn (4MB: 8x128x2048)
    u16* WoT     = (u16*)(ws + 25165824);    // transposeWo -> gemm2
    u16* QKV     = (u16*)(ws + 50331648);    // gemm1 -> repack+transpose_vt
    u16* ctx     = (u16*)(ws + 58720256);    // attn -> gemm2
    float* tab   = (float*)(ws + 75497472);  // rope -> repack
    u16* hiddenB = (u16*)(ws + 76546048);    // cast -> gemm1

    rope_table_k<<<512, 256, 0, stream>>>(tab);
    cast_k<<<8192, 256, 0, stream>>>(hidden, hiddenB, 2048 * 4096 / 4);
    transpose_cast_k<<<dim3(96, 64), 256, 0, stream>>>(Wqkv, WqkvT, 4096, 6144);
    gemm1_big_k<<<256, 512, 0, stream>>>(hiddenB, WqkvT, QKV);
    repack_rope_k<<<5120, 256, 0, stream>>>(QKV, tab, Qb, Kb);
    transpose_vt_k<<<dim3(32, 16), 256, 0, stream>>>(QKV, VTg);
    transpose_cast_k<<<dim3(64, 64), 256, 0, stream>>>(Wo, WoT, 4096, 4096);
    attn_k<<<dim3(8, 32), 512, 0, stream>>>(Qb, Kb, VTg, ctx);
    gemm2_big_k<<<256, 512, 0, stream>>>(ctx, WoT, out);
}

// Round 18
// 306.159 us; speedup vs baseline: 1.6288x; 1.0172x over previous
//
#include <hip/hip_runtime.h>

typedef unsigned short u16;
typedef __bf16 bf16x8 __attribute__((ext_vector_type(8)));
typedef float f32x4 __attribute__((ext_vector_type(4)));
typedef u16 u16x4 __attribute__((ext_vector_type(4)));

constexpr int SEQ = 2048;
constexpr int NQKV = 6144; // (32 + 2*8) * 128

__device__ __forceinline__ float bf2f(u16 x) {
    unsigned int u = ((unsigned int)x) << 16;
    return __builtin_bit_cast(float, u);
}
__device__ __forceinline__ u16 f2bf(float f) {
    unsigned int u = __builtin_bit_cast(unsigned int, f);
    u += 0x7FFF + ((u >> 16) & 1);
    return (u16)(u >> 16);
}

__device__ __forceinline__ void gload16(const void* g, void* l) {
    void* gg = const_cast<void*>(g);
    __builtin_amdgcn_global_load_lds(
        (__attribute__((address_space(1))) void*)gg,
        (__attribute__((address_space(3))) void*)l, 16, 0, 0);
}

// counted-vmcnt gate + raw barrier
__device__ __forceinline__ void gatebar(int G) {
    if (G == 8) asm volatile("s_waitcnt vmcnt(8)" ::: "memory");
    else if (G == 4) asm volatile("s_waitcnt vmcnt(4)" ::: "memory");
    else if (G == 3) asm volatile("s_waitcnt vmcnt(3)" ::: "memory");
    else if (G == 2) asm volatile("s_waitcnt vmcnt(2)" ::: "memory");
    else asm volatile("s_waitcnt vmcnt(0)" ::: "memory");
    __builtin_amdgcn_sched_barrier(0);
    __builtin_amdgcn_s_barrier();
    __builtin_amdgcn_sched_barrier(0);
}

// ---------------- RoPE table ----------------
__global__ void rope_table_k(float* __restrict__ tab) {
    int idx = blockIdx.x * 256 + threadIdx.x;
    if (idx >= SEQ * 64) return;
    int s = idx >> 6;
    int i = idx & 63;
    float invf = expf(-(float)i * (float)(1.0 / 64.0) * logf(10000.0f));
    float ang = (float)s * invf;
    float sv, cv;
    sincosf(ang, &sv, &cv);
    tab[idx * 2] = cv;
    tab[idx * 2 + 1] = sv;
}

// ---------------- fp32 -> bf16 elementwise cast ----------------
__global__ __launch_bounds__(256) void cast_k(const float* __restrict__ src,
                                              u16* __restrict__ dst, int n4) {
    int i = blockIdx.x * 256 + threadIdx.x;
    if (i >= n4) return;
    f32x4 v = *(const f32x4*)&src[(size_t)i * 4];
    u16x4 o;
#pragma unroll
    for (int j = 0; j < 4; ++j) o[j] = f2bf(v[j]);
    *(u16x4*)&dst[(size_t)i * 4] = o;
}

// ---------------- fp32 transpose+cast (R x C fp32 -> C x R bf16) ----------------
__global__ __launch_bounds__(256) void transpose_cast_k(const float* __restrict__ src,
                                                        u16* __restrict__ dst, int R, int C) {
    __shared__ u16 tile[64][65];
    int t = threadIdx.x;
    int bx = blockIdx.x, by = blockIdx.y;
    int r0 = by * 64, c0 = bx * 64;
#pragma unroll
    for (int it = 0; it < 4; ++it) {
        int row = it * 16 + (t >> 4);
        int col = (t & 15) * 4;
        f32x4 v = *(const f32x4*)&src[(size_t)(r0 + row) * C + c0 + col];
        tile[row][col] = f2bf(v[0]); tile[row][col + 1] = f2bf(v[1]);
        tile[row][col + 2] = f2bf(v[2]); tile[row][col + 3] = f2bf(v[3]);
    }
    __syncthreads();
#pragma unroll
    for (int it = 0; it < 4; ++it) {
        int orow = it * 16 + (t >> 4);
        int ocol = (t & 15) * 4;
        u16x4 v;
        v[0] = tile[ocol][orow]; v[1] = tile[ocol + 1][orow];
        v[2] = tile[ocol + 2][orow]; v[3] = tile[ocol + 3][orow];
        *(u16x4*)&dst[(size_t)(c0 + orow) * R + r0 + ocol] = v;
    }
}

// ---- V transpose: VT_g[hv][d][s] <- QKV[s][5120 + hv*128 + d] (bf16) ----
__global__ __launch_bounds__(256) void transpose_vt_k(const u16* __restrict__ QKV,
                                                      u16* __restrict__ VTg) {
    __shared__ u16 tile[64][65];
    int t = threadIdx.x;
    int s0 = blockIdx.x * 64;
    int hv = blockIdx.y >> 1;
    int d0 = (blockIdx.y & 1) * 64;
    const u16* src = QKV + (size_t)s0 * NQKV + 5120 + hv * 128 + d0;
#pragma unroll
    for (int it = 0; it < 4; ++it) {
        int row = it * 16 + (t >> 4);
        int col = (t & 15) * 4;
        u16x4 v = *(const u16x4*)&src[(size_t)row * NQKV + col];
        tile[row][col] = v[0]; tile[row][col + 1] = v[1];
        tile[row][col + 2] = v[2]; tile[row][col + 3] = v[3];
    }
    __syncthreads();
    u16* dst = VTg + (size_t)hv * 128 * SEQ + (size_t)d0 * SEQ + s0;
#pragma unroll
    for (int it = 0; it < 4; ++it) {
        int orow = it * 16 + (t >> 4);
        int ocol = (t & 15) * 4;
        u16x4 v;
        v[0] = tile[ocol][orow]; v[1] = tile[ocol + 1][orow];
        v[2] = tile[ocol + 2][orow]; v[3] = tile[ocol + 3][orow];
        *(u16x4*)&dst[(size_t)orow * SEQ + ocol] = v;
    }
}

// ---- GEMM1 big-tile: C[2048,6144] = A[2048,4096] * BT[6144,4096]^T ----
__global__ __launch_bounds__(512, 2) void gemm1_big_k(const u16* __restrict__ A,
                                                      const u16* __restrict__ BT,
                                                      u16* __restrict__ C) {
    constexpr int K = 4096, N = 6144;
    constexpr int SBUF = 57344;
    __shared__ alignas(16) char lds[2 * SBUF];

    int t = threadIdx.x;
    int lane = t & 63, w = t >> 6;
    int wr = w >> 2, wc = w & 3;
    int l15 = lane & 15, l4 = lane >> 4;

    int wg = blockIdx.x;
    int xcd = wg & 7, j = wg >> 3;
    int bm = ((xcd >> 2) << 2) + (j >> 3);
    int bn = ((xcd & 3) << 3) + (j & 7);

    const u16* Ab = A + (size_t)bm * 256 * K;
    const u16* Bb = BT + (size_t)bn * 192 * K;

    const u16* ga[4]; int da[4];
#pragma unroll
    for (int i = 0; i < 4; ++i) {
        int c = t + i * 512;
        int row = c >> 3;
        int ch = (c & 7) ^ (row & 7);
        ga[i] = Ab + (size_t)row * K + ch * 8;
        da[i] = c * 16;
    }
    const u16* gb[3]; int db[3];
#pragma unroll
    for (int i = 0; i < 3; ++i) {
        int c = t + i * 512;
        int row = c >> 3;
        int ch = (c & 7) ^ (row & 7);
        gb[i] = Bb + (size_t)row * K + ch * 8;
        db[i] = 32768 + c * 16;
    }

    auto stage = [&](int kt) {
        char* L = lds + (kt & 1) * SBUF;
        int ko = kt * 64;
#pragma unroll
        for (int i = 0; i < 4; ++i) gload16(ga[i] + ko, L + da[i]);
#pragma unroll
        for (int i = 0; i < 3; ++i) gload16(gb[i] + ko, L + db[i]);
    };

    f32x4 acc[8][3];
#pragma unroll
    for (int i = 0; i < 8; ++i)
#pragma unroll
        for (int j2 = 0; j2 < 3; ++j2) acc[i][j2] = f32x4{0.f, 0.f, 0.f, 0.f};

    int arow[8];
#pragma unroll
    for (int fm = 0; fm < 8; ++fm) arow[fm] = wr * 128 + fm * 16 + l15;
    int brow[3];
#pragma unroll
    for (int fn = 0; fn < 3; ++fn) brow[fn] = wc * 48 + fn * 16 + l15;

    stage(0);
    gatebar(0);

    for (int kt = 0; kt < 64; ++kt) {
        const u16* L = (const u16*)(lds + (kt & 1) * SBUF);
        if (kt + 1 < 64) stage(kt + 1);
        bf16x8 bf[3][2];
#pragma unroll
        for (int fn = 0; fn < 3; ++fn)
#pragma unroll
            for (int kk = 0; kk < 2; ++kk) {
                int ch = (kk * 4 + l4) ^ (brow[fn] & 7);
                bf[fn][kk] = *(const bf16x8*)&L[16384 + brow[fn] * 64 + ch * 8];
            }
#pragma unroll
        for (int p = 0; p < 4; ++p) {
            bf16x8 af[2][2];
#pragma unroll
            for (int f2 = 0; f2 < 2; ++f2)
#pragma unroll
                for (int kk = 0; kk < 2; ++kk) {
                    int r = arow[p * 2 + f2];
                    int ch = (kk * 4 + l4) ^ (r & 7);
                    af[f2][kk] = *(const bf16x8*)&L[r * 64 + ch * 8];
                }
            __builtin_amdgcn_s_setprio(1);
#pragma unroll
            for (int f2 = 0; f2 < 2; ++f2)
#pragma unroll
                for (int kk = 0; kk < 2; ++kk)
#pragma unroll
                    for (int fn = 0; fn < 3; ++fn)
                        acc[p * 2 + f2][fn] = __builtin_amdgcn_mfma_f32_16x16x32_bf16(
                            af[f2][kk], bf[fn][kk], acc[p * 2 + f2][fn], 0, 0, 0);
            __builtin_amdgcn_s_setprio(0);
        }
        gatebar(0);
    }

#pragma unroll
    for (int fm = 0; fm < 8; ++fm)
#pragma unroll
        for (int fn = 0; fn < 3; ++fn)
#pragma unroll
            for (int i = 0; i < 4; ++i) {
                int row = bm * 256 + wr * 128 + fm * 16 + l4 * 4 + i;
                int col = bn * 192 + wc * 48 + fn * 16 + l15;
                C[(size_t)row * N + col] = f2bf(acc[fm][fn][i]);
            }
}

// ---- GEMM2 big-tile: out[2048,4096] = ctx[2048,4096] * WoT[4096,4096]^T (fp32 out) ----
__global__ __launch_bounds__(512, 2) void gemm2_big_k(const u16* __restrict__ A,
                                                      const u16* __restrict__ BT,
                                                      float* __restrict__ C) {
    constexpr int K = 4096, N = 4096;
    constexpr int SBUF = 49152;
    __shared__ alignas(16) char lds[2 * SBUF];

    int t = threadIdx.x;
    int lane = t & 63, w = t >> 6;
    int wr = w >> 2, wc = w & 3;
    int l15 = lane & 15, l4 = lane >> 4;

    int wg = blockIdx.x;
    int xcd = wg & 7, j = wg >> 3;
    int bm = ((xcd >> 2) << 2) + (j >> 3);
    int bn = ((xcd & 3) << 3) + (j & 7);

    const u16* Ab = A + (size_t)bm * 256 * K;
    const u16* Bb = BT + (size_t)bn * 128 * K;

    const u16* ga[4]; int da[4];
#pragma unroll
    for (int i = 0; i < 4; ++i) {
        int c = t + i * 512;
        int row = c >> 3;
        int ch = (c & 7) ^ (row & 7);
        ga[i] = Ab + (size_t)row * K + ch * 8;
        da[i] = c * 16;
    }
    const u16* gb[2]; int db[2];
#pragma unroll
    for (int i = 0; i < 2; ++i) {
        int c = t + i * 512;
        int row = c >> 3;
        int ch = (c & 7) ^ (row & 7);
        gb[i] = Bb + (size_t)row * K + ch * 8;
        db[i] = 32768 + c * 16;
    }

    auto stage = [&](int kt) {
        char* L = lds + (kt & 1) * SBUF;
        int ko = kt * 64;
#pragma unroll
        for (int i = 0; i < 4; ++i) gload16(ga[i] + ko, L + da[i]);
#pragma unroll
        for (int i = 0; i < 2; ++i) gload16(gb[i] + ko, L + db[i]);
    };

    f32x4 acc[8][2];
#pragma unroll
    for (int i = 0; i < 8; ++i)
#pragma unroll
        for (int j2 = 0; j2 < 2; ++j2) acc[i][j2] = f32x4{0.f, 0.f, 0.f, 0.f};

    int arow[8];
#pragma unroll
    for (int fm = 0; fm < 8; ++fm) arow[fm] = wr * 128 + fm * 16 + l15;
    int brow[2];
#pragma unroll
    for (int fn = 0; fn < 2; ++fn) brow[fn] = wc * 32 + fn * 16 + l15;

    stage(0);
    gatebar(0);

    for (int kt = 0; kt < 64; ++kt) {
        const u16* L = (const u16*)(lds + (kt & 1) * SBUF);
        if (kt + 1 < 64) stage(kt + 1);
        bf16x8 bf[2][2];
#pragma unroll
        for (int fn = 0; fn < 2; ++fn)
#pragma unroll
            for (int kk = 0; kk < 2; ++kk) {
                int ch = (kk * 4 + l4) ^ (brow[fn] & 7);
                bf[fn][kk] = *(const bf16x8*)&L[16384 + brow[fn] * 64 + ch * 8];
            }
#pragma unroll
        for (int p = 0; p < 4; ++p) {
            bf16x8 af[2][2];
#pragma unroll
            for (int f2 = 0; f2 < 2; ++f2)
#pragma unroll
                for (int kk = 0; kk < 2; ++kk) {
                    int r = arow[p * 2 + f2];
                    int ch = (kk * 4 + l4) ^ (r & 7);
                    af[f2][kk] = *(const bf16x8*)&L[r * 64 + ch * 8];
                }
            __builtin_amdgcn_s_setprio(1);
#pragma unroll
            for (int f2 = 0; f2 < 2; ++f2)
#pragma unroll
                for (int kk = 0; kk < 2; ++kk)
#pragma unroll
                    for (int fn = 0; fn < 2; ++fn)
                        acc[p * 2 + f2][fn] = __builtin_amdgcn_mfma_f32_16x16x32_bf16(
                            af[f2][kk], bf[fn][kk], acc[p * 2 + f2][fn], 0, 0, 0);
            __builtin_amdgcn_s_setprio(0);
        }
        gatebar(0);
    }

#pragma unroll
    for (int fm = 0; fm < 8; ++fm)
#pragma unroll
        for (int fn = 0; fn < 2; ++fn)
#pragma unroll
            for (int i = 0; i < 4; ++i) {
                int row = bm * 256 + wr * 128 + fm * 16 + l4 * 4 + i;
                int col = bn * 128 + wc * 32 + fn * 16 + l15;
                C[(size_t)row * N + col] = acc[fm][fn][i];
            }
}

// -------- repack + RoPE (Q,K only): QKV[s,6144] -> Q[h,s,d], K[hk,s,d] --------
__global__ __launch_bounds__(256) void repack_rope_k(const u16* __restrict__ QKV,
                                                     const float* __restrict__ tab,
                                                     u16* __restrict__ Qo, u16* __restrict__ Ko) {
    int idx = blockIdx.x * 256 + threadIdx.x; // < SEQ*40*16
    int i4 = (idx & 15) * 4;
    int su = idx >> 4;
    int u = su % 40;
    int s = su / 40;
    const float* tp = tab + (s * 64 + i4) * 2;
    f32x4 t0 = *(const f32x4*)tp;
    f32x4 t1 = *(const f32x4*)(tp + 4);
    float cv[4] = {t0[0], t0[2], t1[0], t1[2]};
    float sv[4] = {t0[1], t0[3], t1[1], t1[3]};
    const u16* base;
    u16* ob;
    if (u < 32) {
        base = QKV + (size_t)s * NQKV + u * 128;
        ob = Qo + ((size_t)u * SEQ + s) * 128;
    } else {
        base = QKV + (size_t)s * NQKV + 4096 + (u - 32) * 128;
        ob = Ko + ((size_t)(u - 32) * SEQ + s) * 128;
    }
    u16x4 x1 = *(const u16x4*)(base + i4);
    u16x4 x2 = *(const u16x4*)(base + 64 + i4);
    u16x4 o1, o2;
#pragma unroll
    for (int j = 0; j < 4; ++j) {
        float a = bf2f(x1[j]), b = bf2f(x2[j]);
        o1[j] = f2bf(a * cv[j] - b * sv[j]);
        o2[j] = f2bf(b * cv[j] + a * sv[j]);
    }
    *(u16x4*)(ob + i4) = o1;
    *(u16x4*)(ob + 64 + i4) = o2;
}

// ------- causal GQA flash attention: KVBLK=128, 512 threads / 8 waves / 128-row q-blocks,
// ------- paired {bx, 15-bx} (17 uniform tiles), K+V^T via gload_lds double-buffer -------
__global__ __launch_bounds__(512) void attn_k(const u16* __restrict__ Qg,
                                              const u16* __restrict__ Kg,
                                              const u16* __restrict__ VTg,
                                              u16* __restrict__ ctx) {
    constexpr float SCL2 = 0.08838834764831845f * 1.44269504088896340736f; // 1/sqrt(128)*log2e
    constexpr float THR = 11.5f;
    __shared__ alignas(16) u16 Klds[2][128 * 128];  // 2 x 32 KB, XOR-swizzled rows
    __shared__ alignas(16) u16 VTl[2][128 * 128];   // 2 x 32 KB, V^T [d][kv], swizzled
    __shared__ alignas(16) u16 Plds[8 * 16 * 72];   // 18 KB, per-wave P (64-kv half-pass)

    int t = threadIdx.x;
    int lane = t & 63, w = t >> 6;       // 8 waves
    int l15 = lane & 15, l4 = lane >> 4;
    int bx = blockIdx.x;                 // 0..7
    int h = blockIdx.y, hkv = h >> 2;
    const u16* Kh = Kg + (size_t)hkv * SEQ * 128;
    const u16* Vh = VTg + (size_t)hkv * 128 * SEQ;  // V^T: [128][SEQ]
    u16* Pw = &Plds[w * 1152];

    // K staging: slot c = t + i*512 (i 0..3); row = c>>4 (128 rows x 256B), chunk swz
    int kr[4], kchs[4];
#pragma unroll
    for (int i2 = 0; i2 < 4; ++i2) {
        int c = t + i2 * 512;
        kr[i2] = c >> 4;
        kchs[i2] = (c & 15) ^ (kr[i2] & 7);
    }
    // V^T staging: slot c; d = c>>4 (128 d-rows x 256B = 16 chunks), chunk swz
    int vd[4], vchs[4];
#pragma unroll
    for (int i2 = 0; i2 < 4; ++i2) {
        int c = t + i2 * 512;
        vd[i2] = c >> 4;
        vchs[i2] = (c & 15) ^ (vd[i2] & 7);
    }

    int q0 = bx * 128;        // member A; member B = (15-bx)*128
    int ntA = bx + 1;         // A tiles (128-kv); B has 16-bx; total 17

    bf16x8 qf[4];
    f32x4 o[8];
    float m_i[4], l_i[4];     // l_i = per-lane partials (reduced at write_ctx)

    auto kvbase = [&](int tt) { return (tt < ntA ? tt : tt - ntA) << 7; };
    auto load_q = [&]() {
        const u16* Qh = Qg + ((size_t)h * SEQ + q0 + w * 16 + l15) * 128;
#pragma unroll
        for (int ks = 0; ks < 4; ++ks) qf[ks] = *(const bf16x8*)(Qh + ks * 32 + l4 * 8);
    };
    auto reset_acc = [&]() {
#pragma unroll
        for (int nf = 0; nf < 8; ++nf) o[nf] = f32x4{0.f, 0.f, 0.f, 0.f};
#pragma unroll
        for (int i = 0; i < 4; ++i) { m_i[i] = -3.0e38f; l_i[i] = 0.f; }
    };
    auto write_ctx = [&]() {
        float inv[4];
#pragma unroll
        for (int i = 0; i < 4; ++i) {
            float rs = l_i[i];
            rs += __shfl_xor(rs, 1);
            rs += __shfl_xor(rs, 2);
            rs += __shfl_xor(rs, 4);
            rs += __shfl_xor(rs, 8);
            inv[i] = 1.0f / rs;
        }
#pragma unroll
        for (int nf = 0; nf < 8; ++nf)
#pragma unroll
            for (int i = 0; i < 4; ++i) {
                int qrow = q0 + w * 16 + l4 * 4 + i;
                ctx[(size_t)qrow * 4096 + h * 128 + nf * 16 + l15] = f2bf(o[nf][i] * inv[i]);
            }
    };
    auto stage = [&](int tt) {
        int kv0 = kvbase(tt);
        const u16* Kt = Kh + (size_t)kv0 * 128;
        char* kb = (char*)Klds[tt & 1];
        char* vb = (char*)VTl[tt & 1];
#pragma unroll
        for (int i2 = 0; i2 < 4; ++i2)
            gload16(Kt + kr[i2] * 128 + kchs[i2] * 8, kb + (size_t)(t + i2 * 512) * 16);
#pragma unroll
        for (int i2 = 0; i2 < 4; ++i2)
            gload16(Vh + (size_t)vd[i2] * SEQ + kv0 + vchs[i2] * 8,
                    vb + (size_t)(t + i2 * 512) * 16);
    };

    load_q();
    reset_acc();
    stage(0);

    for (int tt = 0; tt < 17; ++tt) {
        // B1: all waves done compute(tt-1) -> safe to overwrite buf (tt+1)&1
        __builtin_amdgcn_s_barrier();
        __builtin_amdgcn_sched_barrier(0);
        bool nxt = (tt + 1 < 17);
        if (nxt) stage(tt + 1); // 8 VMEM
        gatebar(nxt ? 8 : 0);   // K(tt),VT(tt) landed for all waves; tt+1 in flight
        if (tt == ntA) {
            write_ctx();
            q0 = (15 - bx) * 128;
            load_q();
            reset_acc();
        }

        int b = tt & 1;
        int kv0 = kvbase(tt);
        const u16* KL = Klds[b];
        const u16* VL = VTl[b];

        // ---- QK^T: 8 col-groups of 16 ----
        f32x4 sa[8];
#pragma unroll
        for (int cg = 0; cg < 8; ++cg) {
            sa[cg] = f32x4{0.f, 0.f, 0.f, 0.f};
            int row = cg * 16 + l15;
#pragma unroll
            for (int ks = 0; ks < 4; ++ks) {
                int chs = (ks * 4 + l4) ^ (row & 7);
                bf16x8 kf = *(const bf16x8*)&KL[row * 128 + chs * 8];
                sa[cg] = __builtin_amdgcn_mfma_f32_16x16x32_bf16(qf[ks], kf, sa[cg], 0, 0, 0);
            }
        }
#pragma unroll
        for (int cg = 0; cg < 8; ++cg)
#pragma unroll
            for (int i = 0; i < 4; ++i) sa[cg][i] *= SCL2;
        if (kv0 + 127 > q0 + w * 16) {
#pragma unroll
            for (int cg = 0; cg < 8; ++cg) {
                int col = kv0 + cg * 16 + l15;
#pragma unroll
                for (int i = 0; i < 4; ++i) {
                    int qrow = q0 + w * 16 + l4 * 4 + i;
                    if (col > qrow) sa[cg][i] = -3.0e38f;
                }
            }
        }
        // ---- online softmax: per-lane defer test, no shuffles in steady state ----
        float lmx[4];
#pragma unroll
        for (int i = 0; i < 4; ++i) {
            float a0 = fmaxf(fmaxf(sa[0][i], sa[1][i]), fmaxf(sa[2][i], sa[3][i]));
            float a1 = fmaxf(fmaxf(sa[4][i], sa[5][i]), fmaxf(sa[6][i], sa[7][i]));
            lmx[i] = fmaxf(a0, a1);
        }
        bool defer = __all((lmx[0] <= m_i[0] + THR) & (lmx[1] <= m_i[1] + THR) &
                           (lmx[2] <= m_i[2] + THR) & (lmx[3] <= m_i[3] + THR));
        if (!defer) {
            float corr[4];
#pragma unroll
            for (int i = 0; i < 4; ++i) {
                float m0 = lmx[i];
                m0 = fmaxf(m0, __shfl_xor(m0, 1));
                m0 = fmaxf(m0, __shfl_xor(m0, 2));
                m0 = fmaxf(m0, __shfl_xor(m0, 4));
                m0 = fmaxf(m0, __shfl_xor(m0, 8));
                float mnew = fmaxf(m_i[i], m0);
                corr[i] = __builtin_amdgcn_exp2f(m_i[i] - mnew);
                m_i[i] = mnew;
                l_i[i] *= corr[i];
            }
#pragma unroll
            for (int nf = 0; nf < 8; ++nf) {
                o[nf][0] *= corr[0]; o[nf][1] *= corr[1];
                o[nf][2] *= corr[2]; o[nf][3] *= corr[3];
            }
        }
        // ---- two 64-kv half-passes sharing the per-wave P buffer ----
#pragma unroll
        for (int hf = 0; hf < 2; ++hf) {
#pragma unroll
            for (int i = 0; i < 4; ++i) {
                int prow = l4 * 4 + i;
                int sw = (prow >> 1) & 3;
                float rs = 0.f;
#pragma unroll
                for (int cg = 0; cg < 4; ++cg) {
                    float p = __builtin_amdgcn_exp2f(sa[hf * 4 + cg][i] - m_i[i]);
                    rs += p;
                    int ch = cg * 2 + (l15 >> 3);
                    Pw[prow * 72 + ((ch ^ sw) << 3) + (l15 & 7)] = f2bf(p);
                }
                l_i[i] += rs;
            }
            asm volatile("s_waitcnt lgkmcnt(0)" ::: "memory");
            __builtin_amdgcn_sched_barrier(0);
#pragma unroll
            for (int kst = 0; kst < 2; ++kst) {
                int pchs = (kst * 4 + l4) ^ ((l15 >> 1) & 3);
                bf16x8 pf = *(const bf16x8*)&Pw[l15 * 72 + pchs * 8];
                int kst2 = hf * 2 + kst;
#pragma unroll
                for (int nf = 0; nf < 8; ++nf) {
                    int d = nf * 16 + l15;
                    int vch = (kst2 * 4 + l4) ^ (d & 7);
                    bf16x8 vf = *(const bf16x8*)&VL[d * 128 + vch * 8];
                    o[nf] = __builtin_amdgcn_mfma_f32_16x16x32_bf16(pf, vf, o[nf], 0, 0, 0);
                }
            }
        }
    }
    write_ctx();
}

extern "C" void kernel_launch(void* const* d_in, const int* in_sizes, int n_in,
                              void* d_out, int out_size, void* d_ws, size_t ws_size,
                              hipStream_t stream) {
    const float* hidden = (const float*)d_in[0];   // fp32 (per reference dtype)
    // d_in[1] = sequence_mask (unused by reference math: all-ones + causal)
    const float* Wqkv = (const float*)d_in[2];     // fp32
    const float* Wo = (const float*)d_in[3];       // fp32
    float* out = (float*)d_out;                    // fp32 output
    char* ws = (char*)d_ws;

    u16* WqkvT   = (u16*)(ws + 0);           // transpose1 -> gemm1
    u16* Qb      = (u16*)(ws + 0);           // repack -> attn (WqkvT dead)
    u16* Kb      = (u16*)(ws + 16777216);
    u16* VTg     = (u16*)(ws + 20971520);    // transpose_vt -> attn (4MB: 8x128x2048)
    u16* WoT     = (u16*)(ws + 25165824);    // transposeWo -> gemm2
    u16* QKV     = (u16*)(ws + 50331648);    // gemm1 -> repack+transpose_vt
    u16* ctx     = (u16*)(ws + 58720256);    // attn -> gemm2
    float* tab   = (float*)(ws + 75497472);  // rope -> repack
    u16* hiddenB = (u16*)(ws + 76546048);    // cast -> gemm1

    rope_table_k<<<512, 256, 0, stream>>>(tab);
    cast_k<<<8192, 256, 0, stream>>>(hidden, hiddenB, 2048 * 4096 / 4);
    transpose_cast_k<<<dim3(96, 64), 256, 0, stream>>>(Wqkv, WqkvT, 4096, 6144);
    gemm1_big_k<<<256, 512, 0, stream>>>(hiddenB, WqkvT, QKV);
    repack_rope_k<<<5120, 256, 0, stream>>>(QKV, tab, Qb, Kb);
    transpose_vt_k<<<dim3(32, 16), 256, 0, stream>>>(QKV, VTg);
    transpose_cast_k<<<dim3(64, 64), 256, 0, stream>>>(Wo, WoT, 4096, 4096);
    attn_k<<<dim3(8, 32), 512, 0, stream>>>(Qb, Kb, VTg, ctx);
    gemm2_big_k<<<256, 512, 0, stream>>>(ctx, WoT, out);
}